// Round 11
// baseline (2352.886 us; speedup 1.0000x reference)
//
#include <hip/hip_runtime.h>
#include <math.h>

#define NPP 1000
#define BSZ 4
#define HD 128
#define NL 4
#define RBFD 20
#define EDD 16
#define KN 9
#define NKPP 12
#define NN 8000
#define EE 72000
#define STDV 10.0
#define SIGC 25.0
#define GAMC 10.0
#define PID 3.14159265358979323846

__device__ __forceinline__ double silud(double x){ return x / (1.0 + exp(-x)); }

__global__ void k_sent(float* __restrict__ out, float val){
  if(threadIdx.x<5 && blockIdx.x==0) out[threadIdx.x]=val;
}

// ------------------------------------------------------------------
// weight preconversion to f64
// ------------------------------------------------------------------
__global__ __launch_bounds__(256) void k_cvt_node(const float* __restrict__ msgW, double* __restrict__ Wn){
  int idx = blockIdx.x*256+threadIdx.x;
  if(idx >= 4*128*256) return;
  int l = idx>>15; int r = idx & 32767; int k = r>>8; int j = r&255;
  const float* W = msgW + (size_t)l*292*128;
  Wn[idx] = (j<128) ? (double)W[k*128+j] : (double)W[(128+k)*128 + (j-128)];
}
__global__ __launch_bounds__(256) void k_cvt_edge(const float* __restrict__ msgW, const float* __restrict__ msgb,
    double* __restrict__ We){
  int idx = blockIdx.x*256+threadIdx.x;
  if(idx >= 4*37*128) return;
  int l = idx/(37*128); int r = idx%(37*128); int k = r>>7; int j = r&127;
  if(k<36) We[idx] = (double)msgW[(size_t)l*292*128 + (256+k)*128 + j];
  else     We[idx] = (double)msgb[l*128 + j];
}
__global__ __launch_bounds__(256) void k_cvt_xv(const float* __restrict__ xW, const float* __restrict__ vW,
    double* __restrict__ xv){
  int idx = blockIdx.x*256+threadIdx.x;
  if(idx >= 4*128*128) return;
  int l = idx>>14; int r = idx & 16383; int hh = r>>7; int c = r&127;
  xv[(size_t)l*32768 + hh*256 + 2*c]   = (double)xW[(size_t)l*16384 + hh*128 + c];
  xv[(size_t)l*32768 + hh*256 + 2*c+1] = (double)vW[(size_t)l*16384 + hh*128 + c];
}

// ------------------------------------------------------------------
// geometry (f64)
// ------------------------------------------------------------------
__global__ __launch_bounds__(256) void k_geom(const float* __restrict__ X, const float* __restrict__ center,
    const float* __restrict__ kpin, const float* __restrict__ rot, const float* __restrict__ trans,
    double* __restrict__ Xca, double* __restrict__ ori0, double* __restrict__ kpc, double* __restrict__ tkpc){
  int i = blockIdx.x*256 + threadIdx.x;
  const double inv = 1.0/STDV;
  if(i < NN){
    int b = i / (2*NPP);
    int s = (i / NPP) & 1;
    int n = i % NPP;
    double q0 = (double)X[i*12+3] - (double)center[b*3+0];
    double q1 = (double)X[i*12+4] - (double)center[b*3+1];
    double q2 = (double)X[i*12+5] - (double)center[b*3+2];
    if(s==0){
      int o=(b*NPP+n)*3;
      ori0[o]=q0*inv; ori0[o+1]=q1*inv; ori0[o+2]=q2*inv;
      const float* R = rot + b*9;
      #pragma unroll
      for(int d=0; d<3; d++)
        Xca[i*3+d] = (q0*(double)R[d] + q1*(double)R[3+d] + q2*(double)R[6+d])*inv + (double)trans[b*3+d];
    } else {
      Xca[i*3+0]=q0*inv; Xca[i*3+1]=q1*inv; Xca[i*3+2]=q2*inv;
    }
  } else if(i < NN + BSZ*NKPP){
    int j = i - NN;
    int b = j / NKPP;
    double q0 = (double)kpin[j*3+0]-(double)center[b*3+0];
    double q1 = (double)kpin[j*3+1]-(double)center[b*3+1];
    double q2 = (double)kpin[j*3+2]-(double)center[b*3+2];
    kpc[j*3+0]=q0*inv; kpc[j*3+1]=q1*inv; kpc[j*3+2]=q2*inv;
    const float* R = rot + b*9;
    #pragma unroll
    for(int d=0; d<3; d++)
      tkpc[j*3+d] = (q0*(double)R[d] + q1*(double)R[3+d] + q2*(double)R[6+d])*inv + (double)trans[b*3+d];
  }
}

// ------------------------------------------------------------------
__global__ __launch_bounds__(256) void k_edge(const double* __restrict__ Xca, const int* __restrict__ src,
    const int* __restrict__ dst, double* __restrict__ dirv, double* __restrict__ rbfb){
  int e = blockIdx.x*256 + threadIdx.x;
  if(e >= EE) return;
  int sp = src[e], dp = dst[e];
  double d0 = Xca[dp*3+0]-Xca[sp*3+0];
  double d1 = Xca[dp*3+1]-Xca[sp*3+1];
  double d2 = Xca[dp*3+2]-Xca[sp*3+2];
  double nr = sqrt(d0*d0+d1*d1+d2*d2) + 1e-08;
  double iv = 1.0/nr;
  dirv[e*3+0]=d0*iv; dirv[e*3+1]=d1*iv; dirv[e*3+2]=d2*iv;
  #pragma unroll
  for(int j=0;j<RBFD;j++)
    rbfb[e*RBFD+j] = sin(nr*(double)(j+1)*PID)*iv;
}

// ------------------------------------------------------------------
// h init: 4 nodes/block, 256 thr
// ------------------------------------------------------------------
__global__ __launch_bounds__(256) void k_hinit(const float* __restrict__ na,
    const float* __restrict__ W1, const float* __restrict__ b1,
    const float* __restrict__ W2, const float* __restrict__ b2, double* __restrict__ h){
  __shared__ double cin[4][64];
  __shared__ double hmid[4][128];
  int n0 = blockIdx.x*4;
  int tid = threadIdx.x;
  {
    int r=tid>>6, k=tid&63;
    cin[r][k] = (double)na[(n0+r)*64 + k];
  }
  __syncthreads();
  int r = tid>>6, c0 = (tid&63)*2;
  double a0=(double)b1[c0], a1=(double)b1[c0+1];
  for(int k=0;k<64;k++){
    double a = cin[r][k];
    const float* wp = W1 + k*HD + c0;
    a0 += a*(double)wp[0]; a1 += a*(double)wp[1];
  }
  hmid[r][c0]=silud(a0); hmid[r][c0+1]=silud(a1);
  __syncthreads();
  double s0=(double)b2[c0], s1=(double)b2[c0+1];
  for(int k=0;k<HD;k++){
    double a = hmid[r][k];
    const float* wp = W2 + k*HD + c0;
    s0 += a*(double)wp[0]; s1 += a*(double)wp[1];
  }
  h[(size_t)(n0+r)*HD+c0]=s0; h[(size_t)(n0+r)*HD+c0+1]=s1;
}

// ------------------------------------------------------------------
// node projection: 4 nodes/block, 128 thr, col=tid*2, 4-node accum
// ------------------------------------------------------------------
__global__ __launch_bounds__(128) void k_nodeproj(const double* __restrict__ h, const double* __restrict__ Wn,
    double* __restrict__ P){
  __shared__ double cin[4][128];
  int n0 = blockIdx.x*4;
  int tid = threadIdx.x;
  for(int idx=tid; idx<512; idx+=128){
    int r=idx>>7, k=idx&127;
    cin[r][k]=h[(size_t)(n0+r)*HD+k];
  }
  __syncthreads();
  int c0 = tid*2;
  double a00=0,a01=0,a10=0,a11=0,a20=0,a21=0,a30=0,a31=0;
  for(int k=0;k<128;k++){
    double2 w = *(const double2*)(Wn + (size_t)k*256 + c0);
    double x0=cin[0][k],x1=cin[1][k],x2=cin[2][k],x3=cin[3][k];
    a00+=x0*w.x; a01+=x0*w.y; a10+=x1*w.x; a11+=x1*w.y;
    a20+=x2*w.x; a21+=x2*w.y; a30+=x3*w.x; a31+=x3*w.y;
  }
  P[(size_t)(n0+0)*256+c0]=a00; P[(size_t)(n0+0)*256+c0+1]=a01;
  P[(size_t)(n0+1)*256+c0]=a10; P[(size_t)(n0+1)*256+c0+1]=a11;
  P[(size_t)(n0+2)*256+c0]=a20; P[(size_t)(n0+2)*256+c0+1]=a21;
  P[(size_t)(n0+3)*256+c0]=a30; P[(size_t)(n0+3)*256+c0+1]=a31;
}

// ------------------------------------------------------------------
// edge message: m[e] = silu( P[src][0:128] + P[dst][128:256] + feat(e)@Wedge2 )
// ------------------------------------------------------------------
__global__ __launch_bounds__(256) void k_edgemsg(const double* __restrict__ P, const double* __restrict__ rbfb,
    const float* __restrict__ ea, const int* __restrict__ src, const int* __restrict__ dst,
    const double* __restrict__ We, double* __restrict__ m){
  __shared__ double feat[32][41];
  __shared__ int ssi[32], ddi[32];
  int e0 = blockIdx.x*32;
  int tid = threadIdx.x;
  for(int idx=tid; idx<32*RBFD; idx+=256){
    int e=idx/RBFD, k=idx%RBFD;
    feat[e][k]=rbfb[(size_t)(e0+e)*RBFD+k];
  }
  for(int idx=tid; idx<32*EDD; idx+=256){
    int e=idx>>4, k=idx&15;
    feat[e][20+k]=(double)ea[(size_t)(e0+e)*EDD+k];
  }
  if(tid<32){ feat[tid][36]=1.0; ssi[tid]=src[e0+tid]; ddi[tid]=dst[e0+tid]; }
  __syncthreads();
  int t = tid&15, g = tid>>4;
  int j0 = g*8;
  double acc0[8], acc1[8];
  #pragma unroll
  for(int j=0;j<8;j++){ acc0[j]=0.0; acc1[j]=0.0; }
  for(int k=0;k<37;k++){
    const double* wp = We + (size_t)k*128 + j0;
    double a0 = feat[t][k], a1 = feat[t+16][k];
    #pragma unroll
    for(int j=0;j<8;j++){ double w=wp[j]; acc0[j]+=a0*w; acc1[j]+=a1*w; }
  }
  {
    const double* p1 = P + (size_t)ssi[t]*256 + j0;
    const double* p2 = P + (size_t)ddi[t]*256 + 128 + j0;
    double* mr = m + (size_t)(e0+t)*HD + j0;
    #pragma unroll
    for(int j=0;j<8;j++) mr[j] = silud(acc0[j]+p1[j]+p2[j]);
  }
  {
    const double* p1 = P + (size_t)ssi[t+16]*256 + j0;
    const double* p2 = P + (size_t)ddi[t+16]*256 + 128 + j0;
    double* mr = m + (size_t)(e0+t+16)*HD + j0;
    #pragma unroll
    for(int j=0;j<8;j++) mr[j] = silud(acc1[j]+p1[j]+p2[j]);
  }
}

// ------------------------------------------------------------------
// intra = h + silu([h,agg]@W1+b1)@W2+b2 ; agg fused (9-row m sum)
// 4 nodes/block, 128 thr, col=tid, 4-node accum
// ------------------------------------------------------------------
__global__ __launch_bounds__(128) void k_upd(const double* __restrict__ h, const double* __restrict__ m,
    const float* __restrict__ W1, const float* __restrict__ b1,
    const float* __restrict__ W2, const float* __restrict__ b2, double* __restrict__ h2){
  __shared__ double cin[4][256];
  __shared__ double hmid[4][128];
  int n0 = blockIdx.x*4;
  int tid = threadIdx.x;
  for(int idx=tid; idx<4*128; idx+=128){
    int r=idx>>7, k=idx&127;
    cin[r][k] = h[(size_t)(n0+r)*HD+k];
    const double* mp = m + ((size_t)(n0+r)*KN)*HD + k;
    double s=0.0;
    #pragma unroll
    for(int kk=0;kk<KN;kk++) s += mp[(size_t)kk*HD];
    cin[r][128+k]=s;
  }
  __syncthreads();
  int col = tid;
  double bb=(double)b1[col];
  double a0=bb,a1=bb,a2=bb,a3=bb;
  for(int k=0;k<256;k++){
    double w = (double)W1[(size_t)k*HD+col];
    a0 += cin[0][k]*w; a1 += cin[1][k]*w; a2 += cin[2][k]*w; a3 += cin[3][k]*w;
  }
  hmid[0][col]=silud(a0); hmid[1][col]=silud(a1); hmid[2][col]=silud(a2); hmid[3][col]=silud(a3);
  __syncthreads();
  bb=(double)b2[col];
  a0=bb;a1=bb;a2=bb;a3=bb;
  for(int k=0;k<128;k++){
    double w = (double)W2[(size_t)k*HD+col];
    a0 += hmid[0][k]*w; a1 += hmid[1][k]*w; a2 += hmid[2][k]*w; a3 += hmid[3][k]*w;
  }
  h2[(size_t)(n0+0)*HD+col] = cin[0][col]+a0;
  h2[(size_t)(n0+1)*HD+col] = cin[1][col]+a1;
  h2[(size_t)(n0+2)*HD+col] = cin[2][col]+a2;
  h2[(size_t)(n0+3)*HD+col] = cin[3][col]+a3;
}

// ------------------------------------------------------------------
// fused v update: 2 nodes/block SEQUENTIAL in-thread, 128 thr (col=tid)
// m read via wave-uniform addresses (scalar-load eligible, SMEM pipe);
// only md (6/iter) on LDS -> FMA-bound
// ------------------------------------------------------------------
__global__ __launch_bounds__(128) void k_vupd(const double* __restrict__ m, const double* __restrict__ va,
    const double* __restrict__ dirv, const int* __restrict__ src,
    const double* __restrict__ xv, double* __restrict__ vb){
  __shared__ double md[2][3][128];
  __shared__ double dv[2][9][3];
  __shared__ int sp[2][9];
  int n0 = blockIdx.x*2;
  int tid = threadIdx.x;
  const double* m0 = m + (size_t)n0*KN*HD;       // uniform base
  const double* m1 = m0 + (size_t)KN*HD;         // uniform base
  if(tid<18){
    int nd=tid/9, kk=tid-nd*9;
    int e=(n0+nd)*KN+kk;
    sp[nd][kk]=src[e];
    dv[nd][kk][0]=dirv[e*3]; dv[nd][kk][1]=dirv[e*3+1]; dv[nd][kk][2]=dirv[e*3+2];
  }
  __syncthreads();
  {
    // md[nd][c][hh] = sum_kk dv[nd][kk][c] * m[nd][kk][hh]; thread = hh
    double s00=0,s01=0,s02=0,s10=0,s11=0,s12=0;
    for(int kk=0;kk<9;kk++){
      double mk0 = m0[kk*HD+tid];
      double mk1 = m1[kk*HD+tid];
      s00+=dv[0][kk][0]*mk0; s01+=dv[0][kk][1]*mk0; s02+=dv[0][kk][2]*mk0;
      s10+=dv[1][kk][0]*mk1; s11+=dv[1][kk][1]*mk1; s12+=dv[1][kk][2]*mk1;
    }
    md[0][0][tid]=s00; md[0][1][tid]=s01; md[0][2][tid]=s02;
    md[1][0][tid]=s10; md[1][1][tid]=s11; md[1][2][tid]=s12;
  }
  __syncthreads();
  int col = tid;
  double oa0=0,oa1=0,oa2=0, ob0=0,ob1=0,ob2=0;
  double mva[9], mvb[9];
  #pragma unroll
  for(int kk=0;kk<9;kk++){ mva[kk]=0.0; mvb[kk]=0.0; }
  for(int hh=0; hh<128; hh++){
    double2 wp = *(const double2*)(xv + (size_t)hh*256 + 2*col);
    oa0 += md[0][0][hh]*wp.x; oa1 += md[0][1][hh]*wp.x; oa2 += md[0][2][hh]*wp.x;
    ob0 += md[1][0][hh]*wp.x; ob1 += md[1][1][hh]*wp.x; ob2 += md[1][2][hh]*wp.x;
    #pragma unroll
    for(int kk=0;kk<9;kk++){
      mva[kk] += m0[kk*HD+hh]*wp.y;   // uniform -> s_load
      mvb[kk] += m1[kk*HD+hh]*wp.y;   // uniform -> s_load
    }
  }
  {
    double o0=oa0, o1=oa1, o2=oa2;
    #pragma unroll
    for(int kk=0;kk<9;kk++){
      size_t s3 = (size_t)sp[0][kk]*384 + col*3;
      double mk = mva[kk];
      o0 += va[s3]*mk; o1 += va[s3+1]*mk; o2 += va[s3+2]*mk;
    }
    size_t b3 = (size_t)n0*384 + col*3;
    vb[b3]  = va[b3]  + o0;
    vb[b3+1]= va[b3+1]+ o1;
    vb[b3+2]= va[b3+2]+ o2;
  }
  {
    double o0=ob0, o1=ob1, o2=ob2;
    #pragma unroll
    for(int kk=0;kk<9;kk++){
      size_t s3 = (size_t)sp[1][kk]*384 + col*3;
      double mk = mvb[kk];
      o0 += va[s3]*mk; o1 += va[s3+1]*mk; o2 += va[s3+2]*mk;
    }
    size_t b3 = (size_t)(n0+1)*384 + col*3;
    vb[b3]  = va[b3]  + o0;
    vb[b3+1]= va[b3+1]+ o1;
    vb[b3+2]= va[b3+2]+ o2;
  }
}

// ------------------------------------------------------------------
// attention partials + finish
// ------------------------------------------------------------------
__global__ __launch_bounds__(128) void k_att1(const double* __restrict__ h2, double* __restrict__ partial){
  int blk = blockIdx.x;
  int bs = blk>>3, ch = blk&7;
  int col = threadIdx.x;
  size_t base = ((size_t)bs*NPP + ch*125)*HD + col;
  double s=0.0;
  for(int i=0;i<125;i++) s += h2[base + (size_t)i*HD];
  partial[(size_t)blk*HD + col] = s;
}
__global__ __launch_bounds__(128) void k_att2(const double* __restrict__ partial, const float* __restrict__ attW,
    double* __restrict__ u){
  __shared__ double mm[128];
  int bs = blockIdx.x;
  int col = threadIdx.x;
  int os = bs^1;
  double s=0.0;
  for(int c=0;c<8;c++) s += partial[(size_t)(os*8+c)*HD + col];
  mm[col] = s*(1.0/NPP);
  __syncthreads();
  double acc=0.0;
  for(int k=0;k<HD;k++) acc += (double)attW[col*HD+k]*mm[k];
  u[bs*HD+col] = acc;
}

// ------------------------------------------------------------------
// h_new = intra + g*act(intra), g fused
// ------------------------------------------------------------------
__global__ __launch_bounds__(128) void k_actcomb(const double* __restrict__ h2, const double* __restrict__ u,
    const float* __restrict__ W1, const float* __restrict__ b1,
    const float* __restrict__ W2, const float* __restrict__ b2, double* __restrict__ h){
  __shared__ double As[4][128];
  __shared__ double hmid[4][128];
  __shared__ double pd[128];
  __shared__ double gsh[4];
  int n0 = blockIdx.x*4;
  int tid = threadIdx.x;
  int bs = n0/NPP;
  for(int idx=tid; idx<512; idx+=128){
    int r=idx>>7, k=idx&127;
    As[r][k] = h2[(size_t)(n0+r)*HD+k];
  }
  __syncthreads();
  {
    int nd=tid>>5, q=tid&31;
    double p=0.0;
    for(int j=q;j<128;j+=32) p += As[nd][j]*u[bs*HD+j];
    pd[tid]=p;
  }
  __syncthreads();
  if((tid&31)==0){
    int nd=tid>>5;
    double s=0.0;
    for(int i2=0;i2<32;i2++) s+=pd[nd*32+i2];
    gsh[nd]=1.0/(1.0+exp(-s));
  }
  __syncthreads();
  int col = tid;
  double bb=(double)b1[col];
  double a0=bb,a1=bb,a2=bb,a3=bb;
  for(int k=0;k<128;k++){
    double w = (double)W1[(size_t)k*HD+col];
    a0 += As[0][k]*w; a1 += As[1][k]*w; a2 += As[2][k]*w; a3 += As[3][k]*w;
  }
  hmid[0][col]=silud(a0); hmid[1][col]=silud(a1); hmid[2][col]=silud(a2); hmid[3][col]=silud(a3);
  __syncthreads();
  bb=(double)b2[col];
  a0=bb;a1=bb;a2=bb;a3=bb;
  for(int k=0;k<128;k++){
    double w = (double)W2[(size_t)k*HD+col];
    a0 += hmid[0][k]*w; a1 += hmid[1][k]*w; a2 += hmid[2][k]*w; a3 += hmid[3][k]*w;
  }
  h[(size_t)(n0+0)*HD+col] = As[0][col] + gsh[0]*a0;
  h[(size_t)(n0+1)*HD+col] = As[1][col] + gsh[1]*a1;
  h[(size_t)(n0+2)*HD+col] = As[2][col] + gsh[2]*a2;
  h[(size_t)(n0+3)*HD+col] = As[3][col] + gsh[3]*a3;
}

// ------------------------------------------------------------------
// geb vector branch
// ------------------------------------------------------------------
__global__ __launch_bounds__(256) void k_gebv(const double* __restrict__ va,
    const float* __restrict__ Wv1, const float* __restrict__ Wv2,
    double* __restrict__ v1, double* __restrict__ nv2){
  __shared__ double vl[2][384];
  int n0 = blockIdx.x*2;
  int tid = threadIdx.x;
  for(int idx=tid; idx<768; idx+=256){
    int r=idx/384, k=idx%384;
    vl[r][k] = va[(size_t)(n0+r)*384+k];
  }
  __syncthreads();
  int r = tid>>7, col = tid&127;
  double a10=0.0,a11=0.0,a12=0.0, a20=0.0,a21=0.0,a22=0.0;
  for(int hh=0; hh<HD; hh++){
    double w1 = (double)Wv1[hh*HD+col];
    double w2 = (double)Wv2[hh*HD+col];
    double v0=vl[r][hh*3], v1e=vl[r][hh*3+1], v2e=vl[r][hh*3+2];
    a10+=v0*w1; a11+=v1e*w1; a12+=v2e*w1;
    a20+=v0*w2; a21+=v1e*w2; a22+=v2e*w2;
  }
  size_t b3=(size_t)(n0+r)*384+col*3;
  v1[b3]=a10; v1[b3+1]=a11; v1[b3+2]=a12;
  nv2[(size_t)(n0+r)*HD+col]=sqrt(a20*a20+a21*a21+a22*a22);
}

// ------------------------------------------------------------------
// s = silu([h,nv2]@gebW1+b1)@gebW2+b2
// ------------------------------------------------------------------
__global__ __launch_bounds__(256) void k_gebs(const double* __restrict__ h, const double* __restrict__ nv2,
    const float* __restrict__ W1, const float* __restrict__ b1,
    const float* __restrict__ W2, const float* __restrict__ b2, double* __restrict__ s){
  __shared__ double cin[4][256];
  __shared__ double hmid[4][128];
  int n0 = blockIdx.x*4;
  int tid = threadIdx.x;
  for(int idx=tid; idx<4*HD; idx+=256){
    int r=idx>>7, k=idx&127;
    cin[r][k]    = h[(size_t)(n0+r)*HD + k];
    cin[r][HD+k] = nv2[(size_t)(n0+r)*HD + k];
  }
  __syncthreads();
  int r = tid>>6, c0 = (tid&63)*2;
  double a0=(double)b1[c0], a1=(double)b1[c0+1];
  for(int k=0;k<2*HD;k++){
    double a = cin[r][k];
    const float* wp = W1 + (size_t)k*HD + c0;
    a0 += a*(double)wp[0]; a1 += a*(double)wp[1];
  }
  hmid[r][c0]=silud(a0); hmid[r][c0+1]=silud(a1);
  __syncthreads();
  int c1 = (tid&63)*4;
  double s0=(double)b2[c1], s1=(double)b2[c1+1], s2=(double)b2[c1+2], s3=(double)b2[c1+3];
  for(int k=0;k<HD;k++){
    double a = hmid[r][k];
    const float* wp = W2 + (size_t)k*256 + c1;
    s0 += a*(double)wp[0]; s1 += a*(double)wp[1]; s2 += a*(double)wp[2]; s3 += a*(double)wp[3];
  }
  double* srow = s + (size_t)(n0+r)*256 + c1;
  srow[0]=s0; srow[1]=s1; srow[2]=s2; srow[3]=s3;
}

// ------------------------------------------------------------------
__global__ __launch_bounds__(256) void k_kpc(const double* __restrict__ Xca, double* __restrict__ cbb){
  __shared__ double red[768];
  int bs = blockIdx.x;
  int tid = threadIdx.x;
  double s0=0.0,s1=0.0,s2=0.0;
  for(int nidx=tid; nidx<NPP; nidx+=256){
    int i = bs*NPP+nidx;
    s0+=Xca[i*3]; s1+=Xca[i*3+1]; s2+=Xca[i*3+2];
  }
  red[tid]=s0; red[256+tid]=s1; red[512+tid]=s2;
  __syncthreads();
  for(int st=128; st>0; st>>=1){
    if(tid<st){ red[tid]+=red[tid+st]; red[256+tid]+=red[256+tid+st]; red[512+tid]+=red[512+tid+st]; }
    __syncthreads();
  }
  if(tid==0){ cbb[bs*3]=red[0]*(1.0/NPP); cbb[bs*3+1]=red[256]*(1.0/NPP); cbb[bs*3+2]=red[512]*(1.0/NPP); }
}

// ------------------------------------------------------------------
// keypoint partials: 2 nodes/block
// ------------------------------------------------------------------
__global__ __launch_bounds__(256) void k_kpgen(const double* __restrict__ Xca, const double* __restrict__ sbuf,
    const double* __restrict__ v1, const double* __restrict__ cbb, const float* __restrict__ fW,
    const float* __restrict__ sW1, const float* __restrict__ sb1, const float* __restrict__ sW2,
    const float* __restrict__ sb2, double* __restrict__ ypart){
  __shared__ double tt[2][3][128];
  __shared__ double ssv[2][128];
  __shared__ double zz[2][64];
  __shared__ double snorm[2];
  __shared__ double ylL[2][37];
  int blk = blockIdx.x;
  int tid = threadIdx.x;
  int r = tid>>7, t = tid&127;
  int n = blk*2 + r;
  int bs = n/NPP;
  const double* srow = sbuf + (size_t)n*256;
  const double* vrow = v1 + (size_t)n*384;
  double gate = srow[128+t];
  double hp = srow[t];
  double vf0 = vrow[t*3+0]*gate, vf1 = vrow[t*3+1]*gate, vf2 = vrow[t*3+2]*gate;
  tt[r][0][t]=vf0*hp; tt[r][1][t]=vf1*hp; tt[r][2][t]=vf2*hp;
  ssv[r][t]=sqrt(vf0*vf0+vf1*vf1+vf2*vf2);
  if(t==0){
    double x0=Xca[n*3]-cbb[bs*3], x1=Xca[n*3+1]-cbb[bs*3+1], x2=Xca[n*3+2]-cbb[bs*3+2];
    snorm[r]=sqrt(x0*x0+x1*x1+x2*x2);
  }
  __syncthreads();
  if(t<36){
    int k2=t/3, c=t%3;
    double a=0.0;
    for(int hh=0; hh<128; hh++) a += tt[r][c][hh]*(double)fW[hh*NKPP+k2];
    ylL[r][t]=a;
  } else if(t>=64){
    int j=t-64;
    double z=(double)sb1[j];
    for(int hh=0; hh<128; hh++) z += ssv[r][hh]*(double)sW1[hh*64+j];
    z += snorm[r]*(double)sW1[128*64+j];
    zz[r][j]=silud(z)*(double)sW2[j];
  }
  __syncthreads();
  if(t==36){
    double dn=(double)sb2[0];
    for(int j=0;j<64;j++) dn+=zz[r][j];
    ylL[r][36]=dn;
  }
  __syncthreads();
  if(tid<37) ypart[(size_t)blk*37+tid]=ylL[0][tid]+ylL[1][tid];
}

__global__ __launch_bounds__(64) void k_kpfin(const double* __restrict__ ypart,
    const double* __restrict__ cbb, double* __restrict__ Y){
  __shared__ double sums[37];
  int bs=blockIdx.x, tid=threadIdx.x;
  if(tid<37){
    double s=0.0;
    for(int i=0;i<500;i++) s += ypart[(size_t)(bs*500+i)*37 + tid];
    sums[tid]=s;
  }
  __syncthreads();
  if(tid<36){
    double dsh = sums[36]*(1.0/NPP);
    Y[bs*36+tid] = sums[tid]/dsh + cbb[bs*3 + tid%3];
  }
}

// ------------------------------------------------------------------
// per-sample: ot, Kabsch (Horn quaternion), dock, rmsd, X1a
// ------------------------------------------------------------------
__global__ __launch_bounds__(256) void k_final(const double* __restrict__ Y, const double* __restrict__ tkpc,
    const double* __restrict__ kpc, const float* __restrict__ rot, const float* __restrict__ trans,
    const double* __restrict__ Xca, const double* __restrict__ ori0,
    double* __restrict__ x1a, double* __restrict__ otb, double* __restrict__ dockb, double* __restrict__ rmsdb){
  int b = blockIdx.x;
  int tid = threadIdx.x;
  __shared__ double Rs[9];
  __shared__ double ts[3];
  __shared__ double red[256];
  if(tid==0){
    const double* Y1 = Y + (b*2+0)*36;
    const double* Y2 = Y + (b*2+1)*36;
    const double* P1 = tkpc + b*36;
    const double* P2 = kpc + b*36;
    double ot1=0.0, ot2=0.0;
    for(int i=0;i<12;i++){
      double best1=1e300, best2=1e300;
      for(int j=0;j<12;j++){
        double d1=0.0, d2=0.0;
        #pragma unroll
        for(int c=0;c<3;c++){
          double e1=Y1[i*3+c]-P1[j*3+c]; d1+=e1*e1;
          double e2=Y2[i*3+c]-P2[j*3+c]; d2+=e2*e2;
        }
        best1=fmin(best1,d1); best2=fmin(best2,d2);
      }
      ot1+=best1; ot2+=best2;
    }
    double ot = ot1*(1.0/36.0) + ot2*(1.0/36.0);
    double c1[3]={0,0,0}, c2[3]={0,0,0};
    for(int i=0;i<12;i++)
      for(int c=0;c<3;c++){ c1[c]+=Y1[i*3+c]; c2[c]+=Y2[i*3+c]; }
    for(int c=0;c<3;c++){ c1[c]/=12.0; c2[c]/=12.0; }
    double Hm[3][3]={{0,0,0},{0,0,0},{0,0,0}};
    for(int i=0;i<12;i++)
      for(int a=0;a<3;a++)
        for(int c=0;c<3;c++)
          Hm[a][c] += (Y1[i*3+a]-c1[a])*(Y2[i*3+c]-c2[c]);
    double Sxx=Hm[0][0],Sxy=Hm[0][1],Sxz=Hm[0][2];
    double Syx=Hm[1][0],Syy=Hm[1][1],Syz=Hm[1][2];
    double Szx=Hm[2][0],Szy=Hm[2][1],Szz=Hm[2][2];
    double K[4][4];
    K[0][0]=Sxx+Syy+Szz; K[0][1]=Syz-Szy;     K[0][2]=Szx-Sxz;      K[0][3]=Sxy-Syx;
    K[1][0]=K[0][1];     K[1][1]=Sxx-Syy-Szz; K[1][2]=Sxy+Syx;      K[1][3]=Szx+Sxz;
    K[2][0]=K[0][2];     K[2][1]=K[1][2];     K[2][2]=-Sxx+Syy-Szz; K[2][3]=Syz+Szy;
    K[3][0]=K[0][3];     K[3][1]=K[1][3];     K[3][2]=K[2][3];      K[3][3]=-Sxx-Syy+Szz;
    double V[4][4]={{1,0,0,0},{0,1,0,0},{0,0,1,0},{0,0,0,1}};
    for(int sweep=0;sweep<30;sweep++){
      for(int p=0;p<3;p++) for(int q=p+1;q<4;q++){
        double apq=K[p][q];
        if(fabs(apq)<1e-300) continue;
        double tau=(K[q][q]-K[p][p])/(2.0*apq);
        double t=(tau>=0.0?1.0:-1.0)/(fabs(tau)+sqrt(tau*tau+1.0));
        double cs=1.0/sqrt(t*t+1.0), sn=t*cs;
        for(int r2=0;r2<4;r2++){
          double krp=K[r2][p], krq=K[r2][q];
          K[r2][p]=cs*krp - sn*krq;
          K[r2][q]=sn*krp + cs*krq;
        }
        for(int r2=0;r2<4;r2++){
          double kpr=K[p][r2], kqr=K[q][r2];
          K[p][r2]=cs*kpr - sn*kqr;
          K[q][r2]=sn*kpr + cs*kqr;
        }
        for(int r2=0;r2<4;r2++){
          double vrp=V[r2][p], vrq=V[r2][q];
          V[r2][p]=cs*vrp - sn*vrq;
          V[r2][q]=sn*vrp + cs*vrq;
        }
      }
    }
    int mi=0;
    for(int i2=1;i2<4;i2++) if(K[i2][i2]>K[mi][mi]) mi=i2;
    double qw=V[0][mi], qx=V[1][mi], qy=V[2][mi], qz=V[3][mi];
    double Rh[3][3];
    Rh[0][0]=qw*qw+qx*qx-qy*qy-qz*qz; Rh[0][1]=2.0*(qx*qy-qw*qz);       Rh[0][2]=2.0*(qx*qz+qw*qy);
    Rh[1][0]=2.0*(qx*qy+qw*qz);       Rh[1][1]=qw*qw-qx*qx+qy*qy-qz*qz; Rh[1][2]=2.0*(qy*qz-qw*qx);
    Rh[2][0]=2.0*(qx*qz-qw*qy);       Rh[2][1]=2.0*(qy*qz+qw*qx);       Rh[2][2]=qw*qw-qx*qx-qy*qy+qz*qz;
    double objT=0.0, objN=0.0;
    for(int a=0;a<3;a++) for(int c=0;c<3;c++){ objT+=Rh[c][a]*Hm[a][c]; objN+=Rh[a][c]*Hm[a][c]; }
    double Rm[3][3];
    if(objT>=objN){
      for(int a=0;a<3;a++) for(int c=0;c<3;c++) Rm[a][c]=Rh[c][a];
    } else {
      for(int a=0;a<3;a++) for(int c=0;c<3;c++) Rm[a][c]=Rh[a][c];
    }
    double tt[3];
    for(int d=0;d<3;d++) tt[d]=c2[d] - (c1[0]*Rm[0][d]+c1[1]*Rm[1][d]+c1[2]*Rm[2][d]);
    const float* Rt = rot + b*9;
    double dsum=0.0;
    for(int a=0;a<3;a++) for(int c=0;c<3;c++){
      double dd = Rm[a][c] - (double)Rt[c*3+a];
      dsum += dd*dd;
    }
    double dock = dsum/9.0;
    double tsum=0.0;
    for(int d=0;d<3;d++){
      double tref = -((double)trans[b*3+0]*(double)Rt[d*3+0]+(double)trans[b*3+1]*(double)Rt[d*3+1]+(double)trans[b*3+2]*(double)Rt[d*3+2]);
      double dd = tt[d]-tref;
      tsum += dd*dd;
    }
    dock += tsum/3.0;
    otb[b]=ot; dockb[b]=dock;
    for(int a=0;a<3;a++) for(int d=0;d<3;d++) Rs[a*3+d]=Rm[a][d];
    for(int d=0;d<3;d++) ts[d]=tt[d];
  }
  __syncthreads();
  double part=0.0;
  for(int nidx=tid; nidx<NPP; nidx+=256){
    int i = b*2*NPP + nidx;
    double p0=Xca[i*3], p1=Xca[i*3+1], p2=Xca[i*3+2];
    double q0=p0*Rs[0]+p1*Rs[3]+p2*Rs[6]+ts[0];
    double q1=p0*Rs[1]+p1*Rs[4]+p2*Rs[7]+ts[1];
    double q2=p0*Rs[2]+p1*Rs[5]+p2*Rs[8]+ts[2];
    int o=(b*NPP+nidx)*3;
    x1a[o]=q0; x1a[o+1]=q1; x1a[o+2]=q2;
    double d0=q0-ori0[o], d1=q1-ori0[o+1], d2=q2-ori0[o+2];
    part += d0*d0+d1*d1+d2*d2;
  }
  red[tid]=part;
  __syncthreads();
  for(int st=128; st>0; st>>=1){ if(tid<st) red[tid]+=red[tid+st]; __syncthreads(); }
  if(tid==0) rmsdb[b]=red[0]/(double)(NPP*3);
}

// ------------------------------------------------------------------
// stab (f64): 1000 blocks, 8 rows x 32 lanes
// ------------------------------------------------------------------
__global__ __launch_bounds__(256) void k_stab(const double* __restrict__ x1a, const double* __restrict__ Xca,
    double* __restrict__ stabp){
  __shared__ double Bsm[NPP*3];
  __shared__ double red[8];
  int blk=blockIdx.x;
  int bd=blk/125, rg=blk%125;
  int b=bd>>1, dir=bd&1;
  int tid=threadIdx.x;
  const double* Ap = (dir==0) ? (x1a + (size_t)b*NPP*3) : (Xca + (size_t)(b*2+1)*NPP*3);
  const double* Bp = (dir==0) ? (Xca + (size_t)(b*2+1)*NPP*3) : (x1a + (size_t)b*NPP*3);
  for(int idx=tid; idx<NPP*3; idx+=256) Bsm[idx]=Bp[idx]*STDV;
  __syncthreads();
  int row = rg*8 + (tid>>5);
  int jt = tid&31;
  double a0=Ap[row*3]*STDV, a1=Ap[row*3+1]*STDV, a2=Ap[row*3+2]*STDV;
  double mind=1e300;
  for(int j=jt;j<NPP;j+=32){
    double d0=a0-Bsm[j*3], d1=a1-Bsm[j*3+1], d2=a2-Bsm[j*3+2];
    double d=d0*d0+d1*d1+d2*d2;
    mind=fmin(mind,d);
  }
  #pragma unroll
  for(int off=16;off>0;off>>=1) mind=fmin(mind,__shfl_xor(mind,off,32));
  double se=0.0;
  for(int j=jt;j<NPP;j+=32){
    double d0=a0-Bsm[j*3], d1=a1-Bsm[j*3+1], d2=a2-Bsm[j*3+2];
    double d=d0*d0+d1*d1+d2*d2;
    se += exp((mind-d)*(1.0/SIGC));
  }
  #pragma unroll
  for(int off=16;off>0;off>>=1) se += __shfl_xor(se,off,32);
  if(jt==0) red[tid>>5] = fmax(GAMC - mind + SIGC*log(se), 0.0);
  __syncthreads();
  if(tid==0){
    double s=0.0;
    #pragma unroll
    for(int i=0;i<8;i++) s+=red[i];
    stabp[blk]=s;
  }
}

__global__ void k_out(const double* __restrict__ otb, const double* __restrict__ dockb,
    const double* __restrict__ rmsdb, const double* __restrict__ stabp, float* __restrict__ out){
  if(blockIdx.x==0 && threadIdx.x==0){
    double ot=0.0,dock=0.0,rmsd=0.0,stab=0.0;
    for(int b=0;b<BSZ;b++){
      ot+=otb[b]; dock+=dockb[b]; rmsd+=rmsdb[b];
      double s1=0.0,s2=0.0;
      for(int i=0;i<125;i++){ s1+=stabp[(b*2+0)*125+i]; s2+=stabp[(b*2+1)*125+i]; }
      stab += (s1*(1.0/NPP) + s2*(1.0/NPP))*(1.0/STDV);
    }
    ot*=0.25; dock*=0.25; rmsd*=0.25; stab*=0.25;
    out[0]=(float)(ot+dock+stab); out[1]=(float)ot; out[2]=(float)dock; out[3]=(float)stab; out[4]=(float)rmsd;
  }
}

// ------------------------------------------------------------------
extern "C" void kernel_launch(void* const* d_in, const int* in_sizes, int n_in,
                              void* d_out, int out_size, void* d_ws, size_t ws_size,
                              hipStream_t stream){
  const float* X      = (const float*)d_in[0];
  const float* nodea  = (const float*)d_in[1];
  const float* edgea  = (const float*)d_in[2];
  const float* center = (const float*)d_in[3];
  const float* kpin   = (const float*)d_in[4];
  const float* rot    = (const float*)d_in[5];
  const float* trans  = (const float*)d_in[6];
  const float* W_in1  = (const float*)d_in[7];
  const float* b_in1  = (const float*)d_in[8];
  const float* W_in2  = (const float*)d_in[9];
  const float* b_in2  = (const float*)d_in[10];
  const float* msg_W  = (const float*)d_in[11];
  const float* msg_b  = (const float*)d_in[12];
  const float* upd_W1 = (const float*)d_in[13];
  const float* upd_b1 = (const float*)d_in[14];
  const float* upd_W2 = (const float*)d_in[15];
  const float* upd_b2 = (const float*)d_in[16];
  const float* x_W    = (const float*)d_in[17];
  const float* v_W    = (const float*)d_in[18];
  const float* att_W  = (const float*)d_in[19];
  const float* act_W1 = (const float*)d_in[20];
  const float* act_b1 = (const float*)d_in[21];
  const float* act_W2 = (const float*)d_in[22];
  const float* act_b2 = (const float*)d_in[23];
  const float* geb_Wv1= (const float*)d_in[24];
  const float* geb_Wv2= (const float*)d_in[25];
  const float* geb_W1 = (const float*)d_in[26];
  const float* geb_b1 = (const float*)d_in[27];
  const float* geb_W2 = (const float*)d_in[28];
  const float* geb_b2 = (const float*)d_in[29];
  const float* sc_W1  = (const float*)d_in[30];
  const float* sc_b1  = (const float*)d_in[31];
  const float* sc_W2  = (const float*)d_in[32];
  const float* sc_b2  = (const float*)d_in[33];
  const float* fin_W  = (const float*)d_in[34];
  const int*   src    = (const int*)d_in[35];
  const int*   dst    = (const int*)d_in[36];
  float* out = (float*)d_out;

  double* wd = (double*)d_ws;
  size_t o = 0;
  double* XcaD  = wd + o; o += (size_t)NN*3;
  double* ori0D = wd + o; o += (size_t)BSZ*NPP*3;
  double* kpcD  = wd + o; o += 144;
  double* tkpcD = wd + o; o += 144;
  double* dirvD = wd + o; o += (size_t)EE*3;
  double* rbfD  = wd + o; o += (size_t)EE*RBFD;
  double* hbuf  = wd + o; o += (size_t)NN*HD;
  double* Pbuf  = wd + o; o += (size_t)NN*256;
  double* mbuf  = wd + o; o += (size_t)EE*HD;
  double* va    = wd + o; o += (size_t)NN*HD*3;
  double* vb    = wd + o; o += (size_t)NN*HD*3;
  double* ubuf  = wd + o; o += (size_t)BSZ*2*HD;
  double* attp  = wd + o; o += (size_t)64*HD;
  double* nv2b  = wd + o; o += (size_t)NN*HD;
  double* sbuf  = wd + o; o += (size_t)NN*256;
  double* cbbD  = wd + o; o += 24;
  double* ypartD= wd + o; o += (size_t)4000*37;
  double* YbufD = wd + o; o += 8*36;
  double* x1aD  = wd + o; o += (size_t)BSZ*NPP*3;
  double* otb_  = wd + o; o += 4;
  double* dkb_  = wd + o; o += 4;
  double* rmb_  = wd + o; o += 4;
  double* stp_  = wd + o; o += 1000;
  double* Wnode = wd + o; o += (size_t)4*128*256;
  double* Wedge2= wd + o; o += (size_t)4*37*128;
  double* xvW   = wd + o; o += (size_t)4*128*256;

  double* h2b  = Pbuf + (size_t)NN*HD;   // overlays upper half of P (dead after edgemsg)

  size_t need = o*8;
  if(ws_size < need){
    float mb = (float)((double)ws_size / 1.0e6);
    float val = (131072.0f + mb) * 1048576.0f;
    k_sent<<<1,64,0,stream>>>(out, val);
    return;
  }

  hipMemsetAsync(va, 0, (size_t)NN*HD*3*sizeof(double), stream);

  k_cvt_node<<<512,256,0,stream>>>(msg_W, Wnode);
  k_cvt_edge<<<74,256,0,stream>>>(msg_W, msg_b, Wedge2);
  k_cvt_xv<<<256,256,0,stream>>>(x_W, v_W, xvW);

  k_geom<<<32,256,0,stream>>>(X, center, kpin, rot, trans, XcaD, ori0D, kpcD, tkpcD);
  k_edge<<<(EE+255)/256,256,0,stream>>>(XcaD, src, dst, dirvD, rbfD);
  k_hinit<<<NN/4,256,0,stream>>>(nodea, W_in1, b_in1, W_in2, b_in2, hbuf);

  double* vcur = va;
  double* vnxt = vb;
  for(int l=0;l<NL;l++){
    const double* Wn  = Wnode  + (size_t)l*128*256;
    const double* We  = Wedge2 + (size_t)l*37*128;
    const double* xvl = xvW    + (size_t)l*128*256;
    const float* u1W = upd_W1 + (size_t)l*256*HD;
    const float* u1b = upd_b1 + (size_t)l*HD;
    const float* u2W = upd_W2 + (size_t)l*HD*HD;
    const float* u2b = upd_b2 + (size_t)l*HD;
    const float* aWl = att_W  + (size_t)l*HD*HD;
    const float* a1W = act_W1 + (size_t)l*HD*HD;
    const float* a1b = act_b1 + (size_t)l*HD;
    const float* a2W = act_W2 + (size_t)l*HD*HD;
    const float* a2b = act_b2 + (size_t)l*HD;

    k_nodeproj<<<NN/4,128,0,stream>>>(hbuf, Wn, Pbuf);
    k_edgemsg<<<EE/32,256,0,stream>>>(Pbuf, rbfD, edgea, src, dst, We, mbuf);
    k_upd<<<NN/4,128,0,stream>>>(hbuf, mbuf, u1W, u1b, u2W, u2b, h2b);
    k_vupd<<<NN/2,128,0,stream>>>(mbuf, vcur, dirvD, src, xvl, vnxt);
    k_att1<<<64,128,0,stream>>>(h2b, attp);
    k_att2<<<8,128,0,stream>>>(attp, aWl, ubuf);
    k_actcomb<<<NN/4,128,0,stream>>>(h2b, ubuf, a1W, a1b, a2W, a2b, hbuf);
    double* tmp=vcur; vcur=vnxt; vnxt=tmp;
  }
  // vcur == va (final v), vnxt == vb (free -> v1)
  k_gebv<<<NN/2,256,0,stream>>>(vcur, geb_Wv1, geb_Wv2, vnxt, nv2b);
  k_gebs<<<NN/4,256,0,stream>>>(hbuf, nv2b, geb_W1, geb_b1, geb_W2, geb_b2, sbuf);
  k_kpc<<<8,256,0,stream>>>(XcaD, cbbD);
  k_kpgen<<<NN/2,256,0,stream>>>(XcaD, sbuf, vnxt, cbbD, fin_W, sc_W1, sc_b1, sc_W2, sc_b2, ypartD);
  k_kpfin<<<8,64,0,stream>>>(ypartD, cbbD, YbufD);
  k_final<<<BSZ,256,0,stream>>>(YbufD, tkpcD, kpcD, rot, trans, XcaD, ori0D, x1aD, otb_, dkb_, rmb_);
  k_stab<<<1000,256,0,stream>>>(x1aD, XcaD, stp_);
  k_out<<<1,64,0,stream>>>(otb_, dkb_, rmb_, stp_, out);
}

// Round 12
// 1592.583 us; speedup vs baseline: 1.4774x; 1.4774x over previous
//
#include <hip/hip_runtime.h>
#include <math.h>

#define NPP 1000
#define BSZ 4
#define HD 128
#define NL 4
#define RBFD 20
#define EDD 16
#define KN 9
#define NKPP 12
#define NN 8000
#define EE 72000
#define STDV 10.0
#define SIGC 25.0
#define GAMC 10.0
#define PID 3.14159265358979323846

__device__ __forceinline__ double silud(double x){ return x / (1.0 + exp(-x)); }

__global__ void k_sent(float* __restrict__ out, float val){
  if(threadIdx.x<5 && blockIdx.x==0) out[threadIdx.x]=val;
}

// ------------------------------------------------------------------
// weight preconversion to f64
// ------------------------------------------------------------------
__global__ __launch_bounds__(256) void k_cvt_node(const float* __restrict__ msgW, double* __restrict__ Wn){
  int idx = blockIdx.x*256+threadIdx.x;
  if(idx >= 4*128*256) return;
  int l = idx>>15; int r = idx & 32767; int k = r>>8; int j = r&255;
  const float* W = msgW + (size_t)l*292*128;
  Wn[idx] = (j<128) ? (double)W[k*128+j] : (double)W[(128+k)*128 + (j-128)];
}
__global__ __launch_bounds__(256) void k_cvt_edge(const float* __restrict__ msgW, const float* __restrict__ msgb,
    double* __restrict__ We){
  int idx = blockIdx.x*256+threadIdx.x;
  if(idx >= 4*37*128) return;
  int l = idx/(37*128); int r = idx%(37*128); int k = r>>7; int j = r&127;
  if(k<36) We[idx] = (double)msgW[(size_t)l*292*128 + (256+k)*128 + j];
  else     We[idx] = (double)msgb[l*128 + j];
}
__global__ __launch_bounds__(256) void k_cvt_xv(const float* __restrict__ xW, const float* __restrict__ vW,
    double* __restrict__ xv){
  int idx = blockIdx.x*256+threadIdx.x;
  if(idx >= 4*128*128) return;
  int l = idx>>14; int r = idx & 16383; int hh = r>>7; int c = r&127;
  xv[(size_t)l*32768 + hh*256 + 2*c]   = (double)xW[(size_t)l*16384 + hh*128 + c];
  xv[(size_t)l*32768 + hh*256 + 2*c+1] = (double)vW[(size_t)l*16384 + hh*128 + c];
}

// ------------------------------------------------------------------
// geometry (f64)
// ------------------------------------------------------------------
__global__ __launch_bounds__(256) void k_geom(const float* __restrict__ X, const float* __restrict__ center,
    const float* __restrict__ kpin, const float* __restrict__ rot, const float* __restrict__ trans,
    double* __restrict__ Xca, double* __restrict__ ori0, double* __restrict__ kpc, double* __restrict__ tkpc){
  int i = blockIdx.x*256 + threadIdx.x;
  const double inv = 1.0/STDV;
  if(i < NN){
    int b = i / (2*NPP);
    int s = (i / NPP) & 1;
    int n = i % NPP;
    double q0 = (double)X[i*12+3] - (double)center[b*3+0];
    double q1 = (double)X[i*12+4] - (double)center[b*3+1];
    double q2 = (double)X[i*12+5] - (double)center[b*3+2];
    if(s==0){
      int o=(b*NPP+n)*3;
      ori0[o]=q0*inv; ori0[o+1]=q1*inv; ori0[o+2]=q2*inv;
      const float* R = rot + b*9;
      #pragma unroll
      for(int d=0; d<3; d++)
        Xca[i*3+d] = (q0*(double)R[d] + q1*(double)R[3+d] + q2*(double)R[6+d])*inv + (double)trans[b*3+d];
    } else {
      Xca[i*3+0]=q0*inv; Xca[i*3+1]=q1*inv; Xca[i*3+2]=q2*inv;
    }
  } else if(i < NN + BSZ*NKPP){
    int j = i - NN;
    int b = j / NKPP;
    double q0 = (double)kpin[j*3+0]-(double)center[b*3+0];
    double q1 = (double)kpin[j*3+1]-(double)center[b*3+1];
    double q2 = (double)kpin[j*3+2]-(double)center[b*3+2];
    kpc[j*3+0]=q0*inv; kpc[j*3+1]=q1*inv; kpc[j*3+2]=q2*inv;
    const float* R = rot + b*9;
    #pragma unroll
    for(int d=0; d<3; d++)
      tkpc[j*3+d] = (q0*(double)R[d] + q1*(double)R[3+d] + q2*(double)R[6+d])*inv + (double)trans[b*3+d];
  }
}

// ------------------------------------------------------------------
__global__ __launch_bounds__(256) void k_edge(const double* __restrict__ Xca, const int* __restrict__ src,
    const int* __restrict__ dst, double* __restrict__ dirv, double* __restrict__ rbfb){
  int e = blockIdx.x*256 + threadIdx.x;
  if(e >= EE) return;
  int sp = src[e], dp = dst[e];
  double d0 = Xca[dp*3+0]-Xca[sp*3+0];
  double d1 = Xca[dp*3+1]-Xca[sp*3+1];
  double d2 = Xca[dp*3+2]-Xca[sp*3+2];
  double nr = sqrt(d0*d0+d1*d1+d2*d2) + 1e-08;
  double iv = 1.0/nr;
  dirv[e*3+0]=d0*iv; dirv[e*3+1]=d1*iv; dirv[e*3+2]=d2*iv;
  #pragma unroll
  for(int j=0;j<RBFD;j++)
    rbfb[e*RBFD+j] = sin(nr*(double)(j+1)*PID)*iv;
}

// ------------------------------------------------------------------
// h init: 4 nodes/block, 256 thr
// ------------------------------------------------------------------
__global__ __launch_bounds__(256) void k_hinit(const float* __restrict__ na,
    const float* __restrict__ W1, const float* __restrict__ b1,
    const float* __restrict__ W2, const float* __restrict__ b2, double* __restrict__ h){
  __shared__ double cin[4][64];
  __shared__ double hmid[4][128];
  int n0 = blockIdx.x*4;
  int tid = threadIdx.x;
  {
    int r=tid>>6, k=tid&63;
    cin[r][k] = (double)na[(n0+r)*64 + k];
  }
  __syncthreads();
  int r = tid>>6, c0 = (tid&63)*2;
  double a0=(double)b1[c0], a1=(double)b1[c0+1];
  for(int k=0;k<64;k++){
    double a = cin[r][k];
    const float* wp = W1 + k*HD + c0;
    a0 += a*(double)wp[0]; a1 += a*(double)wp[1];
  }
  hmid[r][c0]=silud(a0); hmid[r][c0+1]=silud(a1);
  __syncthreads();
  double s0=(double)b2[c0], s1=(double)b2[c0+1];
  for(int k=0;k<HD;k++){
    double a = hmid[r][k];
    const float* wp = W2 + k*HD + c0;
    s0 += a*(double)wp[0]; s1 += a*(double)wp[1];
  }
  h[(size_t)(n0+r)*HD+c0]=s0; h[(size_t)(n0+r)*HD+c0+1]=s1;
}

// ------------------------------------------------------------------
// node projection: 4 nodes/block, 128 thr, col=tid*2, 4-node accum
// ------------------------------------------------------------------
__global__ __launch_bounds__(128) void k_nodeproj(const double* __restrict__ h, const double* __restrict__ Wn,
    double* __restrict__ P){
  __shared__ double cin[4][128];
  int n0 = blockIdx.x*4;
  int tid = threadIdx.x;
  for(int idx=tid; idx<512; idx+=128){
    int r=idx>>7, k=idx&127;
    cin[r][k]=h[(size_t)(n0+r)*HD+k];
  }
  __syncthreads();
  int c0 = tid*2;
  double a00=0,a01=0,a10=0,a11=0,a20=0,a21=0,a30=0,a31=0;
  for(int k=0;k<128;k++){
    double2 w = *(const double2*)(Wn + (size_t)k*256 + c0);
    double x0=cin[0][k],x1=cin[1][k],x2=cin[2][k],x3=cin[3][k];
    a00+=x0*w.x; a01+=x0*w.y; a10+=x1*w.x; a11+=x1*w.y;
    a20+=x2*w.x; a21+=x2*w.y; a30+=x3*w.x; a31+=x3*w.y;
  }
  P[(size_t)(n0+0)*256+c0]=a00; P[(size_t)(n0+0)*256+c0+1]=a01;
  P[(size_t)(n0+1)*256+c0]=a10; P[(size_t)(n0+1)*256+c0+1]=a11;
  P[(size_t)(n0+2)*256+c0]=a20; P[(size_t)(n0+2)*256+c0+1]=a21;
  P[(size_t)(n0+3)*256+c0]=a30; P[(size_t)(n0+3)*256+c0+1]=a31;
}

// ------------------------------------------------------------------
// edge message: m[e] = silu( P[src][0:128] + P[dst][128:256] + feat(e)@Wedge2 )
// ------------------------------------------------------------------
__global__ __launch_bounds__(256) void k_edgemsg(const double* __restrict__ P, const double* __restrict__ rbfb,
    const float* __restrict__ ea, const int* __restrict__ src, const int* __restrict__ dst,
    const double* __restrict__ We, double* __restrict__ m){
  __shared__ double feat[32][41];
  __shared__ int ssi[32], ddi[32];
  int e0 = blockIdx.x*32;
  int tid = threadIdx.x;
  for(int idx=tid; idx<32*RBFD; idx+=256){
    int e=idx/RBFD, k=idx%RBFD;
    feat[e][k]=rbfb[(size_t)(e0+e)*RBFD+k];
  }
  for(int idx=tid; idx<32*EDD; idx+=256){
    int e=idx>>4, k=idx&15;
    feat[e][20+k]=(double)ea[(size_t)(e0+e)*EDD+k];
  }
  if(tid<32){ feat[tid][36]=1.0; ssi[tid]=src[e0+tid]; ddi[tid]=dst[e0+tid]; }
  __syncthreads();
  int t = tid&15, g = tid>>4;
  int j0 = g*8;
  double acc0[8], acc1[8];
  #pragma unroll
  for(int j=0;j<8;j++){ acc0[j]=0.0; acc1[j]=0.0; }
  for(int k=0;k<37;k++){
    const double* wp = We + (size_t)k*128 + j0;
    double a0 = feat[t][k], a1 = feat[t+16][k];
    #pragma unroll
    for(int j=0;j<8;j++){ double w=wp[j]; acc0[j]+=a0*w; acc1[j]+=a1*w; }
  }
  {
    const double* p1 = P + (size_t)ssi[t]*256 + j0;
    const double* p2 = P + (size_t)ddi[t]*256 + 128 + j0;
    double* mr = m + (size_t)(e0+t)*HD + j0;
    #pragma unroll
    for(int j=0;j<8;j++) mr[j] = silud(acc0[j]+p1[j]+p2[j]);
  }
  {
    const double* p1 = P + (size_t)ssi[t+16]*256 + j0;
    const double* p2 = P + (size_t)ddi[t+16]*256 + 128 + j0;
    double* mr = m + (size_t)(e0+t+16)*HD + j0;
    #pragma unroll
    for(int j=0;j<8;j++) mr[j] = silud(acc1[j]+p1[j]+p2[j]);
  }
}

// ------------------------------------------------------------------
// intra = h + silu([h,agg]@W1+b1)@W2+b2 ; agg fused (9-row m sum)
// 4 nodes/block, 128 thr, col=tid, 4-node accum
// ------------------------------------------------------------------
__global__ __launch_bounds__(128) void k_upd(const double* __restrict__ h, const double* __restrict__ m,
    const float* __restrict__ W1, const float* __restrict__ b1,
    const float* __restrict__ W2, const float* __restrict__ b2, double* __restrict__ h2){
  __shared__ double cin[4][256];
  __shared__ double hmid[4][128];
  int n0 = blockIdx.x*4;
  int tid = threadIdx.x;
  for(int idx=tid; idx<4*128; idx+=128){
    int r=idx>>7, k=idx&127;
    cin[r][k] = h[(size_t)(n0+r)*HD+k];
    const double* mp = m + ((size_t)(n0+r)*KN)*HD + k;
    double s=0.0;
    #pragma unroll
    for(int kk=0;kk<KN;kk++) s += mp[(size_t)kk*HD];
    cin[r][128+k]=s;
  }
  __syncthreads();
  int col = tid;
  double bb=(double)b1[col];
  double a0=bb,a1=bb,a2=bb,a3=bb;
  for(int k=0;k<256;k++){
    double w = (double)W1[(size_t)k*HD+col];
    a0 += cin[0][k]*w; a1 += cin[1][k]*w; a2 += cin[2][k]*w; a3 += cin[3][k]*w;
  }
  hmid[0][col]=silud(a0); hmid[1][col]=silud(a1); hmid[2][col]=silud(a2); hmid[3][col]=silud(a3);
  __syncthreads();
  bb=(double)b2[col];
  a0=bb;a1=bb;a2=bb;a3=bb;
  for(int k=0;k<128;k++){
    double w = (double)W2[(size_t)k*HD+col];
    a0 += hmid[0][k]*w; a1 += hmid[1][k]*w; a2 += hmid[2][k]*w; a3 += hmid[3][k]*w;
  }
  h2[(size_t)(n0+0)*HD+col] = cin[0][col]+a0;
  h2[(size_t)(n0+1)*HD+col] = cin[1][col]+a1;
  h2[(size_t)(n0+2)*HD+col] = cin[2][col]+a2;
  h2[(size_t)(n0+3)*HD+col] = cin[3][col]+a3;
}

// ------------------------------------------------------------------
// fused v update: 4 nodes/block, 256 thr; wave = node (nd=tid>>6 uniform
// per wave -> LDS broadcasts); each thread does 2 adjacent cols ->
// 12 LDS reads feed 24 FMAs (halved LDS traffic per FMA vs round 9)
// ------------------------------------------------------------------
__global__ __launch_bounds__(256) void k_vupd(const double* __restrict__ m, const double* __restrict__ va,
    const double* __restrict__ dirv, const int* __restrict__ src,
    const double* __restrict__ xv, double* __restrict__ vb){
  __shared__ double mT[4][9][128];
  __shared__ double md[4][3][128];
  __shared__ double dv[4][9][3];
  __shared__ int sp[4][9];
  int n0 = blockIdx.x*4;
  int tid = threadIdx.x;
  for(int idx=tid; idx<4*9*128; idx+=256){
    int hh=idx&127, t=idx>>7; int nd=t/9, kk=t-nd*9;
    mT[nd][kk][hh] = m[((size_t)(n0+nd)*KN + kk)*HD + hh];
  }
  if(tid<36){
    int nd=tid/9, kk=tid-nd*9;
    int e=(n0+nd)*KN+kk;
    sp[nd][kk]=src[e];
    dv[nd][kk][0]=dirv[e*3]; dv[nd][kk][1]=dirv[e*3+1]; dv[nd][kk][2]=dirv[e*3+2];
  }
  __syncthreads();
  for(int idx=tid; idx<4*3*128; idx+=256){
    int hh=idx&127, t=idx>>7; int nd=t/3, c=t-nd*3;
    double s=0.0;
    #pragma unroll
    for(int kk=0;kk<9;kk++) s += dv[nd][kk][c]*mT[nd][kk][hh];
    md[nd][c][hh]=s;
  }
  __syncthreads();
  int nd = tid>>6;            // wave-uniform
  int t  = tid&63;
  int c0 = 2*t;               // cols c0, c0+1
  double oA0=0,oA1=0,oA2=0, oB0=0,oB1=0,oB2=0;
  double mvA[9], mvB[9];
  #pragma unroll
  for(int kk=0;kk<9;kk++){ mvA[kk]=0.0; mvB[kk]=0.0; }
  for(int hh=0; hh<128; hh++){
    const double* xp = xv + (size_t)hh*256 + 2*c0;
    double2 wpA = *(const double2*)(xp);      // col c0: (x,v)
    double2 wpB = *(const double2*)(xp+2);    // col c0+1: (x,v)
    double d0 = md[nd][0][hh], d1 = md[nd][1][hh], d2 = md[nd][2][hh];
    oA0 += d0*wpA.x; oA1 += d1*wpA.x; oA2 += d2*wpA.x;
    oB0 += d0*wpB.x; oB1 += d1*wpB.x; oB2 += d2*wpB.x;
    #pragma unroll
    for(int kk=0;kk<9;kk++){
      double mk = mT[nd][kk][hh];
      mvA[kk] += mk*wpA.y;
      mvB[kk] += mk*wpB.y;
    }
  }
  #pragma unroll
  for(int kk=0;kk<9;kk++){
    size_t s3 = (size_t)sp[nd][kk]*384 + c0*3;
    double ka = mvA[kk], kb = mvB[kk];
    oA0 += va[s3]*ka;   oA1 += va[s3+1]*ka; oA2 += va[s3+2]*ka;
    oB0 += va[s3+3]*kb; oB1 += va[s3+4]*kb; oB2 += va[s3+5]*kb;
  }
  size_t b3 = (size_t)(n0+nd)*384 + c0*3;
  vb[b3]  = va[b3]  + oA0;
  vb[b3+1]= va[b3+1]+ oA1;
  vb[b3+2]= va[b3+2]+ oA2;
  vb[b3+3]= va[b3+3]+ oB0;
  vb[b3+4]= va[b3+4]+ oB1;
  vb[b3+5]= va[b3+5]+ oB2;
}

// ------------------------------------------------------------------
// attention partials + finish
// ------------------------------------------------------------------
__global__ __launch_bounds__(128) void k_att1(const double* __restrict__ h2, double* __restrict__ partial){
  int blk = blockIdx.x;
  int bs = blk>>3, ch = blk&7;
  int col = threadIdx.x;
  size_t base = ((size_t)bs*NPP + ch*125)*HD + col;
  double s=0.0;
  for(int i=0;i<125;i++) s += h2[base + (size_t)i*HD];
  partial[(size_t)blk*HD + col] = s;
}
__global__ __launch_bounds__(128) void k_att2(const double* __restrict__ partial, const float* __restrict__ attW,
    double* __restrict__ u){
  __shared__ double mm[128];
  int bs = blockIdx.x;
  int col = threadIdx.x;
  int os = bs^1;
  double s=0.0;
  for(int c=0;c<8;c++) s += partial[(size_t)(os*8+c)*HD + col];
  mm[col] = s*(1.0/NPP);
  __syncthreads();
  double acc=0.0;
  for(int k=0;k<HD;k++) acc += (double)attW[col*HD+k]*mm[k];
  u[bs*HD+col] = acc;
}

// ------------------------------------------------------------------
// h_new = intra + g*act(intra), g fused
// ------------------------------------------------------------------
__global__ __launch_bounds__(128) void k_actcomb(const double* __restrict__ h2, const double* __restrict__ u,
    const float* __restrict__ W1, const float* __restrict__ b1,
    const float* __restrict__ W2, const float* __restrict__ b2, double* __restrict__ h){
  __shared__ double As[4][128];
  __shared__ double hmid[4][128];
  __shared__ double pd[128];
  __shared__ double gsh[4];
  int n0 = blockIdx.x*4;
  int tid = threadIdx.x;
  int bs = n0/NPP;
  for(int idx=tid; idx<512; idx+=128){
    int r=idx>>7, k=idx&127;
    As[r][k] = h2[(size_t)(n0+r)*HD+k];
  }
  __syncthreads();
  {
    int nd=tid>>5, q=tid&31;
    double p=0.0;
    for(int j=q;j<128;j+=32) p += As[nd][j]*u[bs*HD+j];
    pd[tid]=p;
  }
  __syncthreads();
  if((tid&31)==0){
    int nd=tid>>5;
    double s=0.0;
    for(int i2=0;i2<32;i2++) s+=pd[nd*32+i2];
    gsh[nd]=1.0/(1.0+exp(-s));
  }
  __syncthreads();
  int col = tid;
  double bb=(double)b1[col];
  double a0=bb,a1=bb,a2=bb,a3=bb;
  for(int k=0;k<128;k++){
    double w = (double)W1[(size_t)k*HD+col];
    a0 += As[0][k]*w; a1 += As[1][k]*w; a2 += As[2][k]*w; a3 += As[3][k]*w;
  }
  hmid[0][col]=silud(a0); hmid[1][col]=silud(a1); hmid[2][col]=silud(a2); hmid[3][col]=silud(a3);
  __syncthreads();
  bb=(double)b2[col];
  a0=bb;a1=bb;a2=bb;a3=bb;
  for(int k=0;k<128;k++){
    double w = (double)W2[(size_t)k*HD+col];
    a0 += hmid[0][k]*w; a1 += hmid[1][k]*w; a2 += hmid[2][k]*w; a3 += hmid[3][k]*w;
  }
  h[(size_t)(n0+0)*HD+col] = As[0][col] + gsh[0]*a0;
  h[(size_t)(n0+1)*HD+col] = As[1][col] + gsh[1]*a1;
  h[(size_t)(n0+2)*HD+col] = As[2][col] + gsh[2]*a2;
  h[(size_t)(n0+3)*HD+col] = As[3][col] + gsh[3]*a3;
}

// ------------------------------------------------------------------
// geb vector branch
// ------------------------------------------------------------------
__global__ __launch_bounds__(256) void k_gebv(const double* __restrict__ va,
    const float* __restrict__ Wv1, const float* __restrict__ Wv2,
    double* __restrict__ v1, double* __restrict__ nv2){
  __shared__ double vl[2][384];
  int n0 = blockIdx.x*2;
  int tid = threadIdx.x;
  for(int idx=tid; idx<768; idx+=256){
    int r=idx/384, k=idx%384;
    vl[r][k] = va[(size_t)(n0+r)*384+k];
  }
  __syncthreads();
  int r = tid>>7, col = tid&127;
  double a10=0.0,a11=0.0,a12=0.0, a20=0.0,a21=0.0,a22=0.0;
  for(int hh=0; hh<HD; hh++){
    double w1 = (double)Wv1[hh*HD+col];
    double w2 = (double)Wv2[hh*HD+col];
    double v0=vl[r][hh*3], v1e=vl[r][hh*3+1], v2e=vl[r][hh*3+2];
    a10+=v0*w1; a11+=v1e*w1; a12+=v2e*w1;
    a20+=v0*w2; a21+=v1e*w2; a22+=v2e*w2;
  }
  size_t b3=(size_t)(n0+r)*384+col*3;
  v1[b3]=a10; v1[b3+1]=a11; v1[b3+2]=a12;
  nv2[(size_t)(n0+r)*HD+col]=sqrt(a20*a20+a21*a21+a22*a22);
}

// ------------------------------------------------------------------
// s = silu([h,nv2]@gebW1+b1)@gebW2+b2
// ------------------------------------------------------------------
__global__ __launch_bounds__(256) void k_gebs(const double* __restrict__ h, const double* __restrict__ nv2,
    const float* __restrict__ W1, const float* __restrict__ b1,
    const float* __restrict__ W2, const float* __restrict__ b2, double* __restrict__ s){
  __shared__ double cin[4][256];
  __shared__ double hmid[4][128];
  int n0 = blockIdx.x*4;
  int tid = threadIdx.x;
  for(int idx=tid; idx<4*HD; idx+=256){
    int r=idx>>7, k=idx&127;
    cin[r][k]    = h[(size_t)(n0+r)*HD + k];
    cin[r][HD+k] = nv2[(size_t)(n0+r)*HD + k];
  }
  __syncthreads();
  int r = tid>>6, c0 = (tid&63)*2;
  double a0=(double)b1[c0], a1=(double)b1[c0+1];
  for(int k=0;k<2*HD;k++){
    double a = cin[r][k];
    const float* wp = W1 + (size_t)k*HD + c0;
    a0 += a*(double)wp[0]; a1 += a*(double)wp[1];
  }
  hmid[r][c0]=silud(a0); hmid[r][c0+1]=silud(a1);
  __syncthreads();
  int c1 = (tid&63)*4;
  double s0=(double)b2[c1], s1=(double)b2[c1+1], s2=(double)b2[c1+2], s3=(double)b2[c1+3];
  for(int k=0;k<HD;k++){
    double a = hmid[r][k];
    const float* wp = W2 + (size_t)k*256 + c1;
    s0 += a*(double)wp[0]; s1 += a*(double)wp[1]; s2 += a*(double)wp[2]; s3 += a*(double)wp[3];
  }
  double* srow = s + (size_t)(n0+r)*256 + c1;
  srow[0]=s0; srow[1]=s1; srow[2]=s2; srow[3]=s3;
}

// ------------------------------------------------------------------
__global__ __launch_bounds__(256) void k_kpc(const double* __restrict__ Xca, double* __restrict__ cbb){
  __shared__ double red[768];
  int bs = blockIdx.x;
  int tid = threadIdx.x;
  double s0=0.0,s1=0.0,s2=0.0;
  for(int nidx=tid; nidx<NPP; nidx+=256){
    int i = bs*NPP+nidx;
    s0+=Xca[i*3]; s1+=Xca[i*3+1]; s2+=Xca[i*3+2];
  }
  red[tid]=s0; red[256+tid]=s1; red[512+tid]=s2;
  __syncthreads();
  for(int st=128; st>0; st>>=1){
    if(tid<st){ red[tid]+=red[tid+st]; red[256+tid]+=red[256+tid+st]; red[512+tid]+=red[512+tid+st]; }
    __syncthreads();
  }
  if(tid==0){ cbb[bs*3]=red[0]*(1.0/NPP); cbb[bs*3+1]=red[256]*(1.0/NPP); cbb[bs*3+2]=red[512]*(1.0/NPP); }
}

// ------------------------------------------------------------------
// keypoint partials: 2 nodes/block
// ------------------------------------------------------------------
__global__ __launch_bounds__(256) void k_kpgen(const double* __restrict__ Xca, const double* __restrict__ sbuf,
    const double* __restrict__ v1, const double* __restrict__ cbb, const float* __restrict__ fW,
    const float* __restrict__ sW1, const float* __restrict__ sb1, const float* __restrict__ sW2,
    const float* __restrict__ sb2, double* __restrict__ ypart){
  __shared__ double tt[2][3][128];
  __shared__ double ssv[2][128];
  __shared__ double zz[2][64];
  __shared__ double snorm[2];
  __shared__ double ylL[2][37];
  int blk = blockIdx.x;
  int tid = threadIdx.x;
  int r = tid>>7, t = tid&127;
  int n = blk*2 + r;
  int bs = n/NPP;
  const double* srow = sbuf + (size_t)n*256;
  const double* vrow = v1 + (size_t)n*384;
  double gate = srow[128+t];
  double hp = srow[t];
  double vf0 = vrow[t*3+0]*gate, vf1 = vrow[t*3+1]*gate, vf2 = vrow[t*3+2]*gate;
  tt[r][0][t]=vf0*hp; tt[r][1][t]=vf1*hp; tt[r][2][t]=vf2*hp;
  ssv[r][t]=sqrt(vf0*vf0+vf1*vf1+vf2*vf2);
  if(t==0){
    double x0=Xca[n*3]-cbb[bs*3], x1=Xca[n*3+1]-cbb[bs*3+1], x2=Xca[n*3+2]-cbb[bs*3+2];
    snorm[r]=sqrt(x0*x0+x1*x1+x2*x2);
  }
  __syncthreads();
  if(t<36){
    int k2=t/3, c=t%3;
    double a=0.0;
    for(int hh=0; hh<128; hh++) a += tt[r][c][hh]*(double)fW[hh*NKPP+k2];
    ylL[r][t]=a;
  } else if(t>=64){
    int j=t-64;
    double z=(double)sb1[j];
    for(int hh=0; hh<128; hh++) z += ssv[r][hh]*(double)sW1[hh*64+j];
    z += snorm[r]*(double)sW1[128*64+j];
    zz[r][j]=silud(z)*(double)sW2[j];
  }
  __syncthreads();
  if(t==36){
    double dn=(double)sb2[0];
    for(int j=0;j<64;j++) dn+=zz[r][j];
    ylL[r][36]=dn;
  }
  __syncthreads();
  if(tid<37) ypart[(size_t)blk*37+tid]=ylL[0][tid]+ylL[1][tid];
}

__global__ __launch_bounds__(64) void k_kpfin(const double* __restrict__ ypart,
    const double* __restrict__ cbb, double* __restrict__ Y){
  __shared__ double sums[37];
  int bs=blockIdx.x, tid=threadIdx.x;
  if(tid<37){
    double s=0.0;
    for(int i=0;i<500;i++) s += ypart[(size_t)(bs*500+i)*37 + tid];
    sums[tid]=s;
  }
  __syncthreads();
  if(tid<36){
    double dsh = sums[36]*(1.0/NPP);
    Y[bs*36+tid] = sums[tid]/dsh + cbb[bs*3 + tid%3];
  }
}

// ------------------------------------------------------------------
// per-sample: ot, Kabsch (Horn quaternion), dock, rmsd, X1a
// ------------------------------------------------------------------
__global__ __launch_bounds__(256) void k_final(const double* __restrict__ Y, const double* __restrict__ tkpc,
    const double* __restrict__ kpc, const float* __restrict__ rot, const float* __restrict__ trans,
    const double* __restrict__ Xca, const double* __restrict__ ori0,
    double* __restrict__ x1a, double* __restrict__ otb, double* __restrict__ dockb, double* __restrict__ rmsdb){
  int b = blockIdx.x;
  int tid = threadIdx.x;
  __shared__ double Rs[9];
  __shared__ double ts[3];
  __shared__ double red[256];
  if(tid==0){
    const double* Y1 = Y + (b*2+0)*36;
    const double* Y2 = Y + (b*2+1)*36;
    const double* P1 = tkpc + b*36;
    const double* P2 = kpc + b*36;
    double ot1=0.0, ot2=0.0;
    for(int i=0;i<12;i++){
      double best1=1e300, best2=1e300;
      for(int j=0;j<12;j++){
        double d1=0.0, d2=0.0;
        #pragma unroll
        for(int c=0;c<3;c++){
          double e1=Y1[i*3+c]-P1[j*3+c]; d1+=e1*e1;
          double e2=Y2[i*3+c]-P2[j*3+c]; d2+=e2*e2;
        }
        best1=fmin(best1,d1); best2=fmin(best2,d2);
      }
      ot1+=best1; ot2+=best2;
    }
    double ot = ot1*(1.0/36.0) + ot2*(1.0/36.0);
    double c1[3]={0,0,0}, c2[3]={0,0,0};
    for(int i=0;i<12;i++)
      for(int c=0;c<3;c++){ c1[c]+=Y1[i*3+c]; c2[c]+=Y2[i*3+c]; }
    for(int c=0;c<3;c++){ c1[c]/=12.0; c2[c]/=12.0; }
    double Hm[3][3]={{0,0,0},{0,0,0},{0,0,0}};
    for(int i=0;i<12;i++)
      for(int a=0;a<3;a++)
        for(int c=0;c<3;c++)
          Hm[a][c] += (Y1[i*3+a]-c1[a])*(Y2[i*3+c]-c2[c]);
    double Sxx=Hm[0][0],Sxy=Hm[0][1],Sxz=Hm[0][2];
    double Syx=Hm[1][0],Syy=Hm[1][1],Syz=Hm[1][2];
    double Szx=Hm[2][0],Szy=Hm[2][1],Szz=Hm[2][2];
    double K[4][4];
    K[0][0]=Sxx+Syy+Szz; K[0][1]=Syz-Szy;     K[0][2]=Szx-Sxz;      K[0][3]=Sxy-Syx;
    K[1][0]=K[0][1];     K[1][1]=Sxx-Syy-Szz; K[1][2]=Sxy+Syx;      K[1][3]=Szx+Sxz;
    K[2][0]=K[0][2];     K[2][1]=K[1][2];     K[2][2]=-Sxx+Syy-Szz; K[2][3]=Syz+Szy;
    K[3][0]=K[0][3];     K[3][1]=K[1][3];     K[3][2]=K[2][3];      K[3][3]=-Sxx-Syy+Szz;
    double V[4][4]={{1,0,0,0},{0,1,0,0},{0,0,1,0},{0,0,0,1}};
    for(int sweep=0;sweep<30;sweep++){
      for(int p=0;p<3;p++) for(int q=p+1;q<4;q++){
        double apq=K[p][q];
        if(fabs(apq)<1e-300) continue;
        double tau=(K[q][q]-K[p][p])/(2.0*apq);
        double t=(tau>=0.0?1.0:-1.0)/(fabs(tau)+sqrt(tau*tau+1.0));
        double cs=1.0/sqrt(t*t+1.0), sn=t*cs;
        for(int r2=0;r2<4;r2++){
          double krp=K[r2][p], krq=K[r2][q];
          K[r2][p]=cs*krp - sn*krq;
          K[r2][q]=sn*krp + cs*krq;
        }
        for(int r2=0;r2<4;r2++){
          double kpr=K[p][r2], kqr=K[q][r2];
          K[p][r2]=cs*kpr - sn*kqr;
          K[q][r2]=sn*kpr + cs*kqr;
        }
        for(int r2=0;r2<4;r2++){
          double vrp=V[r2][p], vrq=V[r2][q];
          V[r2][p]=cs*vrp - sn*vrq;
          V[r2][q]=sn*vrp + cs*vrq;
        }
      }
    }
    int mi=0;
    for(int i2=1;i2<4;i2++) if(K[i2][i2]>K[mi][mi]) mi=i2;
    double qw=V[0][mi], qx=V[1][mi], qy=V[2][mi], qz=V[3][mi];
    double Rh[3][3];
    Rh[0][0]=qw*qw+qx*qx-qy*qy-qz*qz; Rh[0][1]=2.0*(qx*qy-qw*qz);       Rh[0][2]=2.0*(qx*qz+qw*qy);
    Rh[1][0]=2.0*(qx*qy+qw*qz);       Rh[1][1]=qw*qw-qx*qx+qy*qy-qz*qz; Rh[1][2]=2.0*(qy*qz-qw*qx);
    Rh[2][0]=2.0*(qx*qz-qw*qy);       Rh[2][1]=2.0*(qy*qz+qw*qx);       Rh[2][2]=qw*qw-qx*qx-qy*qy+qz*qz;
    double objT=0.0, objN=0.0;
    for(int a=0;a<3;a++) for(int c=0;c<3;c++){ objT+=Rh[c][a]*Hm[a][c]; objN+=Rh[a][c]*Hm[a][c]; }
    double Rm[3][3];
    if(objT>=objN){
      for(int a=0;a<3;a++) for(int c=0;c<3;c++) Rm[a][c]=Rh[c][a];
    } else {
      for(int a=0;a<3;a++) for(int c=0;c<3;c++) Rm[a][c]=Rh[a][c];
    }
    double tt[3];
    for(int d=0;d<3;d++) tt[d]=c2[d] - (c1[0]*Rm[0][d]+c1[1]*Rm[1][d]+c1[2]*Rm[2][d]);
    const float* Rt = rot + b*9;
    double dsum=0.0;
    for(int a=0;a<3;a++) for(int c=0;c<3;c++){
      double dd = Rm[a][c] - (double)Rt[c*3+a];
      dsum += dd*dd;
    }
    double dock = dsum/9.0;
    double tsum=0.0;
    for(int d=0;d<3;d++){
      double tref = -((double)trans[b*3+0]*(double)Rt[d*3+0]+(double)trans[b*3+1]*(double)Rt[d*3+1]+(double)trans[b*3+2]*(double)Rt[d*3+2]);
      double dd = tt[d]-tref;
      tsum += dd*dd;
    }
    dock += tsum/3.0;
    otb[b]=ot; dockb[b]=dock;
    for(int a=0;a<3;a++) for(int d=0;d<3;d++) Rs[a*3+d]=Rm[a][d];
    for(int d=0;d<3;d++) ts[d]=tt[d];
  }
  __syncthreads();
  double part=0.0;
  for(int nidx=tid; nidx<NPP; nidx+=256){
    int i = b*2*NPP + nidx;
    double p0=Xca[i*3], p1=Xca[i*3+1], p2=Xca[i*3+2];
    double q0=p0*Rs[0]+p1*Rs[3]+p2*Rs[6]+ts[0];
    double q1=p0*Rs[1]+p1*Rs[4]+p2*Rs[7]+ts[1];
    double q2=p0*Rs[2]+p1*Rs[5]+p2*Rs[8]+ts[2];
    int o=(b*NPP+nidx)*3;
    x1a[o]=q0; x1a[o+1]=q1; x1a[o+2]=q2;
    double d0=q0-ori0[o], d1=q1-ori0[o+1], d2=q2-ori0[o+2];
    part += d0*d0+d1*d1+d2*d2;
  }
  red[tid]=part;
  __syncthreads();
  for(int st=128; st>0; st>>=1){ if(tid<st) red[tid]+=red[tid+st]; __syncthreads(); }
  if(tid==0) rmsdb[b]=red[0]/(double)(NPP*3);
}

// ------------------------------------------------------------------
// stab (f64): 1000 blocks, 8 rows x 32 lanes
// ------------------------------------------------------------------
__global__ __launch_bounds__(256) void k_stab(const double* __restrict__ x1a, const double* __restrict__ Xca,
    double* __restrict__ stabp){
  __shared__ double Bsm[NPP*3];
  __shared__ double red[8];
  int blk=blockIdx.x;
  int bd=blk/125, rg=blk%125;
  int b=bd>>1, dir=bd&1;
  int tid=threadIdx.x;
  const double* Ap = (dir==0) ? (x1a + (size_t)b*NPP*3) : (Xca + (size_t)(b*2+1)*NPP*3);
  const double* Bp = (dir==0) ? (Xca + (size_t)(b*2+1)*NPP*3) : (x1a + (size_t)b*NPP*3);
  for(int idx=tid; idx<NPP*3; idx+=256) Bsm[idx]=Bp[idx]*STDV;
  __syncthreads();
  int row = rg*8 + (tid>>5);
  int jt = tid&31;
  double a0=Ap[row*3]*STDV, a1=Ap[row*3+1]*STDV, a2=Ap[row*3+2]*STDV;
  double mind=1e300;
  for(int j=jt;j<NPP;j+=32){
    double d0=a0-Bsm[j*3], d1=a1-Bsm[j*3+1], d2=a2-Bsm[j*3+2];
    double d=d0*d0+d1*d1+d2*d2;
    mind=fmin(mind,d);
  }
  #pragma unroll
  for(int off=16;off>0;off>>=1) mind=fmin(mind,__shfl_xor(mind,off,32));
  double se=0.0;
  for(int j=jt;j<NPP;j+=32){
    double d0=a0-Bsm[j*3], d1=a1-Bsm[j*3+1], d2=a2-Bsm[j*3+2];
    double d=d0*d0+d1*d1+d2*d2;
    se += exp((mind-d)*(1.0/SIGC));
  }
  #pragma unroll
  for(int off=16;off>0;off>>=1) se += __shfl_xor(se,off,32);
  if(jt==0) red[tid>>5] = fmax(GAMC - mind + SIGC*log(se), 0.0);
  __syncthreads();
  if(tid==0){
    double s=0.0;
    #pragma unroll
    for(int i=0;i<8;i++) s+=red[i];
    stabp[blk]=s;
  }
}

__global__ void k_out(const double* __restrict__ otb, const double* __restrict__ dockb,
    const double* __restrict__ rmsdb, const double* __restrict__ stabp, float* __restrict__ out){
  if(blockIdx.x==0 && threadIdx.x==0){
    double ot=0.0,dock=0.0,rmsd=0.0,stab=0.0;
    for(int b=0;b<BSZ;b++){
      ot+=otb[b]; dock+=dockb[b]; rmsd+=rmsdb[b];
      double s1=0.0,s2=0.0;
      for(int i=0;i<125;i++){ s1+=stabp[(b*2+0)*125+i]; s2+=stabp[(b*2+1)*125+i]; }
      stab += (s1*(1.0/NPP) + s2*(1.0/NPP))*(1.0/STDV);
    }
    ot*=0.25; dock*=0.25; rmsd*=0.25; stab*=0.25;
    out[0]=(float)(ot+dock+stab); out[1]=(float)ot; out[2]=(float)dock; out[3]=(float)stab; out[4]=(float)rmsd;
  }
}

// ------------------------------------------------------------------
extern "C" void kernel_launch(void* const* d_in, const int* in_sizes, int n_in,
                              void* d_out, int out_size, void* d_ws, size_t ws_size,
                              hipStream_t stream){
  const float* X      = (const float*)d_in[0];
  const float* nodea  = (const float*)d_in[1];
  const float* edgea  = (const float*)d_in[2];
  const float* center = (const float*)d_in[3];
  const float* kpin   = (const float*)d_in[4];
  const float* rot    = (const float*)d_in[5];
  const float* trans  = (const float*)d_in[6];
  const float* W_in1  = (const float*)d_in[7];
  const float* b_in1  = (const float*)d_in[8];
  const float* W_in2  = (const float*)d_in[9];
  const float* b_in2  = (const float*)d_in[10];
  const float* msg_W  = (const float*)d_in[11];
  const float* msg_b  = (const float*)d_in[12];
  const float* upd_W1 = (const float*)d_in[13];
  const float* upd_b1 = (const float*)d_in[14];
  const float* upd_W2 = (const float*)d_in[15];
  const float* upd_b2 = (const float*)d_in[16];
  const float* x_W    = (const float*)d_in[17];
  const float* v_W    = (const float*)d_in[18];
  const float* att_W  = (const float*)d_in[19];
  const float* act_W1 = (const float*)d_in[20];
  const float* act_b1 = (const float*)d_in[21];
  const float* act_W2 = (const float*)d_in[22];
  const float* act_b2 = (const float*)d_in[23];
  const float* geb_Wv1= (const float*)d_in[24];
  const float* geb_Wv2= (const float*)d_in[25];
  const float* geb_W1 = (const float*)d_in[26];
  const float* geb_b1 = (const float*)d_in[27];
  const float* geb_W2 = (const float*)d_in[28];
  const float* geb_b2 = (const float*)d_in[29];
  const float* sc_W1  = (const float*)d_in[30];
  const float* sc_b1  = (const float*)d_in[31];
  const float* sc_W2  = (const float*)d_in[32];
  const float* sc_b2  = (const float*)d_in[33];
  const float* fin_W  = (const float*)d_in[34];
  const int*   src    = (const int*)d_in[35];
  const int*   dst    = (const int*)d_in[36];
  float* out = (float*)d_out;

  double* wd = (double*)d_ws;
  size_t o = 0;
  double* XcaD  = wd + o; o += (size_t)NN*3;
  double* ori0D = wd + o; o += (size_t)BSZ*NPP*3;
  double* kpcD  = wd + o; o += 144;
  double* tkpcD = wd + o; o += 144;
  double* dirvD = wd + o; o += (size_t)EE*3;
  double* rbfD  = wd + o; o += (size_t)EE*RBFD;
  double* hbuf  = wd + o; o += (size_t)NN*HD;
  double* Pbuf  = wd + o; o += (size_t)NN*256;
  double* mbuf  = wd + o; o += (size_t)EE*HD;
  double* va    = wd + o; o += (size_t)NN*HD*3;
  double* vb    = wd + o; o += (size_t)NN*HD*3;
  double* ubuf  = wd + o; o += (size_t)BSZ*2*HD;
  double* attp  = wd + o; o += (size_t)64*HD;
  double* nv2b  = wd + o; o += (size_t)NN*HD;
  double* sbuf  = wd + o; o += (size_t)NN*256;
  double* cbbD  = wd + o; o += 24;
  double* ypartD= wd + o; o += (size_t)4000*37;
  double* YbufD = wd + o; o += 8*36;
  double* x1aD  = wd + o; o += (size_t)BSZ*NPP*3;
  double* otb_  = wd + o; o += 4;
  double* dkb_  = wd + o; o += 4;
  double* rmb_  = wd + o; o += 4;
  double* stp_  = wd + o; o += 1000;
  double* Wnode = wd + o; o += (size_t)4*128*256;
  double* Wedge2= wd + o; o += (size_t)4*37*128;
  double* xvW   = wd + o; o += (size_t)4*128*256;

  double* h2b  = Pbuf + (size_t)NN*HD;   // overlays upper half of P (dead after edgemsg)

  size_t need = o*8;
  if(ws_size < need){
    float mb = (float)((double)ws_size / 1.0e6);
    float val = (131072.0f + mb) * 1048576.0f;
    k_sent<<<1,64,0,stream>>>(out, val);
    return;
  }

  hipMemsetAsync(va, 0, (size_t)NN*HD*3*sizeof(double), stream);

  k_cvt_node<<<512,256,0,stream>>>(msg_W, Wnode);
  k_cvt_edge<<<74,256,0,stream>>>(msg_W, msg_b, Wedge2);
  k_cvt_xv<<<256,256,0,stream>>>(x_W, v_W, xvW);

  k_geom<<<32,256,0,stream>>>(X, center, kpin, rot, trans, XcaD, ori0D, kpcD, tkpcD);
  k_edge<<<(EE+255)/256,256,0,stream>>>(XcaD, src, dst, dirvD, rbfD);
  k_hinit<<<NN/4,256,0,stream>>>(nodea, W_in1, b_in1, W_in2, b_in2, hbuf);

  double* vcur = va;
  double* vnxt = vb;
  for(int l=0;l<NL;l++){
    const double* Wn  = Wnode  + (size_t)l*128*256;
    const double* We  = Wedge2 + (size_t)l*37*128;
    const double* xvl = xvW    + (size_t)l*128*256;
    const float* u1W = upd_W1 + (size_t)l*256*HD;
    const float* u1b = upd_b1 + (size_t)l*HD;
    const float* u2W = upd_W2 + (size_t)l*HD*HD;
    const float* u2b = upd_b2 + (size_t)l*HD;
    const float* aWl = att_W  + (size_t)l*HD*HD;
    const float* a1W = act_W1 + (size_t)l*HD*HD;
    const float* a1b = act_b1 + (size_t)l*HD;
    const float* a2W = act_W2 + (size_t)l*HD*HD;
    const float* a2b = act_b2 + (size_t)l*HD;

    k_nodeproj<<<NN/4,128,0,stream>>>(hbuf, Wn, Pbuf);
    k_edgemsg<<<EE/32,256,0,stream>>>(Pbuf, rbfD, edgea, src, dst, We, mbuf);
    k_upd<<<NN/4,128,0,stream>>>(hbuf, mbuf, u1W, u1b, u2W, u2b, h2b);
    k_vupd<<<NN/4,256,0,stream>>>(mbuf, vcur, dirvD, src, xvl, vnxt);
    k_att1<<<64,128,0,stream>>>(h2b, attp);
    k_att2<<<8,128,0,stream>>>(attp, aWl, ubuf);
    k_actcomb<<<NN/4,128,0,stream>>>(h2b, ubuf, a1W, a1b, a2W, a2b, hbuf);
    double* tmp=vcur; vcur=vnxt; vnxt=tmp;
  }
  // vcur == va (final v), vnxt == vb (free -> v1)
  k_gebv<<<NN/2,256,0,stream>>>(vcur, geb_Wv1, geb_Wv2, vnxt, nv2b);
  k_gebs<<<NN/4,256,0,stream>>>(hbuf, nv2b, geb_W1, geb_b1, geb_W2, geb_b2, sbuf);
  k_kpc<<<8,256,0,stream>>>(XcaD, cbbD);
  k_kpgen<<<NN/2,256,0,stream>>>(XcaD, sbuf, vnxt, cbbD, fin_W, sc_W1, sc_b1, sc_W2, sc_b2, ypartD);
  k_kpfin<<<8,64,0,stream>>>(ypartD, cbbD, YbufD);
  k_final<<<BSZ,256,0,stream>>>(YbufD, tkpcD, kpcD, rot, trans, XcaD, ori0D, x1aD, otb_, dkb_, rmb_);
  k_stab<<<1000,256,0,stream>>>(x1aD, XcaD, stp_);
  k_out<<<1,64,0,stream>>>(otb_, dkb_, rmb_, stp_, out);
}

// Round 13
// 1555.469 us; speedup vs baseline: 1.5127x; 1.0239x over previous
//
#include <hip/hip_runtime.h>
#include <math.h>

#define NPP 1000
#define BSZ 4
#define HD 128
#define NL 4
#define RBFD 20
#define EDD 16
#define KN 9
#define NKPP 12
#define NN 8000
#define EE 72000
#define STDV 10.0
#define SIGC 25.0
#define GAMC 10.0
#define PID 3.14159265358979323846

__device__ __forceinline__ double silud(double x){ return x / (1.0 + exp(-x)); }

__global__ void k_sent(float* __restrict__ out, float val){
  if(threadIdx.x<5 && blockIdx.x==0) out[threadIdx.x]=val;
}

// ------------------------------------------------------------------
// weight preconversion to f64
// ------------------------------------------------------------------
__global__ __launch_bounds__(256) void k_cvt_node(const float* __restrict__ msgW, double* __restrict__ Wn){
  int idx = blockIdx.x*256+threadIdx.x;
  if(idx >= 4*128*256) return;
  int l = idx>>15; int r = idx & 32767; int k = r>>8; int j = r&255;
  const float* W = msgW + (size_t)l*292*128;
  Wn[idx] = (j<128) ? (double)W[k*128+j] : (double)W[(128+k)*128 + (j-128)];
}
__global__ __launch_bounds__(256) void k_cvt_edge(const float* __restrict__ msgW, const float* __restrict__ msgb,
    double* __restrict__ We){
  int idx = blockIdx.x*256+threadIdx.x;
  if(idx >= 4*37*128) return;
  int l = idx/(37*128); int r = idx%(37*128); int k = r>>7; int j = r&127;
  if(k<36) We[idx] = (double)msgW[(size_t)l*292*128 + (256+k)*128 + j];
  else     We[idx] = (double)msgb[l*128 + j];
}
__global__ __launch_bounds__(256) void k_cvt_xv(const float* __restrict__ xW, const float* __restrict__ vW,
    double* __restrict__ xv){
  int idx = blockIdx.x*256+threadIdx.x;
  if(idx >= 4*128*128) return;
  int l = idx>>14; int r = idx & 16383; int hh = r>>7; int c = r&127;
  xv[(size_t)l*32768 + hh*256 + 2*c]   = (double)xW[(size_t)l*16384 + hh*128 + c];
  xv[(size_t)l*32768 + hh*256 + 2*c+1] = (double)vW[(size_t)l*16384 + hh*128 + c];
}

// ------------------------------------------------------------------
// geometry (f64)
// ------------------------------------------------------------------
__global__ __launch_bounds__(256) void k_geom(const float* __restrict__ X, const float* __restrict__ center,
    const float* __restrict__ kpin, const float* __restrict__ rot, const float* __restrict__ trans,
    double* __restrict__ Xca, double* __restrict__ ori0, double* __restrict__ kpc, double* __restrict__ tkpc){
  int i = blockIdx.x*256 + threadIdx.x;
  const double inv = 1.0/STDV;
  if(i < NN){
    int b = i / (2*NPP);
    int s = (i / NPP) & 1;
    int n = i % NPP;
    double q0 = (double)X[i*12+3] - (double)center[b*3+0];
    double q1 = (double)X[i*12+4] - (double)center[b*3+1];
    double q2 = (double)X[i*12+5] - (double)center[b*3+2];
    if(s==0){
      int o=(b*NPP+n)*3;
      ori0[o]=q0*inv; ori0[o+1]=q1*inv; ori0[o+2]=q2*inv;
      const float* R = rot + b*9;
      #pragma unroll
      for(int d=0; d<3; d++)
        Xca[i*3+d] = (q0*(double)R[d] + q1*(double)R[3+d] + q2*(double)R[6+d])*inv + (double)trans[b*3+d];
    } else {
      Xca[i*3+0]=q0*inv; Xca[i*3+1]=q1*inv; Xca[i*3+2]=q2*inv;
    }
  } else if(i < NN + BSZ*NKPP){
    int j = i - NN;
    int b = j / NKPP;
    double q0 = (double)kpin[j*3+0]-(double)center[b*3+0];
    double q1 = (double)kpin[j*3+1]-(double)center[b*3+1];
    double q2 = (double)kpin[j*3+2]-(double)center[b*3+2];
    kpc[j*3+0]=q0*inv; kpc[j*3+1]=q1*inv; kpc[j*3+2]=q2*inv;
    const float* R = rot + b*9;
    #pragma unroll
    for(int d=0; d<3; d++)
      tkpc[j*3+d] = (q0*(double)R[d] + q1*(double)R[3+d] + q2*(double)R[6+d])*inv + (double)trans[b*3+d];
  }
}

// ------------------------------------------------------------------
__global__ __launch_bounds__(256) void k_edge(const double* __restrict__ Xca, const int* __restrict__ src,
    const int* __restrict__ dst, double* __restrict__ dirv, double* __restrict__ rbfb){
  int e = blockIdx.x*256 + threadIdx.x;
  if(e >= EE) return;
  int sp = src[e], dp = dst[e];
  double d0 = Xca[dp*3+0]-Xca[sp*3+0];
  double d1 = Xca[dp*3+1]-Xca[sp*3+1];
  double d2 = Xca[dp*3+2]-Xca[sp*3+2];
  double nr = sqrt(d0*d0+d1*d1+d2*d2) + 1e-08;
  double iv = 1.0/nr;
  dirv[e*3+0]=d0*iv; dirv[e*3+1]=d1*iv; dirv[e*3+2]=d2*iv;
  #pragma unroll
  for(int j=0;j<RBFD;j++)
    rbfb[e*RBFD+j] = sin(nr*(double)(j+1)*PID)*iv;
}

// ------------------------------------------------------------------
// h init: 4 nodes/block, 256 thr
// ------------------------------------------------------------------
__global__ __launch_bounds__(256) void k_hinit(const float* __restrict__ na,
    const float* __restrict__ W1, const float* __restrict__ b1,
    const float* __restrict__ W2, const float* __restrict__ b2, double* __restrict__ h){
  __shared__ double cin[4][64];
  __shared__ double hmid[4][128];
  int n0 = blockIdx.x*4;
  int tid = threadIdx.x;
  {
    int r=tid>>6, k=tid&63;
    cin[r][k] = (double)na[(n0+r)*64 + k];
  }
  __syncthreads();
  int r = tid>>6, c0 = (tid&63)*2;
  double a0=(double)b1[c0], a1=(double)b1[c0+1];
  for(int k=0;k<64;k++){
    double a = cin[r][k];
    const float* wp = W1 + k*HD + c0;
    a0 += a*(double)wp[0]; a1 += a*(double)wp[1];
  }
  hmid[r][c0]=silud(a0); hmid[r][c0+1]=silud(a1);
  __syncthreads();
  double s0=(double)b2[c0], s1=(double)b2[c0+1];
  for(int k=0;k<HD;k++){
    double a = hmid[r][k];
    const float* wp = W2 + k*HD + c0;
    s0 += a*(double)wp[0]; s1 += a*(double)wp[1];
  }
  h[(size_t)(n0+r)*HD+c0]=s0; h[(size_t)(n0+r)*HD+c0+1]=s1;
}

// ------------------------------------------------------------------
// node projection: 4 nodes/block, 128 thr, col=tid*2, 4-node accum
// ------------------------------------------------------------------
__global__ __launch_bounds__(128) void k_nodeproj(const double* __restrict__ h, const double* __restrict__ Wn,
    double* __restrict__ P){
  __shared__ double cin[4][128];
  int n0 = blockIdx.x*4;
  int tid = threadIdx.x;
  for(int idx=tid; idx<512; idx+=128){
    int r=idx>>7, k=idx&127;
    cin[r][k]=h[(size_t)(n0+r)*HD+k];
  }
  __syncthreads();
  int c0 = tid*2;
  double a00=0,a01=0,a10=0,a11=0,a20=0,a21=0,a30=0,a31=0;
  for(int k=0;k<128;k++){
    double2 w = *(const double2*)(Wn + (size_t)k*256 + c0);
    double x0=cin[0][k],x1=cin[1][k],x2=cin[2][k],x3=cin[3][k];
    a00+=x0*w.x; a01+=x0*w.y; a10+=x1*w.x; a11+=x1*w.y;
    a20+=x2*w.x; a21+=x2*w.y; a30+=x3*w.x; a31+=x3*w.y;
  }
  P[(size_t)(n0+0)*256+c0]=a00; P[(size_t)(n0+0)*256+c0+1]=a01;
  P[(size_t)(n0+1)*256+c0]=a10; P[(size_t)(n0+1)*256+c0+1]=a11;
  P[(size_t)(n0+2)*256+c0]=a20; P[(size_t)(n0+2)*256+c0+1]=a21;
  P[(size_t)(n0+3)*256+c0]=a30; P[(size_t)(n0+3)*256+c0+1]=a31;
}

// ------------------------------------------------------------------
// fused layer kernel: edge messages (into LDS) + upd-MLP + v-update
// 4 nodes/block, 256 thr (half=tid>>7, colp=tid&127)
// ------------------------------------------------------------------
__global__ __launch_bounds__(256) void k_layer(
    const double* __restrict__ P, const double* __restrict__ rbfb, const float* __restrict__ ea,
    const int* __restrict__ src, const double* __restrict__ We,
    const double* __restrict__ h, const float* __restrict__ W1, const float* __restrict__ b1,
    const float* __restrict__ W2, const float* __restrict__ b2, double* __restrict__ h2,
    const double* __restrict__ va, const double* __restrict__ dirv, const double* __restrict__ xv,
    double* __restrict__ vb){
  __shared__ double mT[4][9][128];     // 36 KB, live all phases
  __shared__ double scratch[1536];     // 12 KB: feat | cin+hmid | md
  __shared__ double dv[4][9][3];
  __shared__ int sp[4][9];
  int n0 = blockIdx.x*4;
  int tid = threadIdx.x;
  int e0 = n0*KN;
  // stage feat (rbf,ea,1), sp, dv
  for(int idx=tid; idx<36*RBFD; idx+=256){
    int e=idx/RBFD, f=idx-e*RBFD;
    scratch[e*37+f] = rbfb[(size_t)(e0+e)*RBFD+f];
  }
  for(int idx=tid; idx<36*EDD; idx+=256){
    int e=idx>>4, f=idx&15;
    scratch[e*37+20+f] = (double)ea[(size_t)(e0+e)*EDD+f];
  }
  if(tid<36){
    scratch[tid*37+36]=1.0;
    int nd=tid/9, kk=tid-nd*9;
    int e=e0+nd*9+kk;
    sp[nd][kk]=src[e];
    dv[nd][kk][0]=dirv[e*3]; dv[nd][kk][1]=dirv[e*3+1]; dv[nd][kk][2]=dirv[e*3+2];
  }
  int half = tid>>7, colp = tid&127;
  // preload We column into registers (constant-indexed, stays in VGPRs)
  double wreg[37];
  #pragma unroll
  for(int f=0;f<37;f++) wreg[f]=We[f*128+colp];
  __syncthreads();
  // ---- phase A: m = silu(feat@We + P_src + P_dst), into mT; agg in regs
  double aggv0=0.0, aggv1=0.0;
  {
    int nd = half*2;
    double p2 = P[(size_t)(n0+nd)*256 + 128 + colp];
    double agg=0.0;
    for(int kk=0;kk<9;kk++){
      const double* fe = &scratch[(nd*9+kk)*37];
      double acc=0.0;
      #pragma unroll
      for(int f=0;f<37;f++) acc += fe[f]*wreg[f];
      double mv_ = silud(acc + P[(size_t)sp[nd][kk]*256 + colp] + p2);
      mT[nd][kk][colp]=mv_;
      agg += mv_;
    }
    aggv0=agg;
  }
  {
    int nd = half*2+1;
    double p2 = P[(size_t)(n0+nd)*256 + 128 + colp];
    double agg=0.0;
    for(int kk=0;kk<9;kk++){
      const double* fe = &scratch[(nd*9+kk)*37];
      double acc=0.0;
      #pragma unroll
      for(int f=0;f<37;f++) acc += fe[f]*wreg[f];
      double mv_ = silud(acc + P[(size_t)sp[nd][kk]*256 + colp] + p2);
      mT[nd][kk][colp]=mv_;
      agg += mv_;
    }
    aggv1=agg;
  }
  __syncthreads();    // feat dead -> scratch becomes cin/hmid
  {
    int ndA = half*2, ndB = ndA+1;
    scratch[ndA*256+colp]     = h[(size_t)(n0+ndA)*HD+colp];
    scratch[ndA*256+128+colp] = aggv0;
    scratch[ndB*256+colp]     = h[(size_t)(n0+ndB)*HD+colp];
    scratch[ndB*256+128+colp] = aggv1;
  }
  __syncthreads();
  // ---- phase B: intra = h + silu([h,agg]@W1+b1)@W2+b2
  {
    int ndA = half*2, ndB = ndA+1;
    double bb=(double)b1[colp];
    double a0=bb, a1=bb;
    for(int k=0;k<256;k++){
      double w = (double)W1[(size_t)k*HD+colp];
      a0 += scratch[ndA*256+k]*w;
      a1 += scratch[ndB*256+k]*w;
    }
    scratch[1024+ndA*128+colp]=silud(a0);
    scratch[1024+ndB*128+colp]=silud(a1);
  }
  __syncthreads();
  {
    int ndA = half*2, ndB = ndA+1;
    double bb=(double)b2[colp];
    double a0=bb, a1=bb;
    for(int k=0;k<128;k++){
      double w = (double)W2[(size_t)k*HD+colp];
      a0 += scratch[1024+ndA*128+k]*w;
      a1 += scratch[1024+ndB*128+k]*w;
    }
    h2[(size_t)(n0+ndA)*HD+colp] = scratch[ndA*256+colp] + a0;
    h2[(size_t)(n0+ndB)*HD+colp] = scratch[ndB*256+colp] + a1;
  }
  __syncthreads();    // cin/hmid dead -> scratch becomes md
  // ---- phase C: md then v-update (round-12 structure)
  for(int idx=tid; idx<1536; idx+=256){
    int hh=idx&127, t2=idx>>7; int nd=t2/3, c=t2-nd*3;
    double s=0.0;
    #pragma unroll
    for(int kk=0;kk<9;kk++) s += dv[nd][kk][c]*mT[nd][kk][hh];
    scratch[nd*384 + c*128 + hh]=s;
  }
  __syncthreads();
  int nd = tid>>6;            // wave-uniform
  int t  = tid&63;
  int c0 = 2*t;
  double oA0=0,oA1=0,oA2=0, oB0=0,oB1=0,oB2=0;
  double mvA[9], mvB[9];
  #pragma unroll
  for(int kk=0;kk<9;kk++){ mvA[kk]=0.0; mvB[kk]=0.0; }
  const double* mdb = &scratch[nd*384];
  for(int hh=0; hh<128; hh++){
    const double* xp = xv + (size_t)hh*256 + 2*c0;
    double2 wpA = *(const double2*)(xp);
    double2 wpB = *(const double2*)(xp+2);
    double d0 = mdb[hh], d1 = mdb[128+hh], d2 = mdb[256+hh];
    oA0 += d0*wpA.x; oA1 += d1*wpA.x; oA2 += d2*wpA.x;
    oB0 += d0*wpB.x; oB1 += d1*wpB.x; oB2 += d2*wpB.x;
    #pragma unroll
    for(int kk=0;kk<9;kk++){
      double mk = mT[nd][kk][hh];
      mvA[kk] += mk*wpA.y;
      mvB[kk] += mk*wpB.y;
    }
  }
  #pragma unroll
  for(int kk=0;kk<9;kk++){
    size_t s3 = (size_t)sp[nd][kk]*384 + c0*3;
    double ka = mvA[kk], kb = mvB[kk];
    oA0 += va[s3]*ka;   oA1 += va[s3+1]*ka; oA2 += va[s3+2]*ka;
    oB0 += va[s3+3]*kb; oB1 += va[s3+4]*kb; oB2 += va[s3+5]*kb;
  }
  size_t b3 = (size_t)(n0+nd)*384 + c0*3;
  vb[b3]  = va[b3]  + oA0;
  vb[b3+1]= va[b3+1]+ oA1;
  vb[b3+2]= va[b3+2]+ oA2;
  vb[b3+3]= va[b3+3]+ oB0;
  vb[b3+4]= va[b3+4]+ oB1;
  vb[b3+5]= va[b3+5]+ oB2;
}

// ------------------------------------------------------------------
// attention partials + finish
// ------------------------------------------------------------------
__global__ __launch_bounds__(128) void k_att1(const double* __restrict__ h2, double* __restrict__ partial){
  int blk = blockIdx.x;
  int bs = blk>>3, ch = blk&7;
  int col = threadIdx.x;
  size_t base = ((size_t)bs*NPP + ch*125)*HD + col;
  double s=0.0;
  for(int i=0;i<125;i++) s += h2[base + (size_t)i*HD];
  partial[(size_t)blk*HD + col] = s;
}
__global__ __launch_bounds__(128) void k_att2(const double* __restrict__ partial, const float* __restrict__ attW,
    double* __restrict__ u){
  __shared__ double mm[128];
  int bs = blockIdx.x;
  int col = threadIdx.x;
  int os = bs^1;
  double s=0.0;
  for(int c=0;c<8;c++) s += partial[(size_t)(os*8+c)*HD + col];
  mm[col] = s*(1.0/NPP);
  __syncthreads();
  double acc=0.0;
  for(int k=0;k<HD;k++) acc += (double)attW[col*HD+k]*mm[k];
  u[bs*HD+col] = acc;
}

// ------------------------------------------------------------------
// h_new = intra + g*act(intra), g fused
// ------------------------------------------------------------------
__global__ __launch_bounds__(128) void k_actcomb(const double* __restrict__ h2, const double* __restrict__ u,
    const float* __restrict__ W1, const float* __restrict__ b1,
    const float* __restrict__ W2, const float* __restrict__ b2, double* __restrict__ h){
  __shared__ double As[4][128];
  __shared__ double hmid[4][128];
  __shared__ double pd[128];
  __shared__ double gsh[4];
  int n0 = blockIdx.x*4;
  int tid = threadIdx.x;
  int bs = n0/NPP;
  for(int idx=tid; idx<512; idx+=128){
    int r=idx>>7, k=idx&127;
    As[r][k] = h2[(size_t)(n0+r)*HD+k];
  }
  __syncthreads();
  {
    int nd=tid>>5, q=tid&31;
    double p=0.0;
    for(int j=q;j<128;j+=32) p += As[nd][j]*u[bs*HD+j];
    pd[tid]=p;
  }
  __syncthreads();
  if((tid&31)==0){
    int nd=tid>>5;
    double s=0.0;
    for(int i2=0;i2<32;i2++) s+=pd[nd*32+i2];
    gsh[nd]=1.0/(1.0+exp(-s));
  }
  __syncthreads();
  int col = tid;
  double bb=(double)b1[col];
  double a0=bb,a1=bb,a2=bb,a3=bb;
  for(int k=0;k<128;k++){
    double w = (double)W1[(size_t)k*HD+col];
    a0 += As[0][k]*w; a1 += As[1][k]*w; a2 += As[2][k]*w; a3 += As[3][k]*w;
  }
  hmid[0][col]=silud(a0); hmid[1][col]=silud(a1); hmid[2][col]=silud(a2); hmid[3][col]=silud(a3);
  __syncthreads();
  bb=(double)b2[col];
  a0=bb;a1=bb;a2=bb;a3=bb;
  for(int k=0;k<128;k++){
    double w = (double)W2[(size_t)k*HD+col];
    a0 += hmid[0][k]*w; a1 += hmid[1][k]*w; a2 += hmid[2][k]*w; a3 += hmid[3][k]*w;
  }
  h[(size_t)(n0+0)*HD+col] = As[0][col] + gsh[0]*a0;
  h[(size_t)(n0+1)*HD+col] = As[1][col] + gsh[1]*a1;
  h[(size_t)(n0+2)*HD+col] = As[2][col] + gsh[2]*a2;
  h[(size_t)(n0+3)*HD+col] = As[3][col] + gsh[3]*a3;
}

// ------------------------------------------------------------------
// geb vector branch
// ------------------------------------------------------------------
__global__ __launch_bounds__(256) void k_gebv(const double* __restrict__ va,
    const float* __restrict__ Wv1, const float* __restrict__ Wv2,
    double* __restrict__ v1, double* __restrict__ nv2){
  __shared__ double vl[2][384];
  int n0 = blockIdx.x*2;
  int tid = threadIdx.x;
  for(int idx=tid; idx<768; idx+=256){
    int r=idx/384, k=idx%384;
    vl[r][k] = va[(size_t)(n0+r)*384+k];
  }
  __syncthreads();
  int r = tid>>7, col = tid&127;
  double a10=0.0,a11=0.0,a12=0.0, a20=0.0,a21=0.0,a22=0.0;
  for(int hh=0; hh<HD; hh++){
    double w1 = (double)Wv1[hh*HD+col];
    double w2 = (double)Wv2[hh*HD+col];
    double v0=vl[r][hh*3], v1e=vl[r][hh*3+1], v2e=vl[r][hh*3+2];
    a10+=v0*w1; a11+=v1e*w1; a12+=v2e*w1;
    a20+=v0*w2; a21+=v1e*w2; a22+=v2e*w2;
  }
  size_t b3=(size_t)(n0+r)*384+col*3;
  v1[b3]=a10; v1[b3+1]=a11; v1[b3+2]=a12;
  nv2[(size_t)(n0+r)*HD+col]=sqrt(a20*a20+a21*a21+a22*a22);
}

// ------------------------------------------------------------------
// s = silu([h,nv2]@gebW1+b1)@gebW2+b2
// ------------------------------------------------------------------
__global__ __launch_bounds__(256) void k_gebs(const double* __restrict__ h, const double* __restrict__ nv2,
    const float* __restrict__ W1, const float* __restrict__ b1,
    const float* __restrict__ W2, const float* __restrict__ b2, double* __restrict__ s){
  __shared__ double cin[4][256];
  __shared__ double hmid[4][128];
  int n0 = blockIdx.x*4;
  int tid = threadIdx.x;
  for(int idx=tid; idx<4*HD; idx+=256){
    int r=idx>>7, k=idx&127;
    cin[r][k]    = h[(size_t)(n0+r)*HD + k];
    cin[r][HD+k] = nv2[(size_t)(n0+r)*HD + k];
  }
  __syncthreads();
  int r = tid>>6, c0 = (tid&63)*2;
  double a0=(double)b1[c0], a1=(double)b1[c0+1];
  for(int k=0;k<2*HD;k++){
    double a = cin[r][k];
    const float* wp = W1 + (size_t)k*HD + c0;
    a0 += a*(double)wp[0]; a1 += a*(double)wp[1];
  }
  hmid[r][c0]=silud(a0); hmid[r][c0+1]=silud(a1);
  __syncthreads();
  int c1 = (tid&63)*4;
  double s0=(double)b2[c1], s1=(double)b2[c1+1], s2=(double)b2[c1+2], s3=(double)b2[c1+3];
  for(int k=0;k<HD;k++){
    double a = hmid[r][k];
    const float* wp = W2 + (size_t)k*256 + c1;
    s0 += a*(double)wp[0]; s1 += a*(double)wp[1]; s2 += a*(double)wp[2]; s3 += a*(double)wp[3];
  }
  double* srow = s + (size_t)(n0+r)*256 + c1;
  srow[0]=s0; srow[1]=s1; srow[2]=s2; srow[3]=s3;
}

// ------------------------------------------------------------------
__global__ __launch_bounds__(256) void k_kpc(const double* __restrict__ Xca, double* __restrict__ cbb){
  __shared__ double red[768];
  int bs = blockIdx.x;
  int tid = threadIdx.x;
  double s0=0.0,s1=0.0,s2=0.0;
  for(int nidx=tid; nidx<NPP; nidx+=256){
    int i = bs*NPP+nidx;
    s0+=Xca[i*3]; s1+=Xca[i*3+1]; s2+=Xca[i*3+2];
  }
  red[tid]=s0; red[256+tid]=s1; red[512+tid]=s2;
  __syncthreads();
  for(int st=128; st>0; st>>=1){
    if(tid<st){ red[tid]+=red[tid+st]; red[256+tid]+=red[256+tid+st]; red[512+tid]+=red[512+tid+st]; }
    __syncthreads();
  }
  if(tid==0){ cbb[bs*3]=red[0]*(1.0/NPP); cbb[bs*3+1]=red[256]*(1.0/NPP); cbb[bs*3+2]=red[512]*(1.0/NPP); }
}

// ------------------------------------------------------------------
// keypoint partials: 2 nodes/block
// ------------------------------------------------------------------
__global__ __launch_bounds__(256) void k_kpgen(const double* __restrict__ Xca, const double* __restrict__ sbuf,
    const double* __restrict__ v1, const double* __restrict__ cbb, const float* __restrict__ fW,
    const float* __restrict__ sW1, const float* __restrict__ sb1, const float* __restrict__ sW2,
    const float* __restrict__ sb2, double* __restrict__ ypart){
  __shared__ double tt[2][3][128];
  __shared__ double ssv[2][128];
  __shared__ double zz[2][64];
  __shared__ double snorm[2];
  __shared__ double ylL[2][37];
  int blk = blockIdx.x;
  int tid = threadIdx.x;
  int r = tid>>7, t = tid&127;
  int n = blk*2 + r;
  int bs = n/NPP;
  const double* srow = sbuf + (size_t)n*256;
  const double* vrow = v1 + (size_t)n*384;
  double gate = srow[128+t];
  double hp = srow[t];
  double vf0 = vrow[t*3+0]*gate, vf1 = vrow[t*3+1]*gate, vf2 = vrow[t*3+2]*gate;
  tt[r][0][t]=vf0*hp; tt[r][1][t]=vf1*hp; tt[r][2][t]=vf2*hp;
  ssv[r][t]=sqrt(vf0*vf0+vf1*vf1+vf2*vf2);
  if(t==0){
    double x0=Xca[n*3]-cbb[bs*3], x1=Xca[n*3+1]-cbb[bs*3+1], x2=Xca[n*3+2]-cbb[bs*3+2];
    snorm[r]=sqrt(x0*x0+x1*x1+x2*x2);
  }
  __syncthreads();
  if(t<36){
    int k2=t/3, c=t%3;
    double a=0.0;
    for(int hh=0; hh<128; hh++) a += tt[r][c][hh]*(double)fW[hh*NKPP+k2];
    ylL[r][t]=a;
  } else if(t>=64){
    int j=t-64;
    double z=(double)sb1[j];
    for(int hh=0; hh<128; hh++) z += ssv[r][hh]*(double)sW1[hh*64+j];
    z += snorm[r]*(double)sW1[128*64+j];
    zz[r][j]=silud(z)*(double)sW2[j];
  }
  __syncthreads();
  if(t==36){
    double dn=(double)sb2[0];
    for(int j=0;j<64;j++) dn+=zz[r][j];
    ylL[r][36]=dn;
  }
  __syncthreads();
  if(tid<37) ypart[(size_t)blk*37+tid]=ylL[0][tid]+ylL[1][tid];
}

__global__ __launch_bounds__(64) void k_kpfin(const double* __restrict__ ypart,
    const double* __restrict__ cbb, double* __restrict__ Y){
  __shared__ double sums[37];
  int bs=blockIdx.x, tid=threadIdx.x;
  if(tid<37){
    double s=0.0;
    for(int i=0;i<500;i++) s += ypart[(size_t)(bs*500+i)*37 + tid];
    sums[tid]=s;
  }
  __syncthreads();
  if(tid<36){
    double dsh = sums[36]*(1.0/NPP);
    Y[bs*36+tid] = sums[tid]/dsh + cbb[bs*3 + tid%3];
  }
}

// ------------------------------------------------------------------
// per-sample: ot, Kabsch (Horn quaternion), dock, rmsd, X1a
// ------------------------------------------------------------------
__global__ __launch_bounds__(256) void k_final(const double* __restrict__ Y, const double* __restrict__ tkpc,
    const double* __restrict__ kpc, const float* __restrict__ rot, const float* __restrict__ trans,
    const double* __restrict__ Xca, const double* __restrict__ ori0,
    double* __restrict__ x1a, double* __restrict__ otb, double* __restrict__ dockb, double* __restrict__ rmsdb){
  int b = blockIdx.x;
  int tid = threadIdx.x;
  __shared__ double Rs[9];
  __shared__ double ts[3];
  __shared__ double red[256];
  if(tid==0){
    const double* Y1 = Y + (b*2+0)*36;
    const double* Y2 = Y + (b*2+1)*36;
    const double* P1 = tkpc + b*36;
    const double* P2 = kpc + b*36;
    double ot1=0.0, ot2=0.0;
    for(int i=0;i<12;i++){
      double best1=1e300, best2=1e300;
      for(int j=0;j<12;j++){
        double d1=0.0, d2=0.0;
        #pragma unroll
        for(int c=0;c<3;c++){
          double e1=Y1[i*3+c]-P1[j*3+c]; d1+=e1*e1;
          double e2=Y2[i*3+c]-P2[j*3+c]; d2+=e2*e2;
        }
        best1=fmin(best1,d1); best2=fmin(best2,d2);
      }
      ot1+=best1; ot2+=best2;
    }
    double ot = ot1*(1.0/36.0) + ot2*(1.0/36.0);
    double c1[3]={0,0,0}, c2[3]={0,0,0};
    for(int i=0;i<12;i++)
      for(int c=0;c<3;c++){ c1[c]+=Y1[i*3+c]; c2[c]+=Y2[i*3+c]; }
    for(int c=0;c<3;c++){ c1[c]/=12.0; c2[c]/=12.0; }
    double Hm[3][3]={{0,0,0},{0,0,0},{0,0,0}};
    for(int i=0;i<12;i++)
      for(int a=0;a<3;a++)
        for(int c=0;c<3;c++)
          Hm[a][c] += (Y1[i*3+a]-c1[a])*(Y2[i*3+c]-c2[c]);
    double Sxx=Hm[0][0],Sxy=Hm[0][1],Sxz=Hm[0][2];
    double Syx=Hm[1][0],Syy=Hm[1][1],Syz=Hm[1][2];
    double Szx=Hm[2][0],Szy=Hm[2][1],Szz=Hm[2][2];
    double K[4][4];
    K[0][0]=Sxx+Syy+Szz; K[0][1]=Syz-Szy;     K[0][2]=Szx-Sxz;      K[0][3]=Sxy-Syx;
    K[1][0]=K[0][1];     K[1][1]=Sxx-Syy-Szz; K[1][2]=Sxy+Syx;      K[1][3]=Szx+Sxz;
    K[2][0]=K[0][2];     K[2][1]=K[1][2];     K[2][2]=-Sxx+Syy-Szz; K[2][3]=Syz+Szy;
    K[3][0]=K[0][3];     K[3][1]=K[1][3];     K[3][2]=K[2][3];      K[3][3]=-Sxx-Syy+Szz;
    double V[4][4]={{1,0,0,0},{0,1,0,0},{0,0,1,0},{0,0,0,1}};
    for(int sweep=0;sweep<30;sweep++){
      for(int p=0;p<3;p++) for(int q=p+1;q<4;q++){
        double apq=K[p][q];
        if(fabs(apq)<1e-300) continue;
        double tau=(K[q][q]-K[p][p])/(2.0*apq);
        double t=(tau>=0.0?1.0:-1.0)/(fabs(tau)+sqrt(tau*tau+1.0));
        double cs=1.0/sqrt(t*t+1.0), sn=t*cs;
        for(int r2=0;r2<4;r2++){
          double krp=K[r2][p], krq=K[r2][q];
          K[r2][p]=cs*krp - sn*krq;
          K[r2][q]=sn*krp + cs*krq;
        }
        for(int r2=0;r2<4;r2++){
          double kpr=K[p][r2], kqr=K[q][r2];
          K[p][r2]=cs*kpr - sn*kqr;
          K[q][r2]=sn*kpr + cs*kqr;
        }
        for(int r2=0;r2<4;r2++){
          double vrp=V[r2][p], vrq=V[r2][q];
          V[r2][p]=cs*vrp - sn*vrq;
          V[r2][q]=sn*vrp + cs*vrq;
        }
      }
    }
    int mi=0;
    for(int i2=1;i2<4;i2++) if(K[i2][i2]>K[mi][mi]) mi=i2;
    double qw=V[0][mi], qx=V[1][mi], qy=V[2][mi], qz=V[3][mi];
    double Rh[3][3];
    Rh[0][0]=qw*qw+qx*qx-qy*qy-qz*qz; Rh[0][1]=2.0*(qx*qy-qw*qz);       Rh[0][2]=2.0*(qx*qz+qw*qy);
    Rh[1][0]=2.0*(qx*qy+qw*qz);       Rh[1][1]=qw*qw-qx*qx+qy*qy-qz*qz; Rh[1][2]=2.0*(qy*qz-qw*qx);
    Rh[2][0]=2.0*(qx*qz-qw*qy);       Rh[2][1]=2.0*(qy*qz+qw*qx);       Rh[2][2]=qw*qw-qx*qx-qy*qy+qz*qz;
    double objT=0.0, objN=0.0;
    for(int a=0;a<3;a++) for(int c=0;c<3;c++){ objT+=Rh[c][a]*Hm[a][c]; objN+=Rh[a][c]*Hm[a][c]; }
    double Rm[3][3];
    if(objT>=objN){
      for(int a=0;a<3;a++) for(int c=0;c<3;c++) Rm[a][c]=Rh[c][a];
    } else {
      for(int a=0;a<3;a++) for(int c=0;c<3;c++) Rm[a][c]=Rh[a][c];
    }
    double tt[3];
    for(int d=0;d<3;d++) tt[d]=c2[d] - (c1[0]*Rm[0][d]+c1[1]*Rm[1][d]+c1[2]*Rm[2][d]);
    const float* Rt = rot + b*9;
    double dsum=0.0;
    for(int a=0;a<3;a++) for(int c=0;c<3;c++){
      double dd = Rm[a][c] - (double)Rt[c*3+a];
      dsum += dd*dd;
    }
    double dock = dsum/9.0;
    double tsum=0.0;
    for(int d=0;d<3;d++){
      double tref = -((double)trans[b*3+0]*(double)Rt[d*3+0]+(double)trans[b*3+1]*(double)Rt[d*3+1]+(double)trans[b*3+2]*(double)Rt[d*3+2]);
      double dd = tt[d]-tref;
      tsum += dd*dd;
    }
    dock += tsum/3.0;
    otb[b]=ot; dockb[b]=dock;
    for(int a=0;a<3;a++) for(int d=0;d<3;d++) Rs[a*3+d]=Rm[a][d];
    for(int d=0;d<3;d++) ts[d]=tt[d];
  }
  __syncthreads();
  double part=0.0;
  for(int nidx=tid; nidx<NPP; nidx+=256){
    int i = b*2*NPP + nidx;
    double p0=Xca[i*3], p1=Xca[i*3+1], p2=Xca[i*3+2];
    double q0=p0*Rs[0]+p1*Rs[3]+p2*Rs[6]+ts[0];
    double q1=p0*Rs[1]+p1*Rs[4]+p2*Rs[7]+ts[1];
    double q2=p0*Rs[2]+p1*Rs[5]+p2*Rs[8]+ts[2];
    int o=(b*NPP+nidx)*3;
    x1a[o]=q0; x1a[o+1]=q1; x1a[o+2]=q2;
    double d0=q0-ori0[o], d1=q1-ori0[o+1], d2=q2-ori0[o+2];
    part += d0*d0+d1*d1+d2*d2;
  }
  red[tid]=part;
  __syncthreads();
  for(int st=128; st>0; st>>=1){ if(tid<st) red[tid]+=red[tid+st]; __syncthreads(); }
  if(tid==0) rmsdb[b]=red[0]/(double)(NPP*3);
}

// ------------------------------------------------------------------
// stab (f64): 1000 blocks, 8 rows x 32 lanes
// ------------------------------------------------------------------
__global__ __launch_bounds__(256) void k_stab(const double* __restrict__ x1a, const double* __restrict__ Xca,
    double* __restrict__ stabp){
  __shared__ double Bsm[NPP*3];
  __shared__ double red[8];
  int blk=blockIdx.x;
  int bd=blk/125, rg=blk%125;
  int b=bd>>1, dir=bd&1;
  int tid=threadIdx.x;
  const double* Ap = (dir==0) ? (x1a + (size_t)b*NPP*3) : (Xca + (size_t)(b*2+1)*NPP*3);
  const double* Bp = (dir==0) ? (Xca + (size_t)(b*2+1)*NPP*3) : (x1a + (size_t)b*NPP*3);
  for(int idx=tid; idx<NPP*3; idx+=256) Bsm[idx]=Bp[idx]*STDV;
  __syncthreads();
  int row = rg*8 + (tid>>5);
  int jt = tid&31;
  double a0=Ap[row*3]*STDV, a1=Ap[row*3+1]*STDV, a2=Ap[row*3+2]*STDV;
  double mind=1e300;
  for(int j=jt;j<NPP;j+=32){
    double d0=a0-Bsm[j*3], d1=a1-Bsm[j*3+1], d2=a2-Bsm[j*3+2];
    double d=d0*d0+d1*d1+d2*d2;
    mind=fmin(mind,d);
  }
  #pragma unroll
  for(int off=16;off>0;off>>=1) mind=fmin(mind,__shfl_xor(mind,off,32));
  double se=0.0;
  for(int j=jt;j<NPP;j+=32){
    double d0=a0-Bsm[j*3], d1=a1-Bsm[j*3+1], d2=a2-Bsm[j*3+2];
    double d=d0*d0+d1*d1+d2*d2;
    se += exp((mind-d)*(1.0/SIGC));
  }
  #pragma unroll
  for(int off=16;off>0;off>>=1) se += __shfl_xor(se,off,32);
  if(jt==0) red[tid>>5] = fmax(GAMC - mind + SIGC*log(se), 0.0);
  __syncthreads();
  if(tid==0){
    double s=0.0;
    #pragma unroll
    for(int i=0;i<8;i++) s+=red[i];
    stabp[blk]=s;
  }
}

__global__ void k_out(const double* __restrict__ otb, const double* __restrict__ dockb,
    const double* __restrict__ rmsdb, const double* __restrict__ stabp, float* __restrict__ out){
  if(blockIdx.x==0 && threadIdx.x==0){
    double ot=0.0,dock=0.0,rmsd=0.0,stab=0.0;
    for(int b=0;b<BSZ;b++){
      ot+=otb[b]; dock+=dockb[b]; rmsd+=rmsdb[b];
      double s1=0.0,s2=0.0;
      for(int i=0;i<125;i++){ s1+=stabp[(b*2+0)*125+i]; s2+=stabp[(b*2+1)*125+i]; }
      stab += (s1*(1.0/NPP) + s2*(1.0/NPP))*(1.0/STDV);
    }
    ot*=0.25; dock*=0.25; rmsd*=0.25; stab*=0.25;
    out[0]=(float)(ot+dock+stab); out[1]=(float)ot; out[2]=(float)dock; out[3]=(float)stab; out[4]=(float)rmsd;
  }
}

// ------------------------------------------------------------------
extern "C" void kernel_launch(void* const* d_in, const int* in_sizes, int n_in,
                              void* d_out, int out_size, void* d_ws, size_t ws_size,
                              hipStream_t stream){
  const float* X      = (const float*)d_in[0];
  const float* nodea  = (const float*)d_in[1];
  const float* edgea  = (const float*)d_in[2];
  const float* center = (const float*)d_in[3];
  const float* kpin   = (const float*)d_in[4];
  const float* rot    = (const float*)d_in[5];
  const float* trans  = (const float*)d_in[6];
  const float* W_in1  = (const float*)d_in[7];
  const float* b_in1  = (const float*)d_in[8];
  const float* W_in2  = (const float*)d_in[9];
  const float* b_in2  = (const float*)d_in[10];
  const float* msg_W  = (const float*)d_in[11];
  const float* msg_b  = (const float*)d_in[12];
  const float* upd_W1 = (const float*)d_in[13];
  const float* upd_b1 = (const float*)d_in[14];
  const float* upd_W2 = (const float*)d_in[15];
  const float* upd_b2 = (const float*)d_in[16];
  const float* x_W    = (const float*)d_in[17];
  const float* v_W    = (const float*)d_in[18];
  const float* att_W  = (const float*)d_in[19];
  const float* act_W1 = (const float*)d_in[20];
  const float* act_b1 = (const float*)d_in[21];
  const float* act_W2 = (const float*)d_in[22];
  const float* act_b2 = (const float*)d_in[23];
  const float* geb_Wv1= (const float*)d_in[24];
  const float* geb_Wv2= (const float*)d_in[25];
  const float* geb_W1 = (const float*)d_in[26];
  const float* geb_b1 = (const float*)d_in[27];
  const float* geb_W2 = (const float*)d_in[28];
  const float* geb_b2 = (const float*)d_in[29];
  const float* sc_W1  = (const float*)d_in[30];
  const float* sc_b1  = (const float*)d_in[31];
  const float* sc_W2  = (const float*)d_in[32];
  const float* sc_b2  = (const float*)d_in[33];
  const float* fin_W  = (const float*)d_in[34];
  const int*   src    = (const int*)d_in[35];
  const int*   dst    = (const int*)d_in[36];
  float* out = (float*)d_out;

  double* wd = (double*)d_ws;
  size_t o = 0;
  double* XcaD  = wd + o; o += (size_t)NN*3;
  double* ori0D = wd + o; o += (size_t)BSZ*NPP*3;
  double* kpcD  = wd + o; o += 144;
  double* tkpcD = wd + o; o += 144;
  double* dirvD = wd + o; o += (size_t)EE*3;
  double* rbfD  = wd + o; o += (size_t)EE*RBFD;
  double* hbuf  = wd + o; o += (size_t)NN*HD;
  double* Pbuf  = wd + o; o += (size_t)NN*256;
  double* mbuf  = wd + o; o += (size_t)EE*HD;   // re-used: h2 lives here now
  double* va    = wd + o; o += (size_t)NN*HD*3;
  double* vb    = wd + o; o += (size_t)NN*HD*3;
  double* ubuf  = wd + o; o += (size_t)BSZ*2*HD;
  double* attp  = wd + o; o += (size_t)64*HD;
  double* nv2b  = wd + o; o += (size_t)NN*HD;
  double* sbuf  = wd + o; o += (size_t)NN*256;
  double* cbbD  = wd + o; o += 24;
  double* ypartD= wd + o; o += (size_t)4000*37;
  double* YbufD = wd + o; o += 8*36;
  double* x1aD  = wd + o; o += (size_t)BSZ*NPP*3;
  double* otb_  = wd + o; o += 4;
  double* dkb_  = wd + o; o += 4;
  double* rmb_  = wd + o; o += 4;
  double* stp_  = wd + o; o += 1000;
  double* Wnode = wd + o; o += (size_t)4*128*256;
  double* Wedge2= wd + o; o += (size_t)4*37*128;
  double* xvW   = wd + o; o += (size_t)4*128*256;

  double* h2b  = mbuf;   // own buffer (must NOT alias P: other blocks still read P)

  size_t need = o*8;
  if(ws_size < need){
    float mb = (float)((double)ws_size / 1.0e6);
    float val = (131072.0f + mb) * 1048576.0f;
    k_sent<<<1,64,0,stream>>>(out, val);
    return;
  }

  hipMemsetAsync(va, 0, (size_t)NN*HD*3*sizeof(double), stream);

  k_cvt_node<<<512,256,0,stream>>>(msg_W, Wnode);
  k_cvt_edge<<<74,256,0,stream>>>(msg_W, msg_b, Wedge2);
  k_cvt_xv<<<256,256,0,stream>>>(x_W, v_W, xvW);

  k_geom<<<32,256,0,stream>>>(X, center, kpin, rot, trans, XcaD, ori0D, kpcD, tkpcD);
  k_edge<<<(EE+255)/256,256,0,stream>>>(XcaD, src, dst, dirvD, rbfD);
  k_hinit<<<NN/4,256,0,stream>>>(nodea, W_in1, b_in1, W_in2, b_in2, hbuf);

  double* vcur = va;
  double* vnxt = vb;
  for(int l=0;l<NL;l++){
    const double* Wn  = Wnode  + (size_t)l*128*256;
    const double* We  = Wedge2 + (size_t)l*37*128;
    const double* xvl = xvW    + (size_t)l*128*256;
    const float* u1W = upd_W1 + (size_t)l*256*HD;
    const float* u1b = upd_b1 + (size_t)l*HD;
    const float* u2W = upd_W2 + (size_t)l*HD*HD;
    const float* u2b = upd_b2 + (size_t)l*HD;
    const float* aWl = att_W  + (size_t)l*HD*HD;
    const float* a1W = act_W1 + (size_t)l*HD*HD;
    const float* a1b = act_b1 + (size_t)l*HD;
    const float* a2W = act_W2 + (size_t)l*HD*HD;
    const float* a2b = act_b2 + (size_t)l*HD;

    k_nodeproj<<<NN/4,128,0,stream>>>(hbuf, Wn, Pbuf);
    k_layer<<<NN/4,256,0,stream>>>(Pbuf, rbfD, edgea, src, We,
                                   hbuf, u1W, u1b, u2W, u2b, h2b,
                                   vcur, dirvD, xvl, vnxt);
    k_att1<<<64,128,0,stream>>>(h2b, attp);
    k_att2<<<8,128,0,stream>>>(attp, aWl, ubuf);
    k_actcomb<<<NN/4,128,0,stream>>>(h2b, ubuf, a1W, a1b, a2W, a2b, hbuf);
    double* tmp=vcur; vcur=vnxt; vnxt=tmp;
  }
  // vcur == va (final v), vnxt == vb (free -> v1)
  k_gebv<<<NN/2,256,0,stream>>>(vcur, geb_Wv1, geb_Wv2, vnxt, nv2b);
  k_gebs<<<NN/4,256,0,stream>>>(hbuf, nv2b, geb_W1, geb_b1, geb_W2, geb_b2, sbuf);
  k_kpc<<<8,256,0,stream>>>(XcaD, cbbD);
  k_kpgen<<<NN/2,256,0,stream>>>(XcaD, sbuf, vnxt, cbbD, fin_W, sc_W1, sc_b1, sc_W2, sc_b2, ypartD);
  k_kpfin<<<8,64,0,stream>>>(ypartD, cbbD, YbufD);
  k_final<<<BSZ,256,0,stream>>>(YbufD, tkpcD, kpcD, rot, trans, XcaD, ori0D, x1aD, otb_, dkb_, rmb_);
  k_stab<<<1000,256,0,stream>>>(x1aD, XcaD, stp_);
  k_out<<<1,64,0,stream>>>(otb_, dkb_, rmb_, stp_, out);
}

// Round 15
// 1551.788 us; speedup vs baseline: 1.5162x; 1.0024x over previous
//
#include <hip/hip_runtime.h>
#include <math.h>

#define NPP 1000
#define BSZ 4
#define HD 128
#define NL 4
#define RBFD 20
#define EDD 16
#define KN 9
#define NKPP 12
#define NN 8000
#define EE 72000
#define STDV 10.0
#define SIGC 25.0
#define GAMC 10.0
#define PID 3.14159265358979323846

__device__ __forceinline__ double silud(double x){ return x / (1.0 + exp(-x)); }

__global__ void k_sent(float* __restrict__ out, float val){
  if(threadIdx.x<5 && blockIdx.x==0) out[threadIdx.x]=val;
}

// ------------------------------------------------------------------
// weight preconversion to f64
// ------------------------------------------------------------------
__global__ __launch_bounds__(256) void k_cvt_node(const float* __restrict__ msgW, double* __restrict__ Wn){
  int idx = blockIdx.x*256+threadIdx.x;
  if(idx >= 4*128*256) return;
  int l = idx>>15; int r = idx & 32767; int k = r>>8; int j = r&255;
  const float* W = msgW + (size_t)l*292*128;
  Wn[idx] = (j<128) ? (double)W[k*128+j] : (double)W[(128+k)*128 + (j-128)];
}
__global__ __launch_bounds__(256) void k_cvt_edge(const float* __restrict__ msgW, const float* __restrict__ msgb,
    double* __restrict__ We){
  int idx = blockIdx.x*256+threadIdx.x;
  if(idx >= 4*37*128) return;
  int l = idx/(37*128); int r = idx%(37*128); int k = r>>7; int j = r&127;
  if(k<36) We[idx] = (double)msgW[(size_t)l*292*128 + (256+k)*128 + j];
  else     We[idx] = (double)msgb[l*128 + j];
}
__global__ __launch_bounds__(256) void k_cvt_xv(const float* __restrict__ xW, const float* __restrict__ vW,
    double* __restrict__ xv){
  int idx = blockIdx.x*256+threadIdx.x;
  if(idx >= 4*128*128) return;
  int l = idx>>14; int r = idx & 16383; int hh = r>>7; int c = r&127;
  xv[(size_t)l*32768 + hh*256 + 2*c]   = (double)xW[(size_t)l*16384 + hh*128 + c];
  xv[(size_t)l*32768 + hh*256 + 2*c+1] = (double)vW[(size_t)l*16384 + hh*128 + c];
}

// ------------------------------------------------------------------
// geometry (f64)
// ------------------------------------------------------------------
__global__ __launch_bounds__(256) void k_geom(const float* __restrict__ X, const float* __restrict__ center,
    const float* __restrict__ kpin, const float* __restrict__ rot, const float* __restrict__ trans,
    double* __restrict__ Xca, double* __restrict__ ori0, double* __restrict__ kpc, double* __restrict__ tkpc){
  int i = blockIdx.x*256 + threadIdx.x;
  const double inv = 1.0/STDV;
  if(i < NN){
    int b = i / (2*NPP);
    int s = (i / NPP) & 1;
    int n = i % NPP;
    double q0 = (double)X[i*12+3] - (double)center[b*3+0];
    double q1 = (double)X[i*12+4] - (double)center[b*3+1];
    double q2 = (double)X[i*12+5] - (double)center[b*3+2];
    if(s==0){
      int o=(b*NPP+n)*3;
      ori0[o]=q0*inv; ori0[o+1]=q1*inv; ori0[o+2]=q2*inv;
      const float* R = rot + b*9;
      #pragma unroll
      for(int d=0; d<3; d++)
        Xca[i*3+d] = (q0*(double)R[d] + q1*(double)R[3+d] + q2*(double)R[6+d])*inv + (double)trans[b*3+d];
    } else {
      Xca[i*3+0]=q0*inv; Xca[i*3+1]=q1*inv; Xca[i*3+2]=q2*inv;
    }
  } else if(i < NN + BSZ*NKPP){
    int j = i - NN;
    int b = j / NKPP;
    double q0 = (double)kpin[j*3+0]-(double)center[b*3+0];
    double q1 = (double)kpin[j*3+1]-(double)center[b*3+1];
    double q2 = (double)kpin[j*3+2]-(double)center[b*3+2];
    kpc[j*3+0]=q0*inv; kpc[j*3+1]=q1*inv; kpc[j*3+2]=q2*inv;
    const float* R = rot + b*9;
    #pragma unroll
    for(int d=0; d<3; d++)
      tkpc[j*3+d] = (q0*(double)R[d] + q1*(double)R[3+d] + q2*(double)R[6+d])*inv + (double)trans[b*3+d];
  }
}

// ------------------------------------------------------------------
__global__ __launch_bounds__(256) void k_edge(const double* __restrict__ Xca, const int* __restrict__ src,
    const int* __restrict__ dst, double* __restrict__ dirv, double* __restrict__ rbfb){
  int e = blockIdx.x*256 + threadIdx.x;
  if(e >= EE) return;
  int sp = src[e], dp = dst[e];
  double d0 = Xca[dp*3+0]-Xca[sp*3+0];
  double d1 = Xca[dp*3+1]-Xca[sp*3+1];
  double d2 = Xca[dp*3+2]-Xca[sp*3+2];
  double nr = sqrt(d0*d0+d1*d1+d2*d2) + 1e-08;
  double iv = 1.0/nr;
  dirv[e*3+0]=d0*iv; dirv[e*3+1]=d1*iv; dirv[e*3+2]=d2*iv;
  #pragma unroll
  for(int j=0;j<RBFD;j++)
    rbfb[e*RBFD+j] = sin(nr*(double)(j+1)*PID)*iv;
}

// ------------------------------------------------------------------
// h init: 4 nodes/block, 256 thr
// ------------------------------------------------------------------
__global__ __launch_bounds__(256) void k_hinit(const float* __restrict__ na,
    const float* __restrict__ W1, const float* __restrict__ b1,
    const float* __restrict__ W2, const float* __restrict__ b2, double* __restrict__ h){
  __shared__ double cin[4][64];
  __shared__ double hmid[4][128];
  int n0 = blockIdx.x*4;
  int tid = threadIdx.x;
  {
    int r=tid>>6, k=tid&63;
    cin[r][k] = (double)na[(n0+r)*64 + k];
  }
  __syncthreads();
  int r = tid>>6, c0 = (tid&63)*2;
  double a0=(double)b1[c0], a1=(double)b1[c0+1];
  for(int k=0;k<64;k++){
    double a = cin[r][k];
    const float* wp = W1 + k*HD + c0;
    a0 += a*(double)wp[0]; a1 += a*(double)wp[1];
  }
  hmid[r][c0]=silud(a0); hmid[r][c0+1]=silud(a1);
  __syncthreads();
  double s0=(double)b2[c0], s1=(double)b2[c0+1];
  for(int k=0;k<HD;k++){
    double a = hmid[r][k];
    const float* wp = W2 + k*HD + c0;
    s0 += a*(double)wp[0]; s1 += a*(double)wp[1];
  }
  h[(size_t)(n0+r)*HD+c0]=s0; h[(size_t)(n0+r)*HD+c0+1]=s1;
}

// ------------------------------------------------------------------
// node projection: 8 nodes/block, 256 thr; half=tid>>7 handles 4 nodes,
// c0=(tid&127)*2 -> Wn read once per block (halved L2 traffic)
// ------------------------------------------------------------------
__global__ __launch_bounds__(256) void k_nodeproj(const double* __restrict__ h, const double* __restrict__ Wn,
    double* __restrict__ P){
  __shared__ double cin[8][128];
  int n0 = blockIdx.x*8;
  int tid = threadIdx.x;
  for(int idx=tid; idx<1024; idx+=256){
    int r=idx>>7, k=idx&127;
    cin[r][k]=h[(size_t)(n0+r)*HD+k];
  }
  __syncthreads();
  int half = tid>>7;
  int r0 = half*4;
  int c0 = (tid&127)*2;
  double a00=0,a01=0,a10=0,a11=0,a20=0,a21=0,a30=0,a31=0;
  for(int k=0;k<128;k++){
    double2 w = *(const double2*)(Wn + (size_t)k*256 + c0);
    double x0=cin[r0+0][k],x1=cin[r0+1][k],x2=cin[r0+2][k],x3=cin[r0+3][k];
    a00+=x0*w.x; a01+=x0*w.y; a10+=x1*w.x; a11+=x1*w.y;
    a20+=x2*w.x; a21+=x2*w.y; a30+=x3*w.x; a31+=x3*w.y;
  }
  P[(size_t)(n0+r0+0)*256+c0]=a00; P[(size_t)(n0+r0+0)*256+c0+1]=a01;
  P[(size_t)(n0+r0+1)*256+c0]=a10; P[(size_t)(n0+r0+1)*256+c0+1]=a11;
  P[(size_t)(n0+r0+2)*256+c0]=a20; P[(size_t)(n0+r0+2)*256+c0+1]=a21;
  P[(size_t)(n0+r0+3)*256+c0]=a30; P[(size_t)(n0+r0+3)*256+c0+1]=a31;
}

// ------------------------------------------------------------------
// fused layer kernel: edge messages (into LDS) + upd-MLP + v-update
// 4 nodes/block, 256 thr (half=tid>>7, colp=tid&127)
// ------------------------------------------------------------------
__global__ __launch_bounds__(256) void k_layer(
    const double* __restrict__ P, const double* __restrict__ rbfb, const float* __restrict__ ea,
    const int* __restrict__ src, const double* __restrict__ We,
    const double* __restrict__ h, const float* __restrict__ W1, const float* __restrict__ b1,
    const float* __restrict__ W2, const float* __restrict__ b2, double* __restrict__ h2,
    const double* __restrict__ va, const double* __restrict__ dirv, const double* __restrict__ xv,
    double* __restrict__ vb){
  __shared__ double mT[4][9][128];     // 36 KB, live all phases
  __shared__ double scratch[1536];     // 12 KB: feat | cin+hmid | md
  __shared__ double dv[4][9][3];
  __shared__ int sp[4][9];
  int n0 = blockIdx.x*4;
  int tid = threadIdx.x;
  int e0 = n0*KN;
  for(int idx=tid; idx<36*RBFD; idx+=256){
    int e=idx/RBFD, f=idx-e*RBFD;
    scratch[e*37+f] = rbfb[(size_t)(e0+e)*RBFD+f];
  }
  for(int idx=tid; idx<36*EDD; idx+=256){
    int e=idx>>4, f=idx&15;
    scratch[e*37+20+f] = (double)ea[(size_t)(e0+e)*EDD+f];
  }
  if(tid<36){
    scratch[tid*37+36]=1.0;
    int nd=tid/9, kk=tid-nd*9;
    int e=e0+nd*9+kk;
    sp[nd][kk]=src[e];
    dv[nd][kk][0]=dirv[e*3]; dv[nd][kk][1]=dirv[e*3+1]; dv[nd][kk][2]=dirv[e*3+2];
  }
  int half = tid>>7, colp = tid&127;
  double wreg[37];
  #pragma unroll
  for(int f=0;f<37;f++) wreg[f]=We[f*128+colp];
  __syncthreads();
  // ---- phase A
  double aggv0=0.0, aggv1=0.0;
  {
    int nd = half*2;
    double p2 = P[(size_t)(n0+nd)*256 + 128 + colp];
    double agg=0.0;
    for(int kk=0;kk<9;kk++){
      const double* fe = &scratch[(nd*9+kk)*37];
      double acc=0.0;
      #pragma unroll
      for(int f=0;f<37;f++) acc += fe[f]*wreg[f];
      double mv_ = silud(acc + P[(size_t)sp[nd][kk]*256 + colp] + p2);
      mT[nd][kk][colp]=mv_;
      agg += mv_;
    }
    aggv0=agg;
  }
  {
    int nd = half*2+1;
    double p2 = P[(size_t)(n0+nd)*256 + 128 + colp];
    double agg=0.0;
    for(int kk=0;kk<9;kk++){
      const double* fe = &scratch[(nd*9+kk)*37];
      double acc=0.0;
      #pragma unroll
      for(int f=0;f<37;f++) acc += fe[f]*wreg[f];
      double mv_ = silud(acc + P[(size_t)sp[nd][kk]*256 + colp] + p2);
      mT[nd][kk][colp]=mv_;
      agg += mv_;
    }
    aggv1=agg;
  }
  __syncthreads();
  {
    int ndA = half*2, ndB = ndA+1;
    scratch[ndA*256+colp]     = h[(size_t)(n0+ndA)*HD+colp];
    scratch[ndA*256+128+colp] = aggv0;
    scratch[ndB*256+colp]     = h[(size_t)(n0+ndB)*HD+colp];
    scratch[ndB*256+128+colp] = aggv1;
  }
  __syncthreads();
  // ---- phase B
  {
    int ndA = half*2, ndB = ndA+1;
    double bb=(double)b1[colp];
    double a0=bb, a1=bb;
    for(int k=0;k<256;k++){
      double w = (double)W1[(size_t)k*HD+colp];
      a0 += scratch[ndA*256+k]*w;
      a1 += scratch[ndB*256+k]*w;
    }
    scratch[1024+ndA*128+colp]=silud(a0);
    scratch[1024+ndB*128+colp]=silud(a1);
  }
  __syncthreads();
  {
    int ndA = half*2, ndB = ndA+1;
    double bb=(double)b2[colp];
    double a0=bb, a1=bb;
    for(int k=0;k<128;k++){
      double w = (double)W2[(size_t)k*HD+colp];
      a0 += scratch[1024+ndA*128+k]*w;
      a1 += scratch[1024+ndB*128+k]*w;
    }
    h2[(size_t)(n0+ndA)*HD+colp] = scratch[ndA*256+colp] + a0;
    h2[(size_t)(n0+ndB)*HD+colp] = scratch[ndB*256+colp] + a1;
  }
  __syncthreads();
  // ---- phase C: md then v-update, hh unrolled x2 (per-accumulator order preserved)
  for(int idx=tid; idx<1536; idx+=256){
    int hh=idx&127, t2=idx>>7; int nd=t2/3, c=t2-nd*3;
    double s=0.0;
    #pragma unroll
    for(int kk=0;kk<9;kk++) s += dv[nd][kk][c]*mT[nd][kk][hh];
    scratch[nd*384 + c*128 + hh]=s;
  }
  __syncthreads();
  int nd = tid>>6;            // wave-uniform
  int t  = tid&63;
  int c0 = 2*t;
  double oA0=0,oA1=0,oA2=0, oB0=0,oB1=0,oB2=0;
  double mvA[9], mvB[9];
  #pragma unroll
  for(int kk=0;kk<9;kk++){ mvA[kk]=0.0; mvB[kk]=0.0; }
  const double* mdb = &scratch[nd*384];
  for(int hh=0; hh<128; hh+=2){
    const double* xp0 = xv + (size_t)hh*256 + 2*c0;
    const double* xp1 = xp0 + 256;
    double2 wpA0 = *(const double2*)(xp0);
    double2 wpB0 = *(const double2*)(xp0+2);
    double2 wpA1 = *(const double2*)(xp1);
    double2 wpB1 = *(const double2*)(xp1+2);
    double d00 = mdb[hh],     d10 = mdb[128+hh],   d20 = mdb[256+hh];
    double d01 = mdb[hh+1],   d11 = mdb[128+hh+1], d21 = mdb[256+hh+1];
    oA0 += d00*wpA0.x; oA1 += d10*wpA0.x; oA2 += d20*wpA0.x;
    oB0 += d00*wpB0.x; oB1 += d10*wpB0.x; oB2 += d20*wpB0.x;
    oA0 += d01*wpA1.x; oA1 += d11*wpA1.x; oA2 += d21*wpA1.x;
    oB0 += d01*wpB1.x; oB1 += d11*wpB1.x; oB2 += d21*wpB1.x;
    #pragma unroll
    for(int kk=0;kk<9;kk++){
      double mk0 = mT[nd][kk][hh];
      double mk1 = mT[nd][kk][hh+1];
      mvA[kk] += mk0*wpA0.y;
      mvB[kk] += mk0*wpB0.y;
      mvA[kk] += mk1*wpA1.y;
      mvB[kk] += mk1*wpB1.y;
    }
  }
  #pragma unroll
  for(int kk=0;kk<9;kk++){
    size_t s3 = (size_t)sp[nd][kk]*384 + c0*3;
    double ka = mvA[kk], kb = mvB[kk];
    oA0 += va[s3]*ka;   oA1 += va[s3+1]*ka; oA2 += va[s3+2]*ka;
    oB0 += va[s3+3]*kb; oB1 += va[s3+4]*kb; oB2 += va[s3+5]*kb;
  }
  size_t b3 = (size_t)(n0+nd)*384 + c0*3;
  vb[b3]  = va[b3]  + oA0;
  vb[b3+1]= va[b3+1]+ oA1;
  vb[b3+2]= va[b3+2]+ oA2;
  vb[b3+3]= va[b3+3]+ oB0;
  vb[b3+4]= va[b3+4]+ oB1;
  vb[b3+5]= va[b3+5]+ oB2;
}

// ------------------------------------------------------------------
// attention partials + finish
// ------------------------------------------------------------------
__global__ __launch_bounds__(128) void k_att1(const double* __restrict__ h2, double* __restrict__ partial){
  int blk = blockIdx.x;
  int bs = blk>>3, ch = blk&7;
  int col = threadIdx.x;
  size_t base = ((size_t)bs*NPP + ch*125)*HD + col;
  double s=0.0;
  for(int i=0;i<125;i++) s += h2[base + (size_t)i*HD];
  partial[(size_t)blk*HD + col] = s;
}
__global__ __launch_bounds__(128) void k_att2(const double* __restrict__ partial, const float* __restrict__ attW,
    double* __restrict__ u){
  __shared__ double mm[128];
  int bs = blockIdx.x;
  int col = threadIdx.x;
  int os = bs^1;
  double s=0.0;
  for(int c=0;c<8;c++) s += partial[(size_t)(os*8+c)*HD + col];
  mm[col] = s*(1.0/NPP);
  __syncthreads();
  double acc=0.0;
  for(int k=0;k<HD;k++) acc += (double)attW[col*HD+k]*mm[k];
  u[bs*HD+col] = acc;
}

// ------------------------------------------------------------------
// h_new = intra + g*act(intra), g fused
// ------------------------------------------------------------------
__global__ __launch_bounds__(128) void k_actcomb(const double* __restrict__ h2, const double* __restrict__ u,
    const float* __restrict__ W1, const float* __restrict__ b1,
    const float* __restrict__ W2, const float* __restrict__ b2, double* __restrict__ h){
  __shared__ double As[4][128];
  __shared__ double hmid[4][128];
  __shared__ double pd[128];
  __shared__ double gsh[4];
  int n0 = blockIdx.x*4;
  int tid = threadIdx.x;
  int bs = n0/NPP;
  for(int idx=tid; idx<512; idx+=128){
    int r=idx>>7, k=idx&127;
    As[r][k] = h2[(size_t)(n0+r)*HD+k];
  }
  __syncthreads();
  {
    int nd=tid>>5, q=tid&31;
    double p=0.0;
    for(int j=q;j<128;j+=32) p += As[nd][j]*u[bs*HD+j];
    pd[tid]=p;
  }
  __syncthreads();
  if((tid&31)==0){
    int nd=tid>>5;
    double s=0.0;
    for(int i2=0;i2<32;i2++) s+=pd[nd*32+i2];
    gsh[nd]=1.0/(1.0+exp(-s));
  }
  __syncthreads();
  int col = tid;
  double bb=(double)b1[col];
  double a0=bb,a1=bb,a2=bb,a3=bb;
  for(int k=0;k<128;k++){
    double w = (double)W1[(size_t)k*HD+col];
    a0 += As[0][k]*w; a1 += As[1][k]*w; a2 += As[2][k]*w; a3 += As[3][k]*w;
  }
  hmid[0][col]=silud(a0); hmid[1][col]=silud(a1); hmid[2][col]=silud(a2); hmid[3][col]=silud(a3);
  __syncthreads();
  bb=(double)b2[col];
  a0=bb;a1=bb;a2=bb;a3=bb;
  for(int k=0;k<128;k++){
    double w = (double)W2[(size_t)k*HD+col];
    a0 += hmid[0][k]*w; a1 += hmid[1][k]*w; a2 += hmid[2][k]*w; a3 += hmid[3][k]*w;
  }
  h[(size_t)(n0+0)*HD+col] = As[0][col] + gsh[0]*a0;
  h[(size_t)(n0+1)*HD+col] = As[1][col] + gsh[1]*a1;
  h[(size_t)(n0+2)*HD+col] = As[2][col] + gsh[2]*a2;
  h[(size_t)(n0+3)*HD+col] = As[3][col] + gsh[3]*a3;
}

// ------------------------------------------------------------------
// geb vector branch
// ------------------------------------------------------------------
__global__ __launch_bounds__(256) void k_gebv(const double* __restrict__ va,
    const float* __restrict__ Wv1, const float* __restrict__ Wv2,
    double* __restrict__ v1, double* __restrict__ nv2){
  __shared__ double vl[2][384];
  int n0 = blockIdx.x*2;
  int tid = threadIdx.x;
  for(int idx=tid; idx<768; idx+=256){
    int r=idx/384, k=idx%384;
    vl[r][k] = va[(size_t)(n0+r)*384+k];
  }
  __syncthreads();
  int r = tid>>7, col = tid&127;
  double a10=0.0,a11=0.0,a12=0.0, a20=0.0,a21=0.0,a22=0.0;
  for(int hh=0; hh<HD; hh++){
    double w1 = (double)Wv1[hh*HD+col];
    double w2 = (double)Wv2[hh*HD+col];
    double v0=vl[r][hh*3], v1e=vl[r][hh*3+1], v2e=vl[r][hh*3+2];
    a10+=v0*w1; a11+=v1e*w1; a12+=v2e*w1;
    a20+=v0*w2; a21+=v1e*w2; a22+=v2e*w2;
  }
  size_t b3=(size_t)(n0+r)*384+col*3;
  v1[b3]=a10; v1[b3+1]=a11; v1[b3+2]=a12;
  nv2[(size_t)(n0+r)*HD+col]=sqrt(a20*a20+a21*a21+a22*a22);
}

// ------------------------------------------------------------------
// s = silu([h,nv2]@gebW1+b1)@gebW2+b2
// ------------------------------------------------------------------
__global__ __launch_bounds__(256) void k_gebs(const double* __restrict__ h, const double* __restrict__ nv2,
    const float* __restrict__ W1, const float* __restrict__ b1,
    const float* __restrict__ W2, const float* __restrict__ b2, double* __restrict__ s){
  __shared__ double cin[4][256];
  __shared__ double hmid[4][128];
  int n0 = blockIdx.x*4;
  int tid = threadIdx.x;
  for(int idx=tid; idx<4*HD; idx+=256){
    int r=idx>>7, k=idx&127;
    cin[r][k]    = h[(size_t)(n0+r)*HD + k];
    cin[r][HD+k] = nv2[(size_t)(n0+r)*HD + k];
  }
  __syncthreads();
  int r = tid>>6, c0 = (tid&63)*2;
  double a0=(double)b1[c0], a1=(double)b1[c0+1];
  for(int k=0;k<2*HD;k++){
    double a = cin[r][k];
    const float* wp = W1 + (size_t)k*HD + c0;
    a0 += a*(double)wp[0]; a1 += a*(double)wp[1];
  }
  hmid[r][c0]=silud(a0); hmid[r][c0+1]=silud(a1);
  __syncthreads();
  int c1 = (tid&63)*4;
  double s0=(double)b2[c1], s1=(double)b2[c1+1], s2=(double)b2[c1+2], s3=(double)b2[c1+3];
  for(int k=0;k<HD;k++){
    double a = hmid[r][k];
    const float* wp = W2 + (size_t)k*256 + c1;
    s0 += a*(double)wp[0]; s1 += a*(double)wp[1]; s2 += a*(double)wp[2]; s3 += a*(double)wp[3];
  }
  double* srow = s + (size_t)(n0+r)*256 + c1;
  srow[0]=s0; srow[1]=s1; srow[2]=s2; srow[3]=s3;
}

// ------------------------------------------------------------------
__global__ __launch_bounds__(256) void k_kpc(const double* __restrict__ Xca, double* __restrict__ cbb){
  __shared__ double red[768];
  int bs = blockIdx.x;
  int tid = threadIdx.x;
  double s0=0.0,s1=0.0,s2=0.0;
  for(int nidx=tid; nidx<NPP; nidx+=256){
    int i = bs*NPP+nidx;
    s0+=Xca[i*3]; s1+=Xca[i*3+1]; s2+=Xca[i*3+2];
  }
  red[tid]=s0; red[256+tid]=s1; red[512+tid]=s2;
  __syncthreads();
  for(int st=128; st>0; st>>=1){
    if(tid<st){ red[tid]+=red[tid+st]; red[256+tid]+=red[256+tid+st]; red[512+tid]+=red[512+tid+st]; }
    __syncthreads();
  }
  if(tid==0){ cbb[bs*3]=red[0]*(1.0/NPP); cbb[bs*3+1]=red[256]*(1.0/NPP); cbb[bs*3+2]=red[512]*(1.0/NPP); }
}

// ------------------------------------------------------------------
// keypoint partials: 2 nodes/block
// ------------------------------------------------------------------
__global__ __launch_bounds__(256) void k_kpgen(const double* __restrict__ Xca, const double* __restrict__ sbuf,
    const double* __restrict__ v1, const double* __restrict__ cbb, const float* __restrict__ fW,
    const float* __restrict__ sW1, const float* __restrict__ sb1, const float* __restrict__ sW2,
    const float* __restrict__ sb2, double* __restrict__ ypart){
  __shared__ double tt[2][3][128];
  __shared__ double ssv[2][128];
  __shared__ double zz[2][64];
  __shared__ double snorm[2];
  __shared__ double ylL[2][37];
  int blk = blockIdx.x;
  int tid = threadIdx.x;
  int r = tid>>7, t = tid&127;
  int n = blk*2 + r;
  int bs = n/NPP;
  const double* srow = sbuf + (size_t)n*256;
  const double* vrow = v1 + (size_t)n*384;
  double gate = srow[128+t];
  double hp = srow[t];
  double vf0 = vrow[t*3+0]*gate, vf1 = vrow[t*3+1]*gate, vf2 = vrow[t*3+2]*gate;
  tt[r][0][t]=vf0*hp; tt[r][1][t]=vf1*hp; tt[r][2][t]=vf2*hp;
  ssv[r][t]=sqrt(vf0*vf0+vf1*vf1+vf2*vf2);
  if(t==0){
    double x0=Xca[n*3]-cbb[bs*3], x1=Xca[n*3+1]-cbb[bs*3+1], x2=Xca[n*3+2]-cbb[bs*3+2];
    snorm[r]=sqrt(x0*x0+x1*x1+x2*x2);
  }
  __syncthreads();
  if(t<36){
    int k2=t/3, c=t%3;
    double a=0.0;
    for(int hh=0; hh<128; hh++) a += tt[r][c][hh]*(double)fW[hh*NKPP+k2];
    ylL[r][t]=a;
  } else if(t>=64){
    int j=t-64;
    double z=(double)sb1[j];
    for(int hh=0; hh<128; hh++) z += ssv[r][hh]*(double)sW1[hh*64+j];
    z += snorm[r]*(double)sW1[128*64+j];
    zz[r][j]=silud(z)*(double)sW2[j];
  }
  __syncthreads();
  if(t==36){
    double dn=(double)sb2[0];
    for(int j=0;j<64;j++) dn+=zz[r][j];
    ylL[r][36]=dn;
  }
  __syncthreads();
  if(tid<37) ypart[(size_t)blk*37+tid]=ylL[0][tid]+ylL[1][tid];
}

__global__ __launch_bounds__(64) void k_kpfin(const double* __restrict__ ypart,
    const double* __restrict__ cbb, double* __restrict__ Y){
  __shared__ double sums[37];
  int bs=blockIdx.x, tid=threadIdx.x;
  if(tid<37){
    double s=0.0;
    for(int i=0;i<500;i++) s += ypart[(size_t)(bs*500+i)*37 + tid];
    sums[tid]=s;
  }
  __syncthreads();
  if(tid<36){
    double dsh = sums[36]*(1.0/NPP);
    Y[bs*36+tid] = sums[tid]/dsh + cbb[bs*3 + tid%3];
  }
}

// ------------------------------------------------------------------
// per-sample: ot, Kabsch (Horn quaternion), dock, rmsd, X1a
// ------------------------------------------------------------------
__global__ __launch_bounds__(256) void k_final(const double* __restrict__ Y, const double* __restrict__ tkpc,
    const double* __restrict__ kpc, const float* __restrict__ rot, const float* __restrict__ trans,
    const double* __restrict__ Xca, const double* __restrict__ ori0,
    double* __restrict__ x1a, double* __restrict__ otb, double* __restrict__ dockb, double* __restrict__ rmsdb){
  int b = blockIdx.x;
  int tid = threadIdx.x;
  __shared__ double Rs[9];
  __shared__ double ts[3];
  __shared__ double red[256];
  if(tid==0){
    const double* Y1 = Y + (b*2+0)*36;
    const double* Y2 = Y + (b*2+1)*36;
    const double* P1 = tkpc + b*36;
    const double* P2 = kpc + b*36;
    double ot1=0.0, ot2=0.0;
    for(int i=0;i<12;i++){
      double best1=1e300, best2=1e300;
      for(int j=0;j<12;j++){
        double d1=0.0, d2=0.0;
        #pragma unroll
        for(int c=0;c<3;c++){
          double e1=Y1[i*3+c]-P1[j*3+c]; d1+=e1*e1;
          double e2=Y2[i*3+c]-P2[j*3+c]; d2+=e2*e2;
        }
        best1=fmin(best1,d1); best2=fmin(best2,d2);
      }
      ot1+=best1; ot2+=best2;
    }
    double ot = ot1*(1.0/36.0) + ot2*(1.0/36.0);
    double c1[3]={0,0,0}, c2[3]={0,0,0};
    for(int i=0;i<12;i++)
      for(int c=0;c<3;c++){ c1[c]+=Y1[i*3+c]; c2[c]+=Y2[i*3+c]; }
    for(int c=0;c<3;c++){ c1[c]/=12.0; c2[c]/=12.0; }
    double Hm[3][3]={{0,0,0},{0,0,0},{0,0,0}};
    for(int i=0;i<12;i++)
      for(int a=0;a<3;a++)
        for(int c=0;c<3;c++)
          Hm[a][c] += (Y1[i*3+a]-c1[a])*(Y2[i*3+c]-c2[c]);
    double Sxx=Hm[0][0],Sxy=Hm[0][1],Sxz=Hm[0][2];
    double Syx=Hm[1][0],Syy=Hm[1][1],Syz=Hm[1][2];
    double Szx=Hm[2][0],Szy=Hm[2][1],Szz=Hm[2][2];
    double K[4][4];
    K[0][0]=Sxx+Syy+Szz; K[0][1]=Syz-Szy;     K[0][2]=Szx-Sxz;      K[0][3]=Sxy-Syx;
    K[1][0]=K[0][1];     K[1][1]=Sxx-Syy-Szz; K[1][2]=Sxy+Syx;      K[1][3]=Szx+Sxz;
    K[2][0]=K[0][2];     K[2][1]=K[1][2];     K[2][2]=-Sxx+Syy-Szz; K[2][3]=Syz+Szy;
    K[3][0]=K[0][3];     K[3][1]=K[1][3];     K[3][2]=K[2][3];      K[3][3]=-Sxx-Syy+Szz;
    double V[4][4]={{1,0,0,0},{0,1,0,0},{0,0,1,0},{0,0,0,1}};
    for(int sweep=0;sweep<30;sweep++){
      for(int p=0;p<3;p++) for(int q=p+1;q<4;q++){
        double apq=K[p][q];
        if(fabs(apq)<1e-300) continue;
        double tau=(K[q][q]-K[p][p])/(2.0*apq);
        double t=(tau>=0.0?1.0:-1.0)/(fabs(tau)+sqrt(tau*tau+1.0));
        double cs=1.0/sqrt(t*t+1.0), sn=t*cs;
        for(int r2=0;r2<4;r2++){
          double krp=K[r2][p], krq=K[r2][q];
          K[r2][p]=cs*krp - sn*krq;
          K[r2][q]=sn*krp + cs*krq;
        }
        for(int r2=0;r2<4;r2++){
          double kpr=K[p][r2], kqr=K[q][r2];
          K[p][r2]=cs*kpr - sn*kqr;
          K[q][r2]=sn*kpr + cs*kqr;
        }
        for(int r2=0;r2<4;r2++){
          double vrp=V[r2][p], vrq=V[r2][q];
          V[r2][p]=cs*vrp - sn*vrq;
          V[r2][q]=sn*vrp + cs*vrq;
        }
      }
    }
    int mi=0;
    for(int i2=1;i2<4;i2++) if(K[i2][i2]>K[mi][mi]) mi=i2;
    double qw=V[0][mi], qx=V[1][mi], qy=V[2][mi], qz=V[3][mi];
    double Rh[3][3];
    Rh[0][0]=qw*qw+qx*qx-qy*qy-qz*qz; Rh[0][1]=2.0*(qx*qy-qw*qz);       Rh[0][2]=2.0*(qx*qz+qw*qy);
    Rh[1][0]=2.0*(qx*qy+qw*qz);       Rh[1][1]=qw*qw-qx*qx+qy*qy-qz*qz; Rh[1][2]=2.0*(qy*qz-qw*qx);
    Rh[2][0]=2.0*(qx*qz-qw*qy);       Rh[2][1]=2.0*(qy*qz+qw*qx);       Rh[2][2]=qw*qw-qx*qx-qy*qy+qz*qz;
    double objT=0.0, objN=0.0;
    for(int a=0;a<3;a++) for(int c=0;c<3;c++){ objT+=Rh[c][a]*Hm[a][c]; objN+=Rh[a][c]*Hm[a][c]; }
    double Rm[3][3];
    if(objT>=objN){
      for(int a=0;a<3;a++) for(int c=0;c<3;c++) Rm[a][c]=Rh[c][a];
    } else {
      for(int a=0;a<3;a++) for(int c=0;c<3;c++) Rm[a][c]=Rh[a][c];
    }
    double tt[3];
    for(int d=0;d<3;d++) tt[d]=c2[d] - (c1[0]*Rm[0][d]+c1[1]*Rm[1][d]+c1[2]*Rm[2][d]);
    const float* Rt = rot + b*9;
    double dsum=0.0;
    for(int a=0;a<3;a++) for(int c=0;c<3;c++){
      double dd = Rm[a][c] - (double)Rt[c*3+a];
      dsum += dd*dd;
    }
    double dock = dsum/9.0;
    double tsum=0.0;
    for(int d=0;d<3;d++){
      double tref = -((double)trans[b*3+0]*(double)Rt[d*3+0]+(double)trans[b*3+1]*(double)Rt[d*3+1]+(double)trans[b*3+2]*(double)Rt[d*3+2]);
      double dd = tt[d]-tref;
      tsum += dd*dd;
    }
    dock += tsum/3.0;
    otb[b]=ot; dockb[b]=dock;
    for(int a=0;a<3;a++) for(int d=0;d<3;d++) Rs[a*3+d]=Rm[a][d];
    for(int d=0;d<3;d++) ts[d]=tt[d];
  }
  __syncthreads();
  double part=0.0;
  for(int nidx=tid; nidx<NPP; nidx+=256){
    int i = b*2*NPP + nidx;
    double p0=Xca[i*3], p1=Xca[i*3+1], p2=Xca[i*3+2];
    double q0=p0*Rs[0]+p1*Rs[3]+p2*Rs[6]+ts[0];
    double q1=p0*Rs[1]+p1*Rs[4]+p2*Rs[7]+ts[1];
    double q2=p0*Rs[2]+p1*Rs[5]+p2*Rs[8]+ts[2];
    int o=(b*NPP+nidx)*3;
    x1a[o]=q0; x1a[o+1]=q1; x1a[o+2]=q2;
    double d0=q0-ori0[o], d1=q1-ori0[o+1], d2=q2-ori0[o+2];
    part += d0*d0+d1*d1+d2*d2;
  }
  red[tid]=part;
  __syncthreads();
  for(int st=128; st>0; st>>=1){ if(tid<st) red[tid]+=red[tid+st]; __syncthreads(); }
  if(tid==0) rmsdb[b]=red[0]/(double)(NPP*3);
}

// ------------------------------------------------------------------
// stab (f64, round-13 proven): 1000 blocks, 8 rows x 32 lanes
// [f32 variant is BANNED: 2/2 Inf correlation, rounds 7 & 14]
// ------------------------------------------------------------------
__global__ __launch_bounds__(256) void k_stab(const double* __restrict__ x1a, const double* __restrict__ Xca,
    double* __restrict__ stabp){
  __shared__ double Bsm[NPP*3];
  __shared__ double red[8];
  int blk=blockIdx.x;
  int bd=blk/125, rg=blk%125;
  int b=bd>>1, dir=bd&1;
  int tid=threadIdx.x;
  const double* Ap = (dir==0) ? (x1a + (size_t)b*NPP*3) : (Xca + (size_t)(b*2+1)*NPP*3);
  const double* Bp = (dir==0) ? (Xca + (size_t)(b*2+1)*NPP*3) : (x1a + (size_t)b*NPP*3);
  for(int idx=tid; idx<NPP*3; idx+=256) Bsm[idx]=Bp[idx]*STDV;
  __syncthreads();
  int row = rg*8 + (tid>>5);
  int jt = tid&31;
  double a0=Ap[row*3]*STDV, a1=Ap[row*3+1]*STDV, a2=Ap[row*3+2]*STDV;
  double mind=1e300;
  for(int j=jt;j<NPP;j+=32){
    double d0=a0-Bsm[j*3], d1=a1-Bsm[j*3+1], d2=a2-Bsm[j*3+2];
    double d=d0*d0+d1*d1+d2*d2;
    mind=fmin(mind,d);
  }
  #pragma unroll
  for(int off=16;off>0;off>>=1) mind=fmin(mind,__shfl_xor(mind,off,32));
  double se=0.0;
  for(int j=jt;j<NPP;j+=32){
    double d0=a0-Bsm[j*3], d1=a1-Bsm[j*3+1], d2=a2-Bsm[j*3+2];
    double d=d0*d0+d1*d1+d2*d2;
    se += exp((mind-d)*(1.0/SIGC));
  }
  #pragma unroll
  for(int off=16;off>0;off>>=1) se += __shfl_xor(se,off,32);
  if(jt==0) red[tid>>5] = fmax(GAMC - mind + SIGC*log(se), 0.0);
  __syncthreads();
  if(tid==0){
    double s=0.0;
    #pragma unroll
    for(int i=0;i<8;i++) s+=red[i];
    stabp[blk]=s;
  }
}

__global__ void k_out(const double* __restrict__ otb, const double* __restrict__ dockb,
    const double* __restrict__ rmsdb, const double* __restrict__ stabp, float* __restrict__ out){
  if(blockIdx.x==0 && threadIdx.x==0){
    double ot=0.0,dock=0.0,rmsd=0.0,stab=0.0;
    for(int b=0;b<BSZ;b++){
      ot+=otb[b]; dock+=dockb[b]; rmsd+=rmsdb[b];
      double s1=0.0,s2=0.0;
      for(int i=0;i<125;i++){ s1+=stabp[(b*2+0)*125+i]; s2+=stabp[(b*2+1)*125+i]; }
      stab += (s1*(1.0/NPP) + s2*(1.0/NPP))*(1.0/STDV);
    }
    ot*=0.25; dock*=0.25; rmsd*=0.25; stab*=0.25;
    out[0]=(float)(ot+dock+stab); out[1]=(float)ot; out[2]=(float)dock; out[3]=(float)stab; out[4]=(float)rmsd;
  }
}

// ------------------------------------------------------------------
extern "C" void kernel_launch(void* const* d_in, const int* in_sizes, int n_in,
                              void* d_out, int out_size, void* d_ws, size_t ws_size,
                              hipStream_t stream){
  const float* X      = (const float*)d_in[0];
  const float* nodea  = (const float*)d_in[1];
  const float* edgea  = (const float*)d_in[2];
  const float* center = (const float*)d_in[3];
  const float* kpin   = (const float*)d_in[4];
  const float* rot    = (const float*)d_in[5];
  const float* trans  = (const float*)d_in[6];
  const float* W_in1  = (const float*)d_in[7];
  const float* b_in1  = (const float*)d_in[8];
  const float* W_in2  = (const float*)d_in[9];
  const float* b_in2  = (const float*)d_in[10];
  const float* msg_W  = (const float*)d_in[11];
  const float* msg_b  = (const float*)d_in[12];
  const float* upd_W1 = (const float*)d_in[13];
  const float* upd_b1 = (const float*)d_in[14];
  const float* upd_W2 = (const float*)d_in[15];
  const float* upd_b2 = (const float*)d_in[16];
  const float* x_W    = (const float*)d_in[17];
  const float* v_W    = (const float*)d_in[18];
  const float* att_W  = (const float*)d_in[19];
  const float* act_W1 = (const float*)d_in[20];
  const float* act_b1 = (const float*)d_in[21];
  const float* act_W2 = (const float*)d_in[22];
  const float* act_b2 = (const float*)d_in[23];
  const float* geb_Wv1= (const float*)d_in[24];
  const float* geb_Wv2= (const float*)d_in[25];
  const float* geb_W1 = (const float*)d_in[26];
  const float* geb_b1 = (const float*)d_in[27];
  const float* geb_W2 = (const float*)d_in[28];
  const float* geb_b2 = (const float*)d_in[29];
  const float* sc_W1  = (const float*)d_in[30];
  const float* sc_b1  = (const float*)d_in[31];
  const float* sc_W2  = (const float*)d_in[32];
  const float* sc_b2  = (const float*)d_in[33];
  const float* fin_W  = (const float*)d_in[34];
  const int*   src    = (const int*)d_in[35];
  const int*   dst    = (const int*)d_in[36];
  float* out = (float*)d_out;

  double* wd = (double*)d_ws;
  size_t o = 0;
  double* XcaD  = wd + o; o += (size_t)NN*3;
  double* ori0D = wd + o; o += (size_t)BSZ*NPP*3;
  double* kpcD  = wd + o; o += 144;
  double* tkpcD = wd + o; o += 144;
  double* dirvD = wd + o; o += (size_t)EE*3;
  double* rbfD  = wd + o; o += (size_t)EE*RBFD;
  double* hbuf  = wd + o; o += (size_t)NN*HD;
  double* Pbuf  = wd + o; o += (size_t)NN*256;
  double* mbuf  = wd + o; o += (size_t)EE*HD;   // h2 lives here
  double* va    = wd + o; o += (size_t)NN*HD*3;
  double* vb    = wd + o; o += (size_t)NN*HD*3;
  double* ubuf  = wd + o; o += (size_t)BSZ*2*HD;
  double* attp  = wd + o; o += (size_t)64*HD;
  double* nv2b  = wd + o; o += (size_t)NN*HD;
  double* sbuf  = wd + o; o += (size_t)NN*256;
  double* cbbD  = wd + o; o += 24;
  double* ypartD= wd + o; o += (size_t)4000*37;
  double* YbufD = wd + o; o += 8*36;
  double* x1aD  = wd + o; o += (size_t)BSZ*NPP*3;
  double* otb_  = wd + o; o += 4;
  double* dkb_  = wd + o; o += 4;
  double* rmb_  = wd + o; o += 4;
  double* stp_  = wd + o; o += 1000;
  double* Wnode = wd + o; o += (size_t)4*128*256;
  double* Wedge2= wd + o; o += (size_t)4*37*128;
  double* xvW   = wd + o; o += (size_t)4*128*256;

  double* h2b  = mbuf;

  size_t need = o*8;
  if(ws_size < need){
    float mb = (float)((double)ws_size / 1.0e6);
    float val = (131072.0f + mb) * 1048576.0f;
    k_sent<<<1,64,0,stream>>>(out, val);
    return;
  }

  hipMemsetAsync(va, 0, (size_t)NN*HD*3*sizeof(double), stream);

  k_cvt_node<<<512,256,0,stream>>>(msg_W, Wnode);
  k_cvt_edge<<<74,256,0,stream>>>(msg_W, msg_b, Wedge2);
  k_cvt_xv<<<256,256,0,stream>>>(x_W, v_W, xvW);

  k_geom<<<32,256,0,stream>>>(X, center, kpin, rot, trans, XcaD, ori0D, kpcD, tkpcD);
  k_edge<<<(EE+255)/256,256,0,stream>>>(XcaD, src, dst, dirvD, rbfD);
  k_hinit<<<NN/4,256,0,stream>>>(nodea, W_in1, b_in1, W_in2, b_in2, hbuf);

  double* vcur = va;
  double* vnxt = vb;
  for(int l=0;l<NL;l++){
    const double* Wn  = Wnode  + (size_t)l*128*256;
    const double* We  = Wedge2 + (size_t)l*37*128;
    const double* xvl = xvW    + (size_t)l*128*256;
    const float* u1W = upd_W1 + (size_t)l*256*HD;
    const float* u1b = upd_b1 + (size_t)l*HD;
    const float* u2W = upd_W2 + (size_t)l*HD*HD;
    const float* u2b = upd_b2 + (size_t)l*HD;
    const float* aWl = att_W  + (size_t)l*HD*HD;
    const float* a1W = act_W1 + (size_t)l*HD*HD;
    const float* a1b = act_b1 + (size_t)l*HD;
    const float* a2W = act_W2 + (size_t)l*HD*HD;
    const float* a2b = act_b2 + (size_t)l*HD;

    k_nodeproj<<<NN/8,256,0,stream>>>(hbuf, Wn, Pbuf);
    k_layer<<<NN/4,256,0,stream>>>(Pbuf, rbfD, edgea, src, We,
                                   hbuf, u1W, u1b, u2W, u2b, h2b,
                                   vcur, dirvD, xvl, vnxt);
    k_att1<<<64,128,0,stream>>>(h2b, attp);
    k_att2<<<8,128,0,stream>>>(attp, aWl, ubuf);
    k_actcomb<<<NN/4,128,0,stream>>>(h2b, ubuf, a1W, a1b, a2W, a2b, hbuf);
    double* tmp=vcur; vcur=vnxt; vnxt=tmp;
  }
  // vcur == va (final v), vnxt == vb (free -> v1)
  k_gebv<<<NN/2,256,0,stream>>>(vcur, geb_Wv1, geb_Wv2, vnxt, nv2b);
  k_gebs<<<NN/4,256,0,stream>>>(hbuf, nv2b, geb_W1, geb_b1, geb_W2, geb_b2, sbuf);
  k_kpc<<<8,256,0,stream>>>(XcaD, cbbD);
  k_kpgen<<<NN/2,256,0,stream>>>(XcaD, sbuf, vnxt, cbbD, fin_W, sc_W1, sc_b1, sc_W2, sc_b2, ypartD);
  k_kpfin<<<8,64,0,stream>>>(ypartD, cbbD, YbufD);
  k_final<<<BSZ,256,0,stream>>>(YbufD, tkpcD, kpcD, rot, trans, XcaD, ori0D, x1aD, otb_, dkb_, rmb_);
  k_stab<<<1000,256,0,stream>>>(x1aD, XcaD, stp_);
  k_out<<<1,64,0,stream>>>(otb_, dkb_, rmb_, stp_, out);
}

// Round 16
// 1510.236 us; speedup vs baseline: 1.5580x; 1.0275x over previous
//
#include <hip/hip_runtime.h>
#include <math.h>

#define NPP 1000
#define BSZ 4
#define HD 128
#define NL 4
#define RBFD 20
#define EDD 16
#define KN 9
#define NKPP 12
#define NN 8000
#define EE 72000
#define STDV 10.0
#define SIGC 25.0
#define GAMC 10.0
#define PID 3.14159265358979323846

__device__ __forceinline__ double silud(double x){ return x / (1.0 + exp(-x)); }

__global__ void k_sent(float* __restrict__ out, float val){
  if(threadIdx.x<5 && blockIdx.x==0) out[threadIdx.x]=val;
}

// ------------------------------------------------------------------
// weight preconversion to f64
// ------------------------------------------------------------------
__global__ __launch_bounds__(256) void k_cvt_node(const float* __restrict__ msgW, double* __restrict__ Wn){
  int idx = blockIdx.x*256+threadIdx.x;
  if(idx >= 4*128*256) return;
  int l = idx>>15; int r = idx & 32767; int k = r>>8; int j = r&255;
  const float* W = msgW + (size_t)l*292*128;
  Wn[idx] = (j<128) ? (double)W[k*128+j] : (double)W[(128+k)*128 + (j-128)];
}
__global__ __launch_bounds__(256) void k_cvt_edge(const float* __restrict__ msgW, const float* __restrict__ msgb,
    double* __restrict__ We){
  int idx = blockIdx.x*256+threadIdx.x;
  if(idx >= 4*37*128) return;
  int l = idx/(37*128); int r = idx%(37*128); int k = r>>7; int j = r&127;
  if(k<36) We[idx] = (double)msgW[(size_t)l*292*128 + (256+k)*128 + j];
  else     We[idx] = (double)msgb[l*128 + j];
}
__global__ __launch_bounds__(256) void k_cvt_xv(const float* __restrict__ xW, const float* __restrict__ vW,
    double* __restrict__ xv){
  int idx = blockIdx.x*256+threadIdx.x;
  if(idx >= 4*128*128) return;
  int l = idx>>14; int r = idx & 16383; int hh = r>>7; int c = r&127;
  xv[(size_t)l*32768 + hh*256 + 2*c]   = (double)xW[(size_t)l*16384 + hh*128 + c];
  xv[(size_t)l*32768 + hh*256 + 2*c+1] = (double)vW[(size_t)l*16384 + hh*128 + c];
}

// ------------------------------------------------------------------
// geometry (f64)
// ------------------------------------------------------------------
__global__ __launch_bounds__(256) void k_geom(const float* __restrict__ X, const float* __restrict__ center,
    const float* __restrict__ kpin, const float* __restrict__ rot, const float* __restrict__ trans,
    double* __restrict__ Xca, double* __restrict__ ori0, double* __restrict__ kpc, double* __restrict__ tkpc){
  int i = blockIdx.x*256 + threadIdx.x;
  const double inv = 1.0/STDV;
  if(i < NN){
    int b = i / (2*NPP);
    int s = (i / NPP) & 1;
    int n = i % NPP;
    double q0 = (double)X[i*12+3] - (double)center[b*3+0];
    double q1 = (double)X[i*12+4] - (double)center[b*3+1];
    double q2 = (double)X[i*12+5] - (double)center[b*3+2];
    if(s==0){
      int o=(b*NPP+n)*3;
      ori0[o]=q0*inv; ori0[o+1]=q1*inv; ori0[o+2]=q2*inv;
      const float* R = rot + b*9;
      #pragma unroll
      for(int d=0; d<3; d++)
        Xca[i*3+d] = (q0*(double)R[d] + q1*(double)R[3+d] + q2*(double)R[6+d])*inv + (double)trans[b*3+d];
    } else {
      Xca[i*3+0]=q0*inv; Xca[i*3+1]=q1*inv; Xca[i*3+2]=q2*inv;
    }
  } else if(i < NN + BSZ*NKPP){
    int j = i - NN;
    int b = j / NKPP;
    double q0 = (double)kpin[j*3+0]-(double)center[b*3+0];
    double q1 = (double)kpin[j*3+1]-(double)center[b*3+1];
    double q2 = (double)kpin[j*3+2]-(double)center[b*3+2];
    kpc[j*3+0]=q0*inv; kpc[j*3+1]=q1*inv; kpc[j*3+2]=q2*inv;
    const float* R = rot + b*9;
    #pragma unroll
    for(int d=0; d<3; d++)
      tkpc[j*3+d] = (q0*(double)R[d] + q1*(double)R[3+d] + q2*(double)R[6+d])*inv + (double)trans[b*3+d];
  }
}

// ------------------------------------------------------------------
__global__ __launch_bounds__(256) void k_edge(const double* __restrict__ Xca, const int* __restrict__ src,
    const int* __restrict__ dst, double* __restrict__ dirv, double* __restrict__ rbfb){
  int e = blockIdx.x*256 + threadIdx.x;
  if(e >= EE) return;
  int sp = src[e], dp = dst[e];
  double d0 = Xca[dp*3+0]-Xca[sp*3+0];
  double d1 = Xca[dp*3+1]-Xca[sp*3+1];
  double d2 = Xca[dp*3+2]-Xca[sp*3+2];
  double nr = sqrt(d0*d0+d1*d1+d2*d2) + 1e-08;
  double iv = 1.0/nr;
  dirv[e*3+0]=d0*iv; dirv[e*3+1]=d1*iv; dirv[e*3+2]=d2*iv;
  #pragma unroll
  for(int j=0;j<RBFD;j++)
    rbfb[e*RBFD+j] = sin(nr*(double)(j+1)*PID)*iv;
}

// ------------------------------------------------------------------
// h init: 4 nodes/block, 256 thr
// ------------------------------------------------------------------
__global__ __launch_bounds__(256) void k_hinit(const float* __restrict__ na,
    const float* __restrict__ W1, const float* __restrict__ b1,
    const float* __restrict__ W2, const float* __restrict__ b2, double* __restrict__ h){
  __shared__ double cin[4][64];
  __shared__ double hmid[4][128];
  int n0 = blockIdx.x*4;
  int tid = threadIdx.x;
  {
    int r=tid>>6, k=tid&63;
    cin[r][k] = (double)na[(n0+r)*64 + k];
  }
  __syncthreads();
  int r = tid>>6, c0 = (tid&63)*2;
  double a0=(double)b1[c0], a1=(double)b1[c0+1];
  for(int k=0;k<64;k++){
    double a = cin[r][k];
    const float* wp = W1 + k*HD + c0;
    a0 += a*(double)wp[0]; a1 += a*(double)wp[1];
  }
  hmid[r][c0]=silud(a0); hmid[r][c0+1]=silud(a1);
  __syncthreads();
  double s0=(double)b2[c0], s1=(double)b2[c0+1];
  for(int k=0;k<HD;k++){
    double a = hmid[r][k];
    const float* wp = W2 + k*HD + c0;
    s0 += a*(double)wp[0]; s1 += a*(double)wp[1];
  }
  h[(size_t)(n0+r)*HD+c0]=s0; h[(size_t)(n0+r)*HD+c0+1]=s1;
}

// ------------------------------------------------------------------
// node projection: 8 nodes/block, 256 thr
// ------------------------------------------------------------------
__global__ __launch_bounds__(256) void k_nodeproj(const double* __restrict__ h, const double* __restrict__ Wn,
    double* __restrict__ P){
  __shared__ double cin[8][128];
  int n0 = blockIdx.x*8;
  int tid = threadIdx.x;
  for(int idx=tid; idx<1024; idx+=256){
    int r=idx>>7, k=idx&127;
    cin[r][k]=h[(size_t)(n0+r)*HD+k];
  }
  __syncthreads();
  int half = tid>>7;
  int r0 = half*4;
  int c0 = (tid&127)*2;
  double a00=0,a01=0,a10=0,a11=0,a20=0,a21=0,a30=0,a31=0;
  for(int k=0;k<128;k++){
    double2 w = *(const double2*)(Wn + (size_t)k*256 + c0);
    double x0=cin[r0+0][k],x1=cin[r0+1][k],x2=cin[r0+2][k],x3=cin[r0+3][k];
    a00+=x0*w.x; a01+=x0*w.y; a10+=x1*w.x; a11+=x1*w.y;
    a20+=x2*w.x; a21+=x2*w.y; a30+=x3*w.x; a31+=x3*w.y;
  }
  P[(size_t)(n0+r0+0)*256+c0]=a00; P[(size_t)(n0+r0+0)*256+c0+1]=a01;
  P[(size_t)(n0+r0+1)*256+c0]=a10; P[(size_t)(n0+r0+1)*256+c0+1]=a11;
  P[(size_t)(n0+r0+2)*256+c0]=a20; P[(size_t)(n0+r0+2)*256+c0+1]=a21;
  P[(size_t)(n0+r0+3)*256+c0]=a30; P[(size_t)(n0+r0+3)*256+c0+1]=a31;
}

// ------------------------------------------------------------------
// fused layer kernel: edge messages (into LDS) + upd-MLP + v-update
// 4 nodes/block, 256 thr (half=tid>>7, colp=tid&127)
// phase B uses 4-way interleaved partial sums (ILP 8) — f64 reorder
// noise ~1e-16, amplified <=1e9 -> <=1e-7 rel, threshold 2% (safe)
// ------------------------------------------------------------------
__global__ __launch_bounds__(256) void k_layer(
    const double* __restrict__ P, const double* __restrict__ rbfb, const float* __restrict__ ea,
    const int* __restrict__ src, const double* __restrict__ We,
    const double* __restrict__ h, const float* __restrict__ W1, const float* __restrict__ b1,
    const float* __restrict__ W2, const float* __restrict__ b2, double* __restrict__ h2,
    const double* __restrict__ va, const double* __restrict__ dirv, const double* __restrict__ xv,
    double* __restrict__ vb){
  __shared__ double mT[4][9][128];
  __shared__ double scratch[1536];
  __shared__ double dv[4][9][3];
  __shared__ int sp[4][9];
  int n0 = blockIdx.x*4;
  int tid = threadIdx.x;
  int e0 = n0*KN;
  for(int idx=tid; idx<36*RBFD; idx+=256){
    int e=idx/RBFD, f=idx-e*RBFD;
    scratch[e*37+f] = rbfb[(size_t)(e0+e)*RBFD+f];
  }
  for(int idx=tid; idx<36*EDD; idx+=256){
    int e=idx>>4, f=idx&15;
    scratch[e*37+20+f] = (double)ea[(size_t)(e0+e)*EDD+f];
  }
  if(tid<36){
    scratch[tid*37+36]=1.0;
    int nd=tid/9, kk=tid-nd*9;
    int e=e0+nd*9+kk;
    sp[nd][kk]=src[e];
    dv[nd][kk][0]=dirv[e*3]; dv[nd][kk][1]=dirv[e*3+1]; dv[nd][kk][2]=dirv[e*3+2];
  }
  int half = tid>>7, colp = tid&127;
  double wreg[37];
  #pragma unroll
  for(int f=0;f<37;f++) wreg[f]=We[f*128+colp];
  __syncthreads();
  // ---- phase A
  double aggv0=0.0, aggv1=0.0;
  {
    int nd = half*2;
    double p2 = P[(size_t)(n0+nd)*256 + 128 + colp];
    double agg=0.0;
    for(int kk=0;kk<9;kk++){
      const double* fe = &scratch[(nd*9+kk)*37];
      double acc=0.0;
      #pragma unroll
      for(int f=0;f<37;f++) acc += fe[f]*wreg[f];
      double mv_ = silud(acc + P[(size_t)sp[nd][kk]*256 + colp] + p2);
      mT[nd][kk][colp]=mv_;
      agg += mv_;
    }
    aggv0=agg;
  }
  {
    int nd = half*2+1;
    double p2 = P[(size_t)(n0+nd)*256 + 128 + colp];
    double agg=0.0;
    for(int kk=0;kk<9;kk++){
      const double* fe = &scratch[(nd*9+kk)*37];
      double acc=0.0;
      #pragma unroll
      for(int f=0;f<37;f++) acc += fe[f]*wreg[f];
      double mv_ = silud(acc + P[(size_t)sp[nd][kk]*256 + colp] + p2);
      mT[nd][kk][colp]=mv_;
      agg += mv_;
    }
    aggv1=agg;
  }
  __syncthreads();
  {
    int ndA = half*2, ndB = ndA+1;
    scratch[ndA*256+colp]     = h[(size_t)(n0+ndA)*HD+colp];
    scratch[ndA*256+128+colp] = aggv0;
    scratch[ndB*256+colp]     = h[(size_t)(n0+ndB)*HD+colp];
    scratch[ndB*256+128+colp] = aggv1;
  }
  __syncthreads();
  // ---- phase B (4-way interleaved accumulators)
  {
    int ndA = half*2, ndB = ndA+1;
    double a00=0,a01=0,a02=0,a03=0, a10=0,a11=0,a12=0,a13=0;
    for(int k=0;k<256;k+=4){
      double w0 = (double)W1[(size_t)k*HD+colp];
      double w1 = (double)W1[(size_t)(k+1)*HD+colp];
      double w2 = (double)W1[(size_t)(k+2)*HD+colp];
      double w3 = (double)W1[(size_t)(k+3)*HD+colp];
      a00 += scratch[ndA*256+k]*w0;   a01 += scratch[ndA*256+k+1]*w1;
      a02 += scratch[ndA*256+k+2]*w2; a03 += scratch[ndA*256+k+3]*w3;
      a10 += scratch[ndB*256+k]*w0;   a11 += scratch[ndB*256+k+1]*w1;
      a12 += scratch[ndB*256+k+2]*w2; a13 += scratch[ndB*256+k+3]*w3;
    }
    double a0 = (double)b1[colp] + ((a00+a01)+(a02+a03));
    double a1 = (double)b1[colp] + ((a10+a11)+(a12+a13));
    scratch[1024+ndA*128+colp]=silud(a0);
    scratch[1024+ndB*128+colp]=silud(a1);
  }
  __syncthreads();
  {
    int ndA = half*2, ndB = ndA+1;
    double a00=0,a01=0,a02=0,a03=0, a10=0,a11=0,a12=0,a13=0;
    for(int k=0;k<128;k+=4){
      double w0 = (double)W2[(size_t)k*HD+colp];
      double w1 = (double)W2[(size_t)(k+1)*HD+colp];
      double w2 = (double)W2[(size_t)(k+2)*HD+colp];
      double w3 = (double)W2[(size_t)(k+3)*HD+colp];
      a00 += scratch[1024+ndA*128+k]*w0;   a01 += scratch[1024+ndA*128+k+1]*w1;
      a02 += scratch[1024+ndA*128+k+2]*w2; a03 += scratch[1024+ndA*128+k+3]*w3;
      a10 += scratch[1024+ndB*128+k]*w0;   a11 += scratch[1024+ndB*128+k+1]*w1;
      a12 += scratch[1024+ndB*128+k+2]*w2; a13 += scratch[1024+ndB*128+k+3]*w3;
    }
    double a0 = (double)b2[colp] + ((a00+a01)+(a02+a03));
    double a1 = (double)b2[colp] + ((a10+a11)+(a12+a13));
    h2[(size_t)(n0+ndA)*HD+colp] = scratch[ndA*256+colp] + a0;
    h2[(size_t)(n0+ndB)*HD+colp] = scratch[ndB*256+colp] + a1;
  }
  __syncthreads();
  // ---- phase C: md then v-update, hh unrolled x2
  for(int idx=tid; idx<1536; idx+=256){
    int hh=idx&127, t2=idx>>7; int nd=t2/3, c=t2-nd*3;
    double s=0.0;
    #pragma unroll
    for(int kk=0;kk<9;kk++) s += dv[nd][kk][c]*mT[nd][kk][hh];
    scratch[nd*384 + c*128 + hh]=s;
  }
  __syncthreads();
  int nd = tid>>6;
  int t  = tid&63;
  int c0 = 2*t;
  double oA0=0,oA1=0,oA2=0, oB0=0,oB1=0,oB2=0;
  double mvA[9], mvB[9];
  #pragma unroll
  for(int kk=0;kk<9;kk++){ mvA[kk]=0.0; mvB[kk]=0.0; }
  const double* mdb = &scratch[nd*384];
  for(int hh=0; hh<128; hh+=2){
    const double* xp0 = xv + (size_t)hh*256 + 2*c0;
    const double* xp1 = xp0 + 256;
    double2 wpA0 = *(const double2*)(xp0);
    double2 wpB0 = *(const double2*)(xp0+2);
    double2 wpA1 = *(const double2*)(xp1);
    double2 wpB1 = *(const double2*)(xp1+2);
    double d00 = mdb[hh],     d10 = mdb[128+hh],   d20 = mdb[256+hh];
    double d01 = mdb[hh+1],   d11 = mdb[128+hh+1], d21 = mdb[256+hh+1];
    oA0 += d00*wpA0.x; oA1 += d10*wpA0.x; oA2 += d20*wpA0.x;
    oB0 += d00*wpB0.x; oB1 += d10*wpB0.x; oB2 += d20*wpB0.x;
    oA0 += d01*wpA1.x; oA1 += d11*wpA1.x; oA2 += d21*wpA1.x;
    oB0 += d01*wpB1.x; oB1 += d11*wpB1.x; oB2 += d21*wpB1.x;
    #pragma unroll
    for(int kk=0;kk<9;kk++){
      double mk0 = mT[nd][kk][hh];
      double mk1 = mT[nd][kk][hh+1];
      mvA[kk] += mk0*wpA0.y;
      mvB[kk] += mk0*wpB0.y;
      mvA[kk] += mk1*wpA1.y;
      mvB[kk] += mk1*wpB1.y;
    }
  }
  #pragma unroll
  for(int kk=0;kk<9;kk++){
    size_t s3 = (size_t)sp[nd][kk]*384 + c0*3;
    double ka = mvA[kk], kb = mvB[kk];
    oA0 += va[s3]*ka;   oA1 += va[s3+1]*ka; oA2 += va[s3+2]*ka;
    oB0 += va[s3+3]*kb; oB1 += va[s3+4]*kb; oB2 += va[s3+5]*kb;
  }
  size_t b3 = (size_t)(n0+nd)*384 + c0*3;
  vb[b3]  = va[b3]  + oA0;
  vb[b3+1]= va[b3+1]+ oA1;
  vb[b3+2]= va[b3+2]+ oA2;
  vb[b3+3]= va[b3+3]+ oB0;
  vb[b3+4]= va[b3+4]+ oB1;
  vb[b3+5]= va[b3+5]+ oB2;
}

// ------------------------------------------------------------------
// attention partials + finish
// ------------------------------------------------------------------
__global__ __launch_bounds__(128) void k_att1(const double* __restrict__ h2, double* __restrict__ partial){
  int blk = blockIdx.x;
  int bs = blk>>3, ch = blk&7;
  int col = threadIdx.x;
  size_t base = ((size_t)bs*NPP + ch*125)*HD + col;
  double s=0.0;
  for(int i=0;i<125;i++) s += h2[base + (size_t)i*HD];
  partial[(size_t)blk*HD + col] = s;
}
__global__ __launch_bounds__(128) void k_att2(const double* __restrict__ partial, const float* __restrict__ attW,
    double* __restrict__ u){
  __shared__ double mm[128];
  int bs = blockIdx.x;
  int col = threadIdx.x;
  int os = bs^1;
  double s=0.0;
  for(int c=0;c<8;c++) s += partial[(size_t)(os*8+c)*HD + col];
  mm[col] = s*(1.0/NPP);
  __syncthreads();
  double acc=0.0;
  for(int k=0;k<HD;k++) acc += (double)attW[col*HD+k]*mm[k];
  u[bs*HD+col] = acc;
}

// ------------------------------------------------------------------
// h_new = intra + g*act(intra), g fused
// ------------------------------------------------------------------
__global__ __launch_bounds__(128) void k_actcomb(const double* __restrict__ h2, const double* __restrict__ u,
    const float* __restrict__ W1, const float* __restrict__ b1,
    const float* __restrict__ W2, const float* __restrict__ b2, double* __restrict__ h){
  __shared__ double As[4][128];
  __shared__ double hmid[4][128];
  __shared__ double pd[128];
  __shared__ double gsh[4];
  int n0 = blockIdx.x*4;
  int tid = threadIdx.x;
  int bs = n0/NPP;
  for(int idx=tid; idx<512; idx+=128){
    int r=idx>>7, k=idx&127;
    As[r][k] = h2[(size_t)(n0+r)*HD+k];
  }
  __syncthreads();
  {
    int nd=tid>>5, q=tid&31;
    double p=0.0;
    for(int j=q;j<128;j+=32) p += As[nd][j]*u[bs*HD+j];
    pd[tid]=p;
  }
  __syncthreads();
  if((tid&31)==0){
    int nd=tid>>5;
    double s=0.0;
    for(int i2=0;i2<32;i2++) s+=pd[nd*32+i2];
    gsh[nd]=1.0/(1.0+exp(-s));
  }
  __syncthreads();
  int col = tid;
  double bb=(double)b1[col];
  double a0=bb,a1=bb,a2=bb,a3=bb;
  for(int k=0;k<128;k++){
    double w = (double)W1[(size_t)k*HD+col];
    a0 += As[0][k]*w; a1 += As[1][k]*w; a2 += As[2][k]*w; a3 += As[3][k]*w;
  }
  hmid[0][col]=silud(a0); hmid[1][col]=silud(a1); hmid[2][col]=silud(a2); hmid[3][col]=silud(a3);
  __syncthreads();
  bb=(double)b2[col];
  a0=bb;a1=bb;a2=bb;a3=bb;
  for(int k=0;k<128;k++){
    double w = (double)W2[(size_t)k*HD+col];
    a0 += hmid[0][k]*w; a1 += hmid[1][k]*w; a2 += hmid[2][k]*w; a3 += hmid[3][k]*w;
  }
  h[(size_t)(n0+0)*HD+col] = As[0][col] + gsh[0]*a0;
  h[(size_t)(n0+1)*HD+col] = As[1][col] + gsh[1]*a1;
  h[(size_t)(n0+2)*HD+col] = As[2][col] + gsh[2]*a2;
  h[(size_t)(n0+3)*HD+col] = As[3][col] + gsh[3]*a3;
}

// ------------------------------------------------------------------
// geb vector branch
// ------------------------------------------------------------------
__global__ __launch_bounds__(256) void k_gebv(const double* __restrict__ va,
    const float* __restrict__ Wv1, const float* __restrict__ Wv2,
    double* __restrict__ v1, double* __restrict__ nv2){
  __shared__ double vl[2][384];
  int n0 = blockIdx.x*2;
  int tid = threadIdx.x;
  for(int idx=tid; idx<768; idx+=256){
    int r=idx/384, k=idx%384;
    vl[r][k] = va[(size_t)(n0+r)*384+k];
  }
  __syncthreads();
  int r = tid>>7, col = tid&127;
  double a10=0.0,a11=0.0,a12=0.0, a20=0.0,a21=0.0,a22=0.0;
  for(int hh=0; hh<HD; hh++){
    double w1 = (double)Wv1[hh*HD+col];
    double w2 = (double)Wv2[hh*HD+col];
    double v0=vl[r][hh*3], v1e=vl[r][hh*3+1], v2e=vl[r][hh*3+2];
    a10+=v0*w1; a11+=v1e*w1; a12+=v2e*w1;
    a20+=v0*w2; a21+=v1e*w2; a22+=v2e*w2;
  }
  size_t b3=(size_t)(n0+r)*384+col*3;
  v1[b3]=a10; v1[b3+1]=a11; v1[b3+2]=a12;
  nv2[(size_t)(n0+r)*HD+col]=sqrt(a20*a20+a21*a21+a22*a22);
}

// ------------------------------------------------------------------
// s = silu([h,nv2]@gebW1+b1)@gebW2+b2
// ------------------------------------------------------------------
__global__ __launch_bounds__(256) void k_gebs(const double* __restrict__ h, const double* __restrict__ nv2,
    const float* __restrict__ W1, const float* __restrict__ b1,
    const float* __restrict__ W2, const float* __restrict__ b2, double* __restrict__ s){
  __shared__ double cin[4][256];
  __shared__ double hmid[4][128];
  int n0 = blockIdx.x*4;
  int tid = threadIdx.x;
  for(int idx=tid; idx<4*HD; idx+=256){
    int r=idx>>7, k=idx&127;
    cin[r][k]    = h[(size_t)(n0+r)*HD + k];
    cin[r][HD+k] = nv2[(size_t)(n0+r)*HD + k];
  }
  __syncthreads();
  int r = tid>>6, c0 = (tid&63)*2;
  double a0=(double)b1[c0], a1=(double)b1[c0+1];
  for(int k=0;k<2*HD;k++){
    double a = cin[r][k];
    const float* wp = W1 + (size_t)k*HD + c0;
    a0 += a*(double)wp[0]; a1 += a*(double)wp[1];
  }
  hmid[r][c0]=silud(a0); hmid[r][c0+1]=silud(a1);
  __syncthreads();
  int c1 = (tid&63)*4;
  double s0=(double)b2[c1], s1=(double)b2[c1+1], s2=(double)b2[c1+2], s3=(double)b2[c1+3];
  for(int k=0;k<HD;k++){
    double a = hmid[r][k];
    const float* wp = W2 + (size_t)k*256 + c1;
    s0 += a*(double)wp[0]; s1 += a*(double)wp[1]; s2 += a*(double)wp[2]; s3 += a*(double)wp[3];
  }
  double* srow = s + (size_t)(n0+r)*256 + c1;
  srow[0]=s0; srow[1]=s1; srow[2]=s2; srow[3]=s3;
}

// ------------------------------------------------------------------
__global__ __launch_bounds__(256) void k_kpc(const double* __restrict__ Xca, double* __restrict__ cbb){
  __shared__ double red[768];
  int bs = blockIdx.x;
  int tid = threadIdx.x;
  double s0=0.0,s1=0.0,s2=0.0;
  for(int nidx=tid; nidx<NPP; nidx+=256){
    int i = bs*NPP+nidx;
    s0+=Xca[i*3]; s1+=Xca[i*3+1]; s2+=Xca[i*3+2];
  }
  red[tid]=s0; red[256+tid]=s1; red[512+tid]=s2;
  __syncthreads();
  for(int st=128; st>0; st>>=1){
    if(tid<st){ red[tid]+=red[tid+st]; red[256+tid]+=red[256+tid+st]; red[512+tid]+=red[512+tid+st]; }
    __syncthreads();
  }
  if(tid==0){ cbb[bs*3]=red[0]*(1.0/NPP); cbb[bs*3+1]=red[256]*(1.0/NPP); cbb[bs*3+2]=red[512]*(1.0/NPP); }
}

// ------------------------------------------------------------------
// keypoint partials: 2 nodes/block
// ------------------------------------------------------------------
__global__ __launch_bounds__(256) void k_kpgen(const double* __restrict__ Xca, const double* __restrict__ sbuf,
    const double* __restrict__ v1, const double* __restrict__ cbb, const float* __restrict__ fW,
    const float* __restrict__ sW1, const float* __restrict__ sb1, const float* __restrict__ sW2,
    const float* __restrict__ sb2, double* __restrict__ ypart){
  __shared__ double tt[2][3][128];
  __shared__ double ssv[2][128];
  __shared__ double zz[2][64];
  __shared__ double snorm[2];
  __shared__ double ylL[2][37];
  int blk = blockIdx.x;
  int tid = threadIdx.x;
  int r = tid>>7, t = tid&127;
  int n = blk*2 + r;
  int bs = n/NPP;
  const double* srow = sbuf + (size_t)n*256;
  const double* vrow = v1 + (size_t)n*384;
  double gate = srow[128+t];
  double hp = srow[t];
  double vf0 = vrow[t*3+0]*gate, vf1 = vrow[t*3+1]*gate, vf2 = vrow[t*3+2]*gate;
  tt[r][0][t]=vf0*hp; tt[r][1][t]=vf1*hp; tt[r][2][t]=vf2*hp;
  ssv[r][t]=sqrt(vf0*vf0+vf1*vf1+vf2*vf2);
  if(t==0){
    double x0=Xca[n*3]-cbb[bs*3], x1=Xca[n*3+1]-cbb[bs*3+1], x2=Xca[n*3+2]-cbb[bs*3+2];
    snorm[r]=sqrt(x0*x0+x1*x1+x2*x2);
  }
  __syncthreads();
  if(t<36){
    int k2=t/3, c=t%3;
    double a=0.0;
    for(int hh=0; hh<128; hh++) a += tt[r][c][hh]*(double)fW[hh*NKPP+k2];
    ylL[r][t]=a;
  } else if(t>=64){
    int j=t-64;
    double z=(double)sb1[j];
    for(int hh=0; hh<128; hh++) z += ssv[r][hh]*(double)sW1[hh*64+j];
    z += snorm[r]*(double)sW1[128*64+j];
    zz[r][j]=silud(z)*(double)sW2[j];
  }
  __syncthreads();
  if(t==36){
    double dn=(double)sb2[0];
    for(int j=0;j<64;j++) dn+=zz[r][j];
    ylL[r][36]=dn;
  }
  __syncthreads();
  if(tid<37) ypart[(size_t)blk*37+tid]=ylL[0][tid]+ylL[1][tid];
}

__global__ __launch_bounds__(64) void k_kpfin(const double* __restrict__ ypart,
    const double* __restrict__ cbb, double* __restrict__ Y){
  __shared__ double sums[37];
  int bs=blockIdx.x, tid=threadIdx.x;
  if(tid<37){
    double s=0.0;
    for(int i=0;i<500;i++) s += ypart[(size_t)(bs*500+i)*37 + tid];
    sums[tid]=s;
  }
  __syncthreads();
  if(tid<36){
    double dsh = sums[36]*(1.0/NPP);
    Y[bs*36+tid] = sums[tid]/dsh + cbb[bs*3 + tid%3];
  }
}

// ------------------------------------------------------------------
// per-sample: ot, Kabsch (Horn quaternion), dock, rmsd, X1a
// ------------------------------------------------------------------
__global__ __launch_bounds__(256) void k_final(const double* __restrict__ Y, const double* __restrict__ tkpc,
    const double* __restrict__ kpc, const float* __restrict__ rot, const float* __restrict__ trans,
    const double* __restrict__ Xca, const double* __restrict__ ori0,
    double* __restrict__ x1a, double* __restrict__ otb, double* __restrict__ dockb, double* __restrict__ rmsdb){
  int b = blockIdx.x;
  int tid = threadIdx.x;
  __shared__ double Rs[9];
  __shared__ double ts[3];
  __shared__ double red[256];
  if(tid==0){
    const double* Y1 = Y + (b*2+0)*36;
    const double* Y2 = Y + (b*2+1)*36;
    const double* P1 = tkpc + b*36;
    const double* P2 = kpc + b*36;
    double ot1=0.0, ot2=0.0;
    for(int i=0;i<12;i++){
      double best1=1e300, best2=1e300;
      for(int j=0;j<12;j++){
        double d1=0.0, d2=0.0;
        #pragma unroll
        for(int c=0;c<3;c++){
          double e1=Y1[i*3+c]-P1[j*3+c]; d1+=e1*e1;
          double e2=Y2[i*3+c]-P2[j*3+c]; d2+=e2*e2;
        }
        best1=fmin(best1,d1); best2=fmin(best2,d2);
      }
      ot1+=best1; ot2+=best2;
    }
    double ot = ot1*(1.0/36.0) + ot2*(1.0/36.0);
    double c1[3]={0,0,0}, c2[3]={0,0,0};
    for(int i=0;i<12;i++)
      for(int c=0;c<3;c++){ c1[c]+=Y1[i*3+c]; c2[c]+=Y2[i*3+c]; }
    for(int c=0;c<3;c++){ c1[c]/=12.0; c2[c]/=12.0; }
    double Hm[3][3]={{0,0,0},{0,0,0},{0,0,0}};
    for(int i=0;i<12;i++)
      for(int a=0;a<3;a++)
        for(int c=0;c<3;c++)
          Hm[a][c] += (Y1[i*3+a]-c1[a])*(Y2[i*3+c]-c2[c]);
    double Sxx=Hm[0][0],Sxy=Hm[0][1],Sxz=Hm[0][2];
    double Syx=Hm[1][0],Syy=Hm[1][1],Syz=Hm[1][2];
    double Szx=Hm[2][0],Szy=Hm[2][1],Szz=Hm[2][2];
    double K[4][4];
    K[0][0]=Sxx+Syy+Szz; K[0][1]=Syz-Szy;     K[0][2]=Szx-Sxz;      K[0][3]=Sxy-Syx;
    K[1][0]=K[0][1];     K[1][1]=Sxx-Syy-Szz; K[1][2]=Sxy+Syx;      K[1][3]=Szx+Sxz;
    K[2][0]=K[0][2];     K[2][1]=K[1][2];     K[2][2]=-Sxx+Syy-Szz; K[2][3]=Syz+Szy;
    K[3][0]=K[0][3];     K[3][1]=K[1][3];     K[3][2]=K[2][3];      K[3][3]=-Sxx-Syy+Szz;
    double V[4][4]={{1,0,0,0},{0,1,0,0},{0,0,1,0},{0,0,0,1}};
    for(int sweep=0;sweep<30;sweep++){
      for(int p=0;p<3;p++) for(int q=p+1;q<4;q++){
        double apq=K[p][q];
        if(fabs(apq)<1e-300) continue;
        double tau=(K[q][q]-K[p][p])/(2.0*apq);
        double t=(tau>=0.0?1.0:-1.0)/(fabs(tau)+sqrt(tau*tau+1.0));
        double cs=1.0/sqrt(t*t+1.0), sn=t*cs;
        for(int r2=0;r2<4;r2++){
          double krp=K[r2][p], krq=K[r2][q];
          K[r2][p]=cs*krp - sn*krq;
          K[r2][q]=sn*krp + cs*krq;
        }
        for(int r2=0;r2<4;r2++){
          double kpr=K[p][r2], kqr=K[q][r2];
          K[p][r2]=cs*kpr - sn*kqr;
          K[q][r2]=sn*kpr + cs*kqr;
        }
        for(int r2=0;r2<4;r2++){
          double vrp=V[r2][p], vrq=V[r2][q];
          V[r2][p]=cs*vrp - sn*vrq;
          V[r2][q]=sn*vrp + cs*vrq;
        }
      }
    }
    int mi=0;
    for(int i2=1;i2<4;i2++) if(K[i2][i2]>K[mi][mi]) mi=i2;
    double qw=V[0][mi], qx=V[1][mi], qy=V[2][mi], qz=V[3][mi];
    double Rh[3][3];
    Rh[0][0]=qw*qw+qx*qx-qy*qy-qz*qz; Rh[0][1]=2.0*(qx*qy-qw*qz);       Rh[0][2]=2.0*(qx*qz+qw*qy);
    Rh[1][0]=2.0*(qx*qy+qw*qz);       Rh[1][1]=qw*qw-qx*qx+qy*qy-qz*qz; Rh[1][2]=2.0*(qy*qz-qw*qx);
    Rh[2][0]=2.0*(qx*qz-qw*qy);       Rh[2][1]=2.0*(qy*qz+qw*qx);       Rh[2][2]=qw*qw-qx*qx-qy*qy+qz*qz;
    double objT=0.0, objN=0.0;
    for(int a=0;a<3;a++) for(int c=0;c<3;c++){ objT+=Rh[c][a]*Hm[a][c]; objN+=Rh[a][c]*Hm[a][c]; }
    double Rm[3][3];
    if(objT>=objN){
      for(int a=0;a<3;a++) for(int c=0;c<3;c++) Rm[a][c]=Rh[c][a];
    } else {
      for(int a=0;a<3;a++) for(int c=0;c<3;c++) Rm[a][c]=Rh[a][c];
    }
    double tt[3];
    for(int d=0;d<3;d++) tt[d]=c2[d] - (c1[0]*Rm[0][d]+c1[1]*Rm[1][d]+c1[2]*Rm[2][d]);
    const float* Rt = rot + b*9;
    double dsum=0.0;
    for(int a=0;a<3;a++) for(int c=0;c<3;c++){
      double dd = Rm[a][c] - (double)Rt[c*3+a];
      dsum += dd*dd;
    }
    double dock = dsum/9.0;
    double tsum=0.0;
    for(int d=0;d<3;d++){
      double tref = -((double)trans[b*3+0]*(double)Rt[d*3+0]+(double)trans[b*3+1]*(double)Rt[d*3+1]+(double)trans[b*3+2]*(double)Rt[d*3+2]);
      double dd = tt[d]-tref;
      tsum += dd*dd;
    }
    dock += tsum/3.0;
    otb[b]=ot; dockb[b]=dock;
    for(int a=0;a<3;a++) for(int d=0;d<3;d++) Rs[a*3+d]=Rm[a][d];
    for(int d=0;d<3;d++) ts[d]=tt[d];
  }
  __syncthreads();
  double part=0.0;
  for(int nidx=tid; nidx<NPP; nidx+=256){
    int i = b*2*NPP + nidx;
    double p0=Xca[i*3], p1=Xca[i*3+1], p2=Xca[i*3+2];
    double q0=p0*Rs[0]+p1*Rs[3]+p2*Rs[6]+ts[0];
    double q1=p0*Rs[1]+p1*Rs[4]+p2*Rs[7]+ts[1];
    double q2=p0*Rs[2]+p1*Rs[5]+p2*Rs[8]+ts[2];
    int o=(b*NPP+nidx)*3;
    x1a[o]=q0; x1a[o+1]=q1; x1a[o+2]=q2;
    double d0=q0-ori0[o], d1=q1-ori0[o+1], d2=q2-ori0[o+2];
    part += d0*d0+d1*d1+d2*d2;
  }
  red[tid]=part;
  __syncthreads();
  for(int st=128; st>0; st>>=1){ if(tid<st) red[tid]+=red[tid+st]; __syncthreads(); }
  if(tid==0) rmsdb[b]=red[0]/(double)(NPP*3);
}

// ------------------------------------------------------------------
// stab (f64; f32 variant BANNED: 2/2 Inf correlation, rounds 7 & 14)
// ------------------------------------------------------------------
__global__ __launch_bounds__(256) void k_stab(const double* __restrict__ x1a, const double* __restrict__ Xca,
    double* __restrict__ stabp){
  __shared__ double Bsm[NPP*3];
  __shared__ double red[8];
  int blk=blockIdx.x;
  int bd=blk/125, rg=blk%125;
  int b=bd>>1, dir=bd&1;
  int tid=threadIdx.x;
  const double* Ap = (dir==0) ? (x1a + (size_t)b*NPP*3) : (Xca + (size_t)(b*2+1)*NPP*3);
  const double* Bp = (dir==0) ? (Xca + (size_t)(b*2+1)*NPP*3) : (x1a + (size_t)b*NPP*3);
  for(int idx=tid; idx<NPP*3; idx+=256) Bsm[idx]=Bp[idx]*STDV;
  __syncthreads();
  int row = rg*8 + (tid>>5);
  int jt = tid&31;
  double a0=Ap[row*3]*STDV, a1=Ap[row*3+1]*STDV, a2=Ap[row*3+2]*STDV;
  double mind=1e300;
  for(int j=jt;j<NPP;j+=32){
    double d0=a0-Bsm[j*3], d1=a1-Bsm[j*3+1], d2=a2-Bsm[j*3+2];
    double d=d0*d0+d1*d1+d2*d2;
    mind=fmin(mind,d);
  }
  #pragma unroll
  for(int off=16;off>0;off>>=1) mind=fmin(mind,__shfl_xor(mind,off,32));
  double se=0.0;
  for(int j=jt;j<NPP;j+=32){
    double d0=a0-Bsm[j*3], d1=a1-Bsm[j*3+1], d2=a2-Bsm[j*3+2];
    double d=d0*d0+d1*d1+d2*d2;
    se += exp((mind-d)*(1.0/SIGC));
  }
  #pragma unroll
  for(int off=16;off>0;off>>=1) se += __shfl_xor(se,off,32);
  if(jt==0) red[tid>>5] = fmax(GAMC - mind + SIGC*log(se), 0.0);
  __syncthreads();
  if(tid==0){
    double s=0.0;
    #pragma unroll
    for(int i=0;i<8;i++) s+=red[i];
    stabp[blk]=s;
  }
}

__global__ void k_out(const double* __restrict__ otb, const double* __restrict__ dockb,
    const double* __restrict__ rmsdb, const double* __restrict__ stabp, float* __restrict__ out){
  if(blockIdx.x==0 && threadIdx.x==0){
    double ot=0.0,dock=0.0,rmsd=0.0,stab=0.0;
    for(int b=0;b<BSZ;b++){
      ot+=otb[b]; dock+=dockb[b]; rmsd+=rmsdb[b];
      double s1=0.0,s2=0.0;
      for(int i=0;i<125;i++){ s1+=stabp[(b*2+0)*125+i]; s2+=stabp[(b*2+1)*125+i]; }
      stab += (s1*(1.0/NPP) + s2*(1.0/NPP))*(1.0/STDV);
    }
    ot*=0.25; dock*=0.25; rmsd*=0.25; stab*=0.25;
    out[0]=(float)(ot+dock+stab); out[1]=(float)ot; out[2]=(float)dock; out[3]=(float)stab; out[4]=(float)rmsd;
  }
}

// ------------------------------------------------------------------
extern "C" void kernel_launch(void* const* d_in, const int* in_sizes, int n_in,
                              void* d_out, int out_size, void* d_ws, size_t ws_size,
                              hipStream_t stream){
  const float* X      = (const float*)d_in[0];
  const float* nodea  = (const float*)d_in[1];
  const float* edgea  = (const float*)d_in[2];
  const float* center = (const float*)d_in[3];
  const float* kpin   = (const float*)d_in[4];
  const float* rot    = (const float*)d_in[5];
  const float* trans  = (const float*)d_in[6];
  const float* W_in1  = (const float*)d_in[7];
  const float* b_in1  = (const float*)d_in[8];
  const float* W_in2  = (const float*)d_in[9];
  const float* b_in2  = (const float*)d_in[10];
  const float* msg_W  = (const float*)d_in[11];
  const float* msg_b  = (const float*)d_in[12];
  const float* upd_W1 = (const float*)d_in[13];
  const float* upd_b1 = (const float*)d_in[14];
  const float* upd_W2 = (const float*)d_in[15];
  const float* upd_b2 = (const float*)d_in[16];
  const float* x_W    = (const float*)d_in[17];
  const float* v_W    = (const float*)d_in[18];
  const float* att_W  = (const float*)d_in[19];
  const float* act_W1 = (const float*)d_in[20];
  const float* act_b1 = (const float*)d_in[21];
  const float* act_W2 = (const float*)d_in[22];
  const float* act_b2 = (const float*)d_in[23];
  const float* geb_Wv1= (const float*)d_in[24];
  const float* geb_Wv2= (const float*)d_in[25];
  const float* geb_W1 = (const float*)d_in[26];
  const float* geb_b1 = (const float*)d_in[27];
  const float* geb_W2 = (const float*)d_in[28];
  const float* geb_b2 = (const float*)d_in[29];
  const float* sc_W1  = (const float*)d_in[30];
  const float* sc_b1  = (const float*)d_in[31];
  const float* sc_W2  = (const float*)d_in[32];
  const float* sc_b2  = (const float*)d_in[33];
  const float* fin_W  = (const float*)d_in[34];
  const int*   src    = (const int*)d_in[35];
  const int*   dst    = (const int*)d_in[36];
  float* out = (float*)d_out;

  double* wd = (double*)d_ws;
  size_t o = 0;
  double* XcaD  = wd + o; o += (size_t)NN*3;
  double* ori0D = wd + o; o += (size_t)BSZ*NPP*3;
  double* kpcD  = wd + o; o += 144;
  double* tkpcD = wd + o; o += 144;
  double* dirvD = wd + o; o += (size_t)EE*3;
  double* rbfD  = wd + o; o += (size_t)EE*RBFD;
  double* hbuf  = wd + o; o += (size_t)NN*HD;
  double* Pbuf  = wd + o; o += (size_t)NN*256;
  double* mbuf  = wd + o; o += (size_t)EE*HD;   // h2 lives here
  double* va    = wd + o; o += (size_t)NN*HD*3;
  double* vb    = wd + o; o += (size_t)NN*HD*3;
  double* ubuf  = wd + o; o += (size_t)BSZ*2*HD;
  double* attp  = wd + o; o += (size_t)64*HD;
  double* nv2b  = wd + o; o += (size_t)NN*HD;
  double* sbuf  = wd + o; o += (size_t)NN*256;
  double* cbbD  = wd + o; o += 24;
  double* ypartD= wd + o; o += (size_t)4000*37;
  double* YbufD = wd + o; o += 8*36;
  double* x1aD  = wd + o; o += (size_t)BSZ*NPP*3;
  double* otb_  = wd + o; o += 4;
  double* dkb_  = wd + o; o += 4;
  double* rmb_  = wd + o; o += 4;
  double* stp_  = wd + o; o += 1000;
  double* Wnode = wd + o; o += (size_t)4*128*256;
  double* Wedge2= wd + o; o += (size_t)4*37*128;
  double* xvW   = wd + o; o += (size_t)4*128*256;

  double* h2b  = mbuf;

  size_t need = o*8;
  if(ws_size < need){
    float mb = (float)((double)ws_size / 1.0e6);
    float val = (131072.0f + mb) * 1048576.0f;
    k_sent<<<1,64,0,stream>>>(out, val);
    return;
  }

  hipMemsetAsync(va, 0, (size_t)NN*HD*3*sizeof(double), stream);

  k_cvt_node<<<512,256,0,stream>>>(msg_W, Wnode);
  k_cvt_edge<<<74,256,0,stream>>>(msg_W, msg_b, Wedge2);
  k_cvt_xv<<<256,256,0,stream>>>(x_W, v_W, xvW);

  k_geom<<<32,256,0,stream>>>(X, center, kpin, rot, trans, XcaD, ori0D, kpcD, tkpcD);
  k_edge<<<(EE+255)/256,256,0,stream>>>(XcaD, src, dst, dirvD, rbfD);
  k_hinit<<<NN/4,256,0,stream>>>(nodea, W_in1, b_in1, W_in2, b_in2, hbuf);

  double* vcur = va;
  double* vnxt = vb;
  for(int l=0;l<NL;l++){
    const double* Wn  = Wnode  + (size_t)l*128*256;
    const double* We  = Wedge2 + (size_t)l*37*128;
    const double* xvl = xvW    + (size_t)l*128*256;
    const float* u1W = upd_W1 + (size_t)l*256*HD;
    const float* u1b = upd_b1 + (size_t)l*HD;
    const float* u2W = upd_W2 + (size_t)l*HD*HD;
    const float* u2b = upd_b2 + (size_t)l*HD;
    const float* aWl = att_W  + (size_t)l*HD*HD;
    const float* a1W = act_W1 + (size_t)l*HD*HD;
    const float* a1b = act_b1 + (size_t)l*HD;
    const float* a2W = act_W2 + (size_t)l*HD*HD;
    const float* a2b = act_b2 + (size_t)l*HD;

    k_nodeproj<<<NN/8,256,0,stream>>>(hbuf, Wn, Pbuf);
    k_layer<<<NN/4,256,0,stream>>>(Pbuf, rbfD, edgea, src, We,
                                   hbuf, u1W, u1b, u2W, u2b, h2b,
                                   vcur, dirvD, xvl, vnxt);
    k_att1<<<64,128,0,stream>>>(h2b, attp);
    k_att2<<<8,128,0,stream>>>(attp, aWl, ubuf);
    k_actcomb<<<NN/4,128,0,stream>>>(h2b, ubuf, a1W, a1b, a2W, a2b, hbuf);
    double* tmp=vcur; vcur=vnxt; vnxt=tmp;
  }
  // vcur == va (final v), vnxt == vb (free -> v1)
  k_gebv<<<NN/2,256,0,stream>>>(vcur, geb_Wv1, geb_Wv2, vnxt, nv2b);
  k_gebs<<<NN/4,256,0,stream>>>(hbuf, nv2b, geb_W1, geb_b1, geb_W2, geb_b2, sbuf);
  k_kpc<<<8,256,0,stream>>>(XcaD, cbbD);
  k_kpgen<<<NN/2,256,0,stream>>>(XcaD, sbuf, vnxt, cbbD, fin_W, sc_W1, sc_b1, sc_W2, sc_b2, ypartD);
  k_kpfin<<<8,64,0,stream>>>(ypartD, cbbD, YbufD);
  k_final<<<BSZ,256,0,stream>>>(YbufD, tkpcD, kpcD, rot, trans, XcaD, ori0D, x1aD, otb_, dkb_, rmb_);
  k_stab<<<1000,256,0,stream>>>(x1aD, XcaD, stp_);
  k_out<<<1,64,0,stream>>>(otb_, dkb_, rmb_, stp_, out);
}

// Round 17
// 1406.691 us; speedup vs baseline: 1.6726x; 1.0736x over previous
//
#include <hip/hip_runtime.h>
#include <math.h>

#define NPP 1000
#define BSZ 4
#define HD 128
#define NL 4
#define RBFD 20
#define EDD 16
#define KN 9
#define NKPP 12
#define NN 8000
#define EE 72000
#define STDV 10.0
#define SIGC 25.0
#define GAMC 10.0
#define PID 3.14159265358979323846

__device__ __forceinline__ double silud(double x){ return x / (1.0 + exp(-x)); }

__global__ void k_sent(float* __restrict__ out, float val){
  if(threadIdx.x<5 && blockIdx.x==0) out[threadIdx.x]=val;
}

// ------------------------------------------------------------------
// weight preconversion to f64
// ------------------------------------------------------------------
__global__ __launch_bounds__(256) void k_cvt_node(const float* __restrict__ msgW, double* __restrict__ Wn){
  int idx = blockIdx.x*256+threadIdx.x;
  if(idx >= 4*128*256) return;
  int l = idx>>15; int r = idx & 32767; int k = r>>8; int j = r&255;
  const float* W = msgW + (size_t)l*292*128;
  Wn[idx] = (j<128) ? (double)W[k*128+j] : (double)W[(128+k)*128 + (j-128)];
}
__global__ __launch_bounds__(256) void k_cvt_edge(const float* __restrict__ msgW, const float* __restrict__ msgb,
    double* __restrict__ We){
  int idx = blockIdx.x*256+threadIdx.x;
  if(idx >= 4*37*128) return;
  int l = idx/(37*128); int r = idx%(37*128); int k = r>>7; int j = r&127;
  if(k<36) We[idx] = (double)msgW[(size_t)l*292*128 + (256+k)*128 + j];
  else     We[idx] = (double)msgb[l*128 + j];
}
__global__ __launch_bounds__(256) void k_cvt_xv(const float* __restrict__ xW, const float* __restrict__ vW,
    double* __restrict__ xv){
  int idx = blockIdx.x*256+threadIdx.x;
  if(idx >= 4*128*128) return;
  int l = idx>>14; int r = idx & 16383; int hh = r>>7; int c = r&127;
  xv[(size_t)l*32768 + hh*256 + 2*c]   = (double)xW[(size_t)l*16384 + hh*128 + c];
  xv[(size_t)l*32768 + hh*256 + 2*c+1] = (double)vW[(size_t)l*16384 + hh*128 + c];
}

// ------------------------------------------------------------------
// geometry (f64)
// ------------------------------------------------------------------
__global__ __launch_bounds__(256) void k_geom(const float* __restrict__ X, const float* __restrict__ center,
    const float* __restrict__ kpin, const float* __restrict__ rot, const float* __restrict__ trans,
    double* __restrict__ Xca, double* __restrict__ ori0, double* __restrict__ kpc, double* __restrict__ tkpc){
  int i = blockIdx.x*256 + threadIdx.x;
  const double inv = 1.0/STDV;
  if(i < NN){
    int b = i / (2*NPP);
    int s = (i / NPP) & 1;
    int n = i % NPP;
    double q0 = (double)X[i*12+3] - (double)center[b*3+0];
    double q1 = (double)X[i*12+4] - (double)center[b*3+1];
    double q2 = (double)X[i*12+5] - (double)center[b*3+2];
    if(s==0){
      int o=(b*NPP+n)*3;
      ori0[o]=q0*inv; ori0[o+1]=q1*inv; ori0[o+2]=q2*inv;
      const float* R = rot + b*9;
      #pragma unroll
      for(int d=0; d<3; d++)
        Xca[i*3+d] = (q0*(double)R[d] + q1*(double)R[3+d] + q2*(double)R[6+d])*inv + (double)trans[b*3+d];
    } else {
      Xca[i*3+0]=q0*inv; Xca[i*3+1]=q1*inv; Xca[i*3+2]=q2*inv;
    }
  } else if(i < NN + BSZ*NKPP){
    int j = i - NN;
    int b = j / NKPP;
    double q0 = (double)kpin[j*3+0]-(double)center[b*3+0];
    double q1 = (double)kpin[j*3+1]-(double)center[b*3+1];
    double q2 = (double)kpin[j*3+2]-(double)center[b*3+2];
    kpc[j*3+0]=q0*inv; kpc[j*3+1]=q1*inv; kpc[j*3+2]=q2*inv;
    const float* R = rot + b*9;
    #pragma unroll
    for(int d=0; d<3; d++)
      tkpc[j*3+d] = (q0*(double)R[d] + q1*(double)R[3+d] + q2*(double)R[6+d])*inv + (double)trans[b*3+d];
  }
}

// ------------------------------------------------------------------
__global__ __launch_bounds__(256) void k_edge(const double* __restrict__ Xca, const int* __restrict__ src,
    const int* __restrict__ dst, double* __restrict__ dirv, double* __restrict__ rbfb){
  int e = blockIdx.x*256 + threadIdx.x;
  if(e >= EE) return;
  int sp = src[e], dp = dst[e];
  double d0 = Xca[dp*3+0]-Xca[sp*3+0];
  double d1 = Xca[dp*3+1]-Xca[sp*3+1];
  double d2 = Xca[dp*3+2]-Xca[sp*3+2];
  double nr = sqrt(d0*d0+d1*d1+d2*d2) + 1e-08;
  double iv = 1.0/nr;
  dirv[e*3+0]=d0*iv; dirv[e*3+1]=d1*iv; dirv[e*3+2]=d2*iv;
  #pragma unroll
  for(int j=0;j<RBFD;j++)
    rbfb[e*RBFD+j] = sin(nr*(double)(j+1)*PID)*iv;
}

// ------------------------------------------------------------------
// h init: 4 nodes/block, 256 thr
// ------------------------------------------------------------------
__global__ __launch_bounds__(256) void k_hinit(const float* __restrict__ na,
    const float* __restrict__ W1, const float* __restrict__ b1,
    const float* __restrict__ W2, const float* __restrict__ b2, double* __restrict__ h){
  __shared__ double cin[4][64];
  __shared__ double hmid[4][128];
  int n0 = blockIdx.x*4;
  int tid = threadIdx.x;
  {
    int r=tid>>6, k=tid&63;
    cin[r][k] = (double)na[(n0+r)*64 + k];
  }
  __syncthreads();
  int r = tid>>6, c0 = (tid&63)*2;
  double a0=(double)b1[c0], a1=(double)b1[c0+1];
  for(int k=0;k<64;k++){
    double a = cin[r][k];
    const float* wp = W1 + k*HD + c0;
    a0 += a*(double)wp[0]; a1 += a*(double)wp[1];
  }
  hmid[r][c0]=silud(a0); hmid[r][c0+1]=silud(a1);
  __syncthreads();
  double s0=(double)b2[c0], s1=(double)b2[c0+1];
  for(int k=0;k<HD;k++){
    double a = hmid[r][k];
    const float* wp = W2 + k*HD + c0;
    s0 += a*(double)wp[0]; s1 += a*(double)wp[1];
  }
  h[(size_t)(n0+r)*HD+c0]=s0; h[(size_t)(n0+r)*HD+c0+1]=s1;
}

// ------------------------------------------------------------------
// node projection: 8 nodes/block, 256 thr
// ------------------------------------------------------------------
__global__ __launch_bounds__(256) void k_nodeproj(const double* __restrict__ h, const double* __restrict__ Wn,
    double* __restrict__ P){
  __shared__ double cin[8][128];
  int n0 = blockIdx.x*8;
  int tid = threadIdx.x;
  for(int idx=tid; idx<1024; idx+=256){
    int r=idx>>7, k=idx&127;
    cin[r][k]=h[(size_t)(n0+r)*HD+k];
  }
  __syncthreads();
  int half = tid>>7;
  int r0 = half*4;
  int c0 = (tid&127)*2;
  double a00=0,a01=0,a10=0,a11=0,a20=0,a21=0,a30=0,a31=0;
  for(int k=0;k<128;k++){
    double2 w = *(const double2*)(Wn + (size_t)k*256 + c0);
    double x0=cin[r0+0][k],x1=cin[r0+1][k],x2=cin[r0+2][k],x3=cin[r0+3][k];
    a00+=x0*w.x; a01+=x0*w.y; a10+=x1*w.x; a11+=x1*w.y;
    a20+=x2*w.x; a21+=x2*w.y; a30+=x3*w.x; a31+=x3*w.y;
  }
  P[(size_t)(n0+r0+0)*256+c0]=a00; P[(size_t)(n0+r0+0)*256+c0+1]=a01;
  P[(size_t)(n0+r0+1)*256+c0]=a10; P[(size_t)(n0+r0+1)*256+c0+1]=a11;
  P[(size_t)(n0+r0+2)*256+c0]=a20; P[(size_t)(n0+r0+2)*256+c0+1]=a21;
  P[(size_t)(n0+r0+3)*256+c0]=a30; P[(size_t)(n0+r0+3)*256+c0+1]=a31;
}

// ------------------------------------------------------------------
// fused layer kernel: edge messages (into LDS) + upd-MLP + v-update
// phase A kk-paired (2 indep chains, agg order preserved);
// phase B 4-way interleaved; phase C hh x2 unrolled
// ------------------------------------------------------------------
__global__ __launch_bounds__(256) void k_layer(
    const double* __restrict__ P, const double* __restrict__ rbfb, const float* __restrict__ ea,
    const int* __restrict__ src, const double* __restrict__ We,
    const double* __restrict__ h, const float* __restrict__ W1, const float* __restrict__ b1,
    const float* __restrict__ W2, const float* __restrict__ b2, double* __restrict__ h2,
    const double* __restrict__ va, const double* __restrict__ dirv, const double* __restrict__ xv,
    double* __restrict__ vb){
  __shared__ double mT[4][9][128];
  __shared__ double scratch[1536];
  __shared__ double dv[4][9][3];
  __shared__ int sp[4][9];
  int n0 = blockIdx.x*4;
  int tid = threadIdx.x;
  int e0 = n0*KN;
  for(int idx=tid; idx<36*RBFD; idx+=256){
    int e=idx/RBFD, f=idx-e*RBFD;
    scratch[e*37+f] = rbfb[(size_t)(e0+e)*RBFD+f];
  }
  for(int idx=tid; idx<36*EDD; idx+=256){
    int e=idx>>4, f=idx&15;
    scratch[e*37+20+f] = (double)ea[(size_t)(e0+e)*EDD+f];
  }
  if(tid<36){
    scratch[tid*37+36]=1.0;
    int nd=tid/9, kk=tid-nd*9;
    int e=e0+nd*9+kk;
    sp[nd][kk]=src[e];
    dv[nd][kk][0]=dirv[e*3]; dv[nd][kk][1]=dirv[e*3+1]; dv[nd][kk][2]=dirv[e*3+2];
  }
  int half = tid>>7, colp = tid&127;
  double wreg[37];
  #pragma unroll
  for(int f=0;f<37;f++) wreg[f]=We[f*128+colp];
  __syncthreads();
  // ---- phase A (kk paired: 2 independent 37-chains; agg order preserved)
  double aggv0=0.0, aggv1=0.0;
  #pragma unroll
  for(int u=0;u<2;u++){
    int nd = half*2+u;
    double p2 = P[(size_t)(n0+nd)*256 + 128 + colp];
    double agg=0.0;
    for(int kk=0;kk<8;kk+=2){
      const double* fe0 = &scratch[(nd*9+kk)*37];
      const double* fe1 = &scratch[(nd*9+kk+1)*37];
      double pg0 = P[(size_t)sp[nd][kk]*256 + colp];
      double pg1 = P[(size_t)sp[nd][kk+1]*256 + colp];
      double acc0=0.0, acc1=0.0;
      #pragma unroll
      for(int f=0;f<37;f++){ acc0 += fe0[f]*wreg[f]; acc1 += fe1[f]*wreg[f]; }
      double mv0 = silud(acc0 + pg0 + p2);
      double mv1 = silud(acc1 + pg1 + p2);
      mT[nd][kk][colp]=mv0;
      mT[nd][kk+1][colp]=mv1;
      agg += mv0;
      agg += mv1;
    }
    {
      const double* fe = &scratch[(nd*9+8)*37];
      double acc=0.0;
      #pragma unroll
      for(int f=0;f<37;f++) acc += fe[f]*wreg[f];
      double mv_ = silud(acc + P[(size_t)sp[nd][8]*256 + colp] + p2);
      mT[nd][8][colp]=mv_;
      agg += mv_;
    }
    if(u==0) aggv0=agg; else aggv1=agg;
  }
  __syncthreads();
  {
    int ndA = half*2, ndB = ndA+1;
    scratch[ndA*256+colp]     = h[(size_t)(n0+ndA)*HD+colp];
    scratch[ndA*256+128+colp] = aggv0;
    scratch[ndB*256+colp]     = h[(size_t)(n0+ndB)*HD+colp];
    scratch[ndB*256+128+colp] = aggv1;
  }
  __syncthreads();
  // ---- phase B (4-way interleaved accumulators)
  {
    int ndA = half*2, ndB = ndA+1;
    double a00=0,a01=0,a02=0,a03=0, a10=0,a11=0,a12=0,a13=0;
    for(int k=0;k<256;k+=4){
      double w0 = (double)W1[(size_t)k*HD+colp];
      double w1 = (double)W1[(size_t)(k+1)*HD+colp];
      double w2 = (double)W1[(size_t)(k+2)*HD+colp];
      double w3 = (double)W1[(size_t)(k+3)*HD+colp];
      a00 += scratch[ndA*256+k]*w0;   a01 += scratch[ndA*256+k+1]*w1;
      a02 += scratch[ndA*256+k+2]*w2; a03 += scratch[ndA*256+k+3]*w3;
      a10 += scratch[ndB*256+k]*w0;   a11 += scratch[ndB*256+k+1]*w1;
      a12 += scratch[ndB*256+k+2]*w2; a13 += scratch[ndB*256+k+3]*w3;
    }
    double a0 = (double)b1[colp] + ((a00+a01)+(a02+a03));
    double a1 = (double)b1[colp] + ((a10+a11)+(a12+a13));
    scratch[1024+ndA*128+colp]=silud(a0);
    scratch[1024+ndB*128+colp]=silud(a1);
  }
  __syncthreads();
  {
    int ndA = half*2, ndB = ndA+1;
    double a00=0,a01=0,a02=0,a03=0, a10=0,a11=0,a12=0,a13=0;
    for(int k=0;k<128;k+=4){
      double w0 = (double)W2[(size_t)k*HD+colp];
      double w1 = (double)W2[(size_t)(k+1)*HD+colp];
      double w2 = (double)W2[(size_t)(k+2)*HD+colp];
      double w3 = (double)W2[(size_t)(k+3)*HD+colp];
      a00 += scratch[1024+ndA*128+k]*w0;   a01 += scratch[1024+ndA*128+k+1]*w1;
      a02 += scratch[1024+ndA*128+k+2]*w2; a03 += scratch[1024+ndA*128+k+3]*w3;
      a10 += scratch[1024+ndB*128+k]*w0;   a11 += scratch[1024+ndB*128+k+1]*w1;
      a12 += scratch[1024+ndB*128+k+2]*w2; a13 += scratch[1024+ndB*128+k+3]*w3;
    }
    double a0 = (double)b2[colp] + ((a00+a01)+(a02+a03));
    double a1 = (double)b2[colp] + ((a10+a11)+(a12+a13));
    h2[(size_t)(n0+ndA)*HD+colp] = scratch[ndA*256+colp] + a0;
    h2[(size_t)(n0+ndB)*HD+colp] = scratch[ndB*256+colp] + a1;
  }
  __syncthreads();
  // ---- phase C: md then v-update, hh unrolled x2
  for(int idx=tid; idx<1536; idx+=256){
    int hh=idx&127, t2=idx>>7; int nd=t2/3, c=t2-nd*3;
    double s=0.0;
    #pragma unroll
    for(int kk=0;kk<9;kk++) s += dv[nd][kk][c]*mT[nd][kk][hh];
    scratch[nd*384 + c*128 + hh]=s;
  }
  __syncthreads();
  int nd = tid>>6;
  int t  = tid&63;
  int c0 = 2*t;
  double oA0=0,oA1=0,oA2=0, oB0=0,oB1=0,oB2=0;
  double mvA[9], mvB[9];
  #pragma unroll
  for(int kk=0;kk<9;kk++){ mvA[kk]=0.0; mvB[kk]=0.0; }
  const double* mdb = &scratch[nd*384];
  for(int hh=0; hh<128; hh+=2){
    const double* xp0 = xv + (size_t)hh*256 + 2*c0;
    const double* xp1 = xp0 + 256;
    double2 wpA0 = *(const double2*)(xp0);
    double2 wpB0 = *(const double2*)(xp0+2);
    double2 wpA1 = *(const double2*)(xp1);
    double2 wpB1 = *(const double2*)(xp1+2);
    double d00 = mdb[hh],     d10 = mdb[128+hh],   d20 = mdb[256+hh];
    double d01 = mdb[hh+1],   d11 = mdb[128+hh+1], d21 = mdb[256+hh+1];
    oA0 += d00*wpA0.x; oA1 += d10*wpA0.x; oA2 += d20*wpA0.x;
    oB0 += d00*wpB0.x; oB1 += d10*wpB0.x; oB2 += d20*wpB0.x;
    oA0 += d01*wpA1.x; oA1 += d11*wpA1.x; oA2 += d21*wpA1.x;
    oB0 += d01*wpB1.x; oB1 += d11*wpB1.x; oB2 += d21*wpB1.x;
    #pragma unroll
    for(int kk=0;kk<9;kk++){
      double mk0 = mT[nd][kk][hh];
      double mk1 = mT[nd][kk][hh+1];
      mvA[kk] += mk0*wpA0.y;
      mvB[kk] += mk0*wpB0.y;
      mvA[kk] += mk1*wpA1.y;
      mvB[kk] += mk1*wpB1.y;
    }
  }
  #pragma unroll
  for(int kk=0;kk<9;kk++){
    size_t s3 = (size_t)sp[nd][kk]*384 + c0*3;
    double ka = mvA[kk], kb = mvB[kk];
    oA0 += va[s3]*ka;   oA1 += va[s3+1]*ka; oA2 += va[s3+2]*ka;
    oB0 += va[s3+3]*kb; oB1 += va[s3+4]*kb; oB2 += va[s3+5]*kb;
  }
  size_t b3 = (size_t)(n0+nd)*384 + c0*3;
  vb[b3]  = va[b3]  + oA0;
  vb[b3+1]= va[b3+1]+ oA1;
  vb[b3+2]= va[b3+2]+ oA2;
  vb[b3+3]= va[b3+3]+ oB0;
  vb[b3+4]= va[b3+4]+ oB1;
  vb[b3+5]= va[b3+5]+ oB2;
}

// ------------------------------------------------------------------
// attention partials + finish
// ------------------------------------------------------------------
__global__ __launch_bounds__(128) void k_att1(const double* __restrict__ h2, double* __restrict__ partial){
  int blk = blockIdx.x;
  int bs = blk>>3, ch = blk&7;
  int col = threadIdx.x;
  size_t base = ((size_t)bs*NPP + ch*125)*HD + col;
  double s=0.0;
  for(int i=0;i<125;i++) s += h2[base + (size_t)i*HD];
  partial[(size_t)blk*HD + col] = s;
}
__global__ __launch_bounds__(128) void k_att2(const double* __restrict__ partial, const float* __restrict__ attW,
    double* __restrict__ u){
  __shared__ double mm[128];
  int bs = blockIdx.x;
  int col = threadIdx.x;
  int os = bs^1;
  double s=0.0;
  for(int c=0;c<8;c++) s += partial[(size_t)(os*8+c)*HD + col];
  mm[col] = s*(1.0/NPP);
  __syncthreads();
  double acc=0.0;
  for(int k=0;k<HD;k++) acc += (double)attW[col*HD+k]*mm[k];
  u[bs*HD+col] = acc;
}

// ------------------------------------------------------------------
// h_new = intra + g*act(intra), g fused; k-interleaved x2 (ILP 8)
// ------------------------------------------------------------------
__global__ __launch_bounds__(128) void k_actcomb(const double* __restrict__ h2, const double* __restrict__ u,
    const float* __restrict__ W1, const float* __restrict__ b1,
    const float* __restrict__ W2, const float* __restrict__ b2, double* __restrict__ h){
  __shared__ double As[4][128];
  __shared__ double hmid[4][128];
  __shared__ double pd[128];
  __shared__ double gsh[4];
  int n0 = blockIdx.x*4;
  int tid = threadIdx.x;
  int bs = n0/NPP;
  for(int idx=tid; idx<512; idx+=128){
    int r=idx>>7, k=idx&127;
    As[r][k] = h2[(size_t)(n0+r)*HD+k];
  }
  __syncthreads();
  {
    int nd=tid>>5, q=tid&31;
    double p=0.0;
    for(int j=q;j<128;j+=32) p += As[nd][j]*u[bs*HD+j];
    pd[tid]=p;
  }
  __syncthreads();
  if((tid&31)==0){
    int nd=tid>>5;
    double s=0.0;
    for(int i2=0;i2<32;i2++) s+=pd[nd*32+i2];
    gsh[nd]=1.0/(1.0+exp(-s));
  }
  __syncthreads();
  int col = tid;
  {
    double a0a=0,a0b=0,a1a=0,a1b=0,a2a=0,a2b=0,a3a=0,a3b=0;
    for(int k=0;k<128;k+=2){
      double w0 = (double)W1[(size_t)k*HD+col];
      double w1 = (double)W1[(size_t)(k+1)*HD+col];
      a0a += As[0][k]*w0; a0b += As[0][k+1]*w1;
      a1a += As[1][k]*w0; a1b += As[1][k+1]*w1;
      a2a += As[2][k]*w0; a2b += As[2][k+1]*w1;
      a3a += As[3][k]*w0; a3b += As[3][k+1]*w1;
    }
    double bb=(double)b1[col];
    hmid[0][col]=silud(bb+(a0a+a0b));
    hmid[1][col]=silud(bb+(a1a+a1b));
    hmid[2][col]=silud(bb+(a2a+a2b));
    hmid[3][col]=silud(bb+(a3a+a3b));
  }
  __syncthreads();
  {
    double a0a=0,a0b=0,a1a=0,a1b=0,a2a=0,a2b=0,a3a=0,a3b=0;
    for(int k=0;k<128;k+=2){
      double w0 = (double)W2[(size_t)k*HD+col];
      double w1 = (double)W2[(size_t)(k+1)*HD+col];
      a0a += hmid[0][k]*w0; a0b += hmid[0][k+1]*w1;
      a1a += hmid[1][k]*w0; a1b += hmid[1][k+1]*w1;
      a2a += hmid[2][k]*w0; a2b += hmid[2][k+1]*w1;
      a3a += hmid[3][k]*w0; a3b += hmid[3][k+1]*w1;
    }
    double bb=(double)b2[col];
    h[(size_t)(n0+0)*HD+col] = As[0][col] + gsh[0]*(bb+(a0a+a0b));
    h[(size_t)(n0+1)*HD+col] = As[1][col] + gsh[1]*(bb+(a1a+a1b));
    h[(size_t)(n0+2)*HD+col] = As[2][col] + gsh[2]*(bb+(a2a+a2b));
    h[(size_t)(n0+3)*HD+col] = As[3][col] + gsh[3]*(bb+(a3a+a3b));
  }
}

// ------------------------------------------------------------------
// geb vector branch
// ------------------------------------------------------------------
__global__ __launch_bounds__(256) void k_gebv(const double* __restrict__ va,
    const float* __restrict__ Wv1, const float* __restrict__ Wv2,
    double* __restrict__ v1, double* __restrict__ nv2){
  __shared__ double vl[2][384];
  int n0 = blockIdx.x*2;
  int tid = threadIdx.x;
  for(int idx=tid; idx<768; idx+=256){
    int r=idx/384, k=idx%384;
    vl[r][k] = va[(size_t)(n0+r)*384+k];
  }
  __syncthreads();
  int r = tid>>7, col = tid&127;
  double a10=0.0,a11=0.0,a12=0.0, a20=0.0,a21=0.0,a22=0.0;
  for(int hh=0; hh<HD; hh++){
    double w1 = (double)Wv1[hh*HD+col];
    double w2 = (double)Wv2[hh*HD+col];
    double v0=vl[r][hh*3], v1e=vl[r][hh*3+1], v2e=vl[r][hh*3+2];
    a10+=v0*w1; a11+=v1e*w1; a12+=v2e*w1;
    a20+=v0*w2; a21+=v1e*w2; a22+=v2e*w2;
  }
  size_t b3=(size_t)(n0+r)*384+col*3;
  v1[b3]=a10; v1[b3+1]=a11; v1[b3+2]=a12;
  nv2[(size_t)(n0+r)*HD+col]=sqrt(a20*a20+a21*a21+a22*a22);
}

// ------------------------------------------------------------------
// s = silu([h,nv2]@gebW1+b1)@gebW2+b2
// ------------------------------------------------------------------
__global__ __launch_bounds__(256) void k_gebs(const double* __restrict__ h, const double* __restrict__ nv2,
    const float* __restrict__ W1, const float* __restrict__ b1,
    const float* __restrict__ W2, const float* __restrict__ b2, double* __restrict__ s){
  __shared__ double cin[4][256];
  __shared__ double hmid[4][128];
  int n0 = blockIdx.x*4;
  int tid = threadIdx.x;
  for(int idx=tid; idx<4*HD; idx+=256){
    int r=idx>>7, k=idx&127;
    cin[r][k]    = h[(size_t)(n0+r)*HD + k];
    cin[r][HD+k] = nv2[(size_t)(n0+r)*HD + k];
  }
  __syncthreads();
  int r = tid>>6, c0 = (tid&63)*2;
  double a0=(double)b1[c0], a1=(double)b1[c0+1];
  for(int k=0;k<2*HD;k++){
    double a = cin[r][k];
    const float* wp = W1 + (size_t)k*HD + c0;
    a0 += a*(double)wp[0]; a1 += a*(double)wp[1];
  }
  hmid[r][c0]=silud(a0); hmid[r][c0+1]=silud(a1);
  __syncthreads();
  int c1 = (tid&63)*4;
  double s0=(double)b2[c1], s1=(double)b2[c1+1], s2=(double)b2[c1+2], s3=(double)b2[c1+3];
  for(int k=0;k<HD;k++){
    double a = hmid[r][k];
    const float* wp = W2 + (size_t)k*256 + c1;
    s0 += a*(double)wp[0]; s1 += a*(double)wp[1]; s2 += a*(double)wp[2]; s3 += a*(double)wp[3];
  }
  double* srow = s + (size_t)(n0+r)*256 + c1;
  srow[0]=s0; srow[1]=s1; srow[2]=s2; srow[3]=s3;
}

// ------------------------------------------------------------------
__global__ __launch_bounds__(256) void k_kpc(const double* __restrict__ Xca, double* __restrict__ cbb){
  __shared__ double red[768];
  int bs = blockIdx.x;
  int tid = threadIdx.x;
  double s0=0.0,s1=0.0,s2=0.0;
  for(int nidx=tid; nidx<NPP; nidx+=256){
    int i = bs*NPP+nidx;
    s0+=Xca[i*3]; s1+=Xca[i*3+1]; s2+=Xca[i*3+2];
  }
  red[tid]=s0; red[256+tid]=s1; red[512+tid]=s2;
  __syncthreads();
  for(int st=128; st>0; st>>=1){
    if(tid<st){ red[tid]+=red[tid+st]; red[256+tid]+=red[256+tid+st]; red[512+tid]+=red[512+tid+st]; }
    __syncthreads();
  }
  if(tid==0){ cbb[bs*3]=red[0]*(1.0/NPP); cbb[bs*3+1]=red[256]*(1.0/NPP); cbb[bs*3+2]=red[512]*(1.0/NPP); }
}

// ------------------------------------------------------------------
// keypoint partials: 2 nodes/block
// ------------------------------------------------------------------
__global__ __launch_bounds__(256) void k_kpgen(const double* __restrict__ Xca, const double* __restrict__ sbuf,
    const double* __restrict__ v1, const double* __restrict__ cbb, const float* __restrict__ fW,
    const float* __restrict__ sW1, const float* __restrict__ sb1, const float* __restrict__ sW2,
    const float* __restrict__ sb2, double* __restrict__ ypart){
  __shared__ double tt[2][3][128];
  __shared__ double ssv[2][128];
  __shared__ double zz[2][64];
  __shared__ double snorm[2];
  __shared__ double ylL[2][37];
  int blk = blockIdx.x;
  int tid = threadIdx.x;
  int r = tid>>7, t = tid&127;
  int n = blk*2 + r;
  int bs = n/NPP;
  const double* srow = sbuf + (size_t)n*256;
  const double* vrow = v1 + (size_t)n*384;
  double gate = srow[128+t];
  double hp = srow[t];
  double vf0 = vrow[t*3+0]*gate, vf1 = vrow[t*3+1]*gate, vf2 = vrow[t*3+2]*gate;
  tt[r][0][t]=vf0*hp; tt[r][1][t]=vf1*hp; tt[r][2][t]=vf2*hp;
  ssv[r][t]=sqrt(vf0*vf0+vf1*vf1+vf2*vf2);
  if(t==0){
    double x0=Xca[n*3]-cbb[bs*3], x1=Xca[n*3+1]-cbb[bs*3+1], x2=Xca[n*3+2]-cbb[bs*3+2];
    snorm[r]=sqrt(x0*x0+x1*x1+x2*x2);
  }
  __syncthreads();
  if(t<36){
    int k2=t/3, c=t%3;
    double a=0.0;
    for(int hh=0; hh<128; hh++) a += tt[r][c][hh]*(double)fW[hh*NKPP+k2];
    ylL[r][t]=a;
  } else if(t>=64){
    int j=t-64;
    double z=(double)sb1[j];
    for(int hh=0; hh<128; hh++) z += ssv[r][hh]*(double)sW1[hh*64+j];
    z += snorm[r]*(double)sW1[128*64+j];
    zz[r][j]=silud(z)*(double)sW2[j];
  }
  __syncthreads();
  if(t==36){
    double dn=(double)sb2[0];
    for(int j=0;j<64;j++) dn+=zz[r][j];
    ylL[r][36]=dn;
  }
  __syncthreads();
  if(tid<37) ypart[(size_t)blk*37+tid]=ylL[0][tid]+ylL[1][tid];
}

__global__ __launch_bounds__(64) void k_kpfin(const double* __restrict__ ypart,
    const double* __restrict__ cbb, double* __restrict__ Y){
  __shared__ double sums[37];
  int bs=blockIdx.x, tid=threadIdx.x;
  if(tid<37){
    double s=0.0;
    for(int i=0;i<500;i++) s += ypart[(size_t)(bs*500+i)*37 + tid];
    sums[tid]=s;
  }
  __syncthreads();
  if(tid<36){
    double dsh = sums[36]*(1.0/NPP);
    Y[bs*36+tid] = sums[tid]/dsh + cbb[bs*3 + tid%3];
  }
}

// ------------------------------------------------------------------
// per-sample: ot, Kabsch (Horn quaternion), dock, rmsd, X1a
// ------------------------------------------------------------------
__global__ __launch_bounds__(256) void k_final(const double* __restrict__ Y, const double* __restrict__ tkpc,
    const double* __restrict__ kpc, const float* __restrict__ rot, const float* __restrict__ trans,
    const double* __restrict__ Xca, const double* __restrict__ ori0,
    double* __restrict__ x1a, double* __restrict__ otb, double* __restrict__ dockb, double* __restrict__ rmsdb){
  int b = blockIdx.x;
  int tid = threadIdx.x;
  __shared__ double Rs[9];
  __shared__ double ts[3];
  __shared__ double red[256];
  if(tid==0){
    const double* Y1 = Y + (b*2+0)*36;
    const double* Y2 = Y + (b*2+1)*36;
    const double* P1 = tkpc + b*36;
    const double* P2 = kpc + b*36;
    double ot1=0.0, ot2=0.0;
    for(int i=0;i<12;i++){
      double best1=1e300, best2=1e300;
      for(int j=0;j<12;j++){
        double d1=0.0, d2=0.0;
        #pragma unroll
        for(int c=0;c<3;c++){
          double e1=Y1[i*3+c]-P1[j*3+c]; d1+=e1*e1;
          double e2=Y2[i*3+c]-P2[j*3+c]; d2+=e2*e2;
        }
        best1=fmin(best1,d1); best2=fmin(best2,d2);
      }
      ot1+=best1; ot2+=best2;
    }
    double ot = ot1*(1.0/36.0) + ot2*(1.0/36.0);
    double c1[3]={0,0,0}, c2[3]={0,0,0};
    for(int i=0;i<12;i++)
      for(int c=0;c<3;c++){ c1[c]+=Y1[i*3+c]; c2[c]+=Y2[i*3+c]; }
    for(int c=0;c<3;c++){ c1[c]/=12.0; c2[c]/=12.0; }
    double Hm[3][3]={{0,0,0},{0,0,0},{0,0,0}};
    for(int i=0;i<12;i++)
      for(int a=0;a<3;a++)
        for(int c=0;c<3;c++)
          Hm[a][c] += (Y1[i*3+a]-c1[a])*(Y2[i*3+c]-c2[c]);
    double Sxx=Hm[0][0],Sxy=Hm[0][1],Sxz=Hm[0][2];
    double Syx=Hm[1][0],Syy=Hm[1][1],Syz=Hm[1][2];
    double Szx=Hm[2][0],Szy=Hm[2][1],Szz=Hm[2][2];
    double K[4][4];
    K[0][0]=Sxx+Syy+Szz; K[0][1]=Syz-Szy;     K[0][2]=Szx-Sxz;      K[0][3]=Sxy-Syx;
    K[1][0]=K[0][1];     K[1][1]=Sxx-Syy-Szz; K[1][2]=Sxy+Syx;      K[1][3]=Szx+Sxz;
    K[2][0]=K[0][2];     K[2][1]=K[1][2];     K[2][2]=-Sxx+Syy-Szz; K[2][3]=Syz+Szy;
    K[3][0]=K[0][3];     K[3][1]=K[1][3];     K[3][2]=K[2][3];      K[3][3]=-Sxx-Syy+Szz;
    double V[4][4]={{1,0,0,0},{0,1,0,0},{0,0,1,0},{0,0,0,1}};
    for(int sweep=0;sweep<30;sweep++){
      for(int p=0;p<3;p++) for(int q=p+1;q<4;q++){
        double apq=K[p][q];
        if(fabs(apq)<1e-300) continue;
        double tau=(K[q][q]-K[p][p])/(2.0*apq);
        double t=(tau>=0.0?1.0:-1.0)/(fabs(tau)+sqrt(tau*tau+1.0));
        double cs=1.0/sqrt(t*t+1.0), sn=t*cs;
        for(int r2=0;r2<4;r2++){
          double krp=K[r2][p], krq=K[r2][q];
          K[r2][p]=cs*krp - sn*krq;
          K[r2][q]=sn*krp + cs*krq;
        }
        for(int r2=0;r2<4;r2++){
          double kpr=K[p][r2], kqr=K[q][r2];
          K[p][r2]=cs*kpr - sn*kqr;
          K[q][r2]=sn*kpr + cs*kqr;
        }
        for(int r2=0;r2<4;r2++){
          double vrp=V[r2][p], vrq=V[r2][q];
          V[r2][p]=cs*vrp - sn*vrq;
          V[r2][q]=sn*vrp + cs*vrq;
        }
      }
    }
    int mi=0;
    for(int i2=1;i2<4;i2++) if(K[i2][i2]>K[mi][mi]) mi=i2;
    double qw=V[0][mi], qx=V[1][mi], qy=V[2][mi], qz=V[3][mi];
    double Rh[3][3];
    Rh[0][0]=qw*qw+qx*qx-qy*qy-qz*qz; Rh[0][1]=2.0*(qx*qy-qw*qz);       Rh[0][2]=2.0*(qx*qz+qw*qy);
    Rh[1][0]=2.0*(qx*qy+qw*qz);       Rh[1][1]=qw*qw-qx*qx+qy*qy-qz*qz; Rh[1][2]=2.0*(qy*qz-qw*qx);
    Rh[2][0]=2.0*(qx*qz-qw*qy);       Rh[2][1]=2.0*(qy*qz+qw*qx);       Rh[2][2]=qw*qw-qx*qx-qy*qy+qz*qz;
    double objT=0.0, objN=0.0;
    for(int a=0;a<3;a++) for(int c=0;c<3;c++){ objT+=Rh[c][a]*Hm[a][c]; objN+=Rh[a][c]*Hm[a][c]; }
    double Rm[3][3];
    if(objT>=objN){
      for(int a=0;a<3;a++) for(int c=0;c<3;c++) Rm[a][c]=Rh[c][a];
    } else {
      for(int a=0;a<3;a++) for(int c=0;c<3;c++) Rm[a][c]=Rh[a][c];
    }
    double tt[3];
    for(int d=0;d<3;d++) tt[d]=c2[d] - (c1[0]*Rm[0][d]+c1[1]*Rm[1][d]+c1[2]*Rm[2][d]);
    const float* Rt = rot + b*9;
    double dsum=0.0;
    for(int a=0;a<3;a++) for(int c=0;c<3;c++){
      double dd = Rm[a][c] - (double)Rt[c*3+a];
      dsum += dd*dd;
    }
    double dock = dsum/9.0;
    double tsum=0.0;
    for(int d=0;d<3;d++){
      double tref = -((double)trans[b*3+0]*(double)Rt[d*3+0]+(double)trans[b*3+1]*(double)Rt[d*3+1]+(double)trans[b*3+2]*(double)Rt[d*3+2]);
      double dd = tt[d]-tref;
      tsum += dd*dd;
    }
    dock += tsum/3.0;
    otb[b]=ot; dockb[b]=dock;
    for(int a=0;a<3;a++) for(int d=0;d<3;d++) Rs[a*3+d]=Rm[a][d];
    for(int d=0;d<3;d++) ts[d]=tt[d];
  }
  __syncthreads();
  double part=0.0;
  for(int nidx=tid; nidx<NPP; nidx+=256){
    int i = b*2*NPP + nidx;
    double p0=Xca[i*3], p1=Xca[i*3+1], p2=Xca[i*3+2];
    double q0=p0*Rs[0]+p1*Rs[3]+p2*Rs[6]+ts[0];
    double q1=p0*Rs[1]+p1*Rs[4]+p2*Rs[7]+ts[1];
    double q2=p0*Rs[2]+p1*Rs[5]+p2*Rs[8]+ts[2];
    int o=(b*NPP+nidx)*3;
    x1a[o]=q0; x1a[o+1]=q1; x1a[o+2]=q2;
    double d0=q0-ori0[o], d1=q1-ori0[o+1], d2=q2-ori0[o+2];
    part += d0*d0+d1*d1+d2*d2;
  }
  red[tid]=part;
  __syncthreads();
  for(int st=128; st>0; st>>=1){ if(tid<st) red[tid]+=red[tid+st]; __syncthreads(); }
  if(tid==0) rmsdb[b]=red[0]/(double)(NPP*3);
}

// ------------------------------------------------------------------
// stab (f64; f32 variant BANNED: 2/2 Inf correlation, rounds 7 & 14)
// ------------------------------------------------------------------
__global__ __launch_bounds__(256) void k_stab(const double* __restrict__ x1a, const double* __restrict__ Xca,
    double* __restrict__ stabp){
  __shared__ double Bsm[NPP*3];
  __shared__ double red[8];
  int blk=blockIdx.x;
  int bd=blk/125, rg=blk%125;
  int b=bd>>1, dir=bd&1;
  int tid=threadIdx.x;
  const double* Ap = (dir==0) ? (x1a + (size_t)b*NPP*3) : (Xca + (size_t)(b*2+1)*NPP*3);
  const double* Bp = (dir==0) ? (Xca + (size_t)(b*2+1)*NPP*3) : (x1a + (size_t)b*NPP*3);
  for(int idx=tid; idx<NPP*3; idx+=256) Bsm[idx]=Bp[idx]*STDV;
  __syncthreads();
  int row = rg*8 + (tid>>5);
  int jt = tid&31;
  double a0=Ap[row*3]*STDV, a1=Ap[row*3+1]*STDV, a2=Ap[row*3+2]*STDV;
  double mind=1e300;
  for(int j=jt;j<NPP;j+=32){
    double d0=a0-Bsm[j*3], d1=a1-Bsm[j*3+1], d2=a2-Bsm[j*3+2];
    double d=d0*d0+d1*d1+d2*d2;
    mind=fmin(mind,d);
  }
  #pragma unroll
  for(int off=16;off>0;off>>=1) mind=fmin(mind,__shfl_xor(mind,off,32));
  double se=0.0;
  for(int j=jt;j<NPP;j+=32){
    double d0=a0-Bsm[j*3], d1=a1-Bsm[j*3+1], d2=a2-Bsm[j*3+2];
    double d=d0*d0+d1*d1+d2*d2;
    se += exp((mind-d)*(1.0/SIGC));
  }
  #pragma unroll
  for(int off=16;off>0;off>>=1) se += __shfl_xor(se,off,32);
  if(jt==0) red[tid>>5] = fmax(GAMC - mind + SIGC*log(se), 0.0);
  __syncthreads();
  if(tid==0){
    double s=0.0;
    #pragma unroll
    for(int i=0;i<8;i++) s+=red[i];
    stabp[blk]=s;
  }
}

__global__ void k_out(const double* __restrict__ otb, const double* __restrict__ dockb,
    const double* __restrict__ rmsdb, const double* __restrict__ stabp, float* __restrict__ out){
  if(blockIdx.x==0 && threadIdx.x==0){
    double ot=0.0,dock=0.0,rmsd=0.0,stab=0.0;
    for(int b=0;b<BSZ;b++){
      ot+=otb[b]; dock+=dockb[b]; rmsd+=rmsdb[b];
      double s1=0.0,s2=0.0;
      for(int i=0;i<125;i++){ s1+=stabp[(b*2+0)*125+i]; s2+=stabp[(b*2+1)*125+i]; }
      stab += (s1*(1.0/NPP) + s2*(1.0/NPP))*(1.0/STDV);
    }
    ot*=0.25; dock*=0.25; rmsd*=0.25; stab*=0.25;
    out[0]=(float)(ot+dock+stab); out[1]=(float)ot; out[2]=(float)dock; out[3]=(float)stab; out[4]=(float)rmsd;
  }
}

// ------------------------------------------------------------------
extern "C" void kernel_launch(void* const* d_in, const int* in_sizes, int n_in,
                              void* d_out, int out_size, void* d_ws, size_t ws_size,
                              hipStream_t stream){
  const float* X      = (const float*)d_in[0];
  const float* nodea  = (const float*)d_in[1];
  const float* edgea  = (const float*)d_in[2];
  const float* center = (const float*)d_in[3];
  const float* kpin   = (const float*)d_in[4];
  const float* rot    = (const float*)d_in[5];
  const float* trans  = (const float*)d_in[6];
  const float* W_in1  = (const float*)d_in[7];
  const float* b_in1  = (const float*)d_in[8];
  const float* W_in2  = (const float*)d_in[9];
  const float* b_in2  = (const float*)d_in[10];
  const float* msg_W  = (const float*)d_in[11];
  const float* msg_b  = (const float*)d_in[12];
  const float* upd_W1 = (const float*)d_in[13];
  const float* upd_b1 = (const float*)d_in[14];
  const float* upd_W2 = (const float*)d_in[15];
  const float* upd_b2 = (const float*)d_in[16];
  const float* x_W    = (const float*)d_in[17];
  const float* v_W    = (const float*)d_in[18];
  const float* att_W  = (const float*)d_in[19];
  const float* act_W1 = (const float*)d_in[20];
  const float* act_b1 = (const float*)d_in[21];
  const float* act_W2 = (const float*)d_in[22];
  const float* act_b2 = (const float*)d_in[23];
  const float* geb_Wv1= (const float*)d_in[24];
  const float* geb_Wv2= (const float*)d_in[25];
  const float* geb_W1 = (const float*)d_in[26];
  const float* geb_b1 = (const float*)d_in[27];
  const float* geb_W2 = (const float*)d_in[28];
  const float* geb_b2 = (const float*)d_in[29];
  const float* sc_W1  = (const float*)d_in[30];
  const float* sc_b1  = (const float*)d_in[31];
  const float* sc_W2  = (const float*)d_in[32];
  const float* sc_b2  = (const float*)d_in[33];
  const float* fin_W  = (const float*)d_in[34];
  const int*   src    = (const int*)d_in[35];
  const int*   dst    = (const int*)d_in[36];
  float* out = (float*)d_out;

  double* wd = (double*)d_ws;
  size_t o = 0;
  double* XcaD  = wd + o; o += (size_t)NN*3;
  double* ori0D = wd + o; o += (size_t)BSZ*NPP*3;
  double* kpcD  = wd + o; o += 144;
  double* tkpcD = wd + o; o += 144;
  double* dirvD = wd + o; o += (size_t)EE*3;
  double* rbfD  = wd + o; o += (size_t)EE*RBFD;
  double* hbuf  = wd + o; o += (size_t)NN*HD;
  double* Pbuf  = wd + o; o += (size_t)NN*256;
  double* mbuf  = wd + o; o += (size_t)EE*HD;   // h2 lives here
  double* va    = wd + o; o += (size_t)NN*HD*3;
  double* vb    = wd + o; o += (size_t)NN*HD*3;
  double* ubuf  = wd + o; o += (size_t)BSZ*2*HD;
  double* attp  = wd + o; o += (size_t)64*HD;
  double* nv2b  = wd + o; o += (size_t)NN*HD;
  double* sbuf  = wd + o; o += (size_t)NN*256;
  double* cbbD  = wd + o; o += 24;
  double* ypartD= wd + o; o += (size_t)4000*37;
  double* YbufD = wd + o; o += 8*36;
  double* x1aD  = wd + o; o += (size_t)BSZ*NPP*3;
  double* otb_  = wd + o; o += 4;
  double* dkb_  = wd + o; o += 4;
  double* rmb_  = wd + o; o += 4;
  double* stp_  = wd + o; o += 1000;
  double* Wnode = wd + o; o += (size_t)4*128*256;
  double* Wedge2= wd + o; o += (size_t)4*37*128;
  double* xvW   = wd + o; o += (size_t)4*128*256;

  double* h2b  = mbuf;

  size_t need = o*8;
  if(ws_size < need){
    float mb = (float)((double)ws_size / 1.0e6);
    float val = (131072.0f + mb) * 1048576.0f;
    k_sent<<<1,64,0,stream>>>(out, val);
    return;
  }

  hipMemsetAsync(va, 0, (size_t)NN*HD*3*sizeof(double), stream);

  k_cvt_node<<<512,256,0,stream>>>(msg_W, Wnode);
  k_cvt_edge<<<74,256,0,stream>>>(msg_W, msg_b, Wedge2);
  k_cvt_xv<<<256,256,0,stream>>>(x_W, v_W, xvW);

  k_geom<<<32,256,0,stream>>>(X, center, kpin, rot, trans, XcaD, ori0D, kpcD, tkpcD);
  k_edge<<<(EE+255)/256,256,0,stream>>>(XcaD, src, dst, dirvD, rbfD);
  k_hinit<<<NN/4,256,0,stream>>>(nodea, W_in1, b_in1, W_in2, b_in2, hbuf);

  double* vcur = va;
  double* vnxt = vb;
  for(int l=0;l<NL;l++){
    const double* Wn  = Wnode  + (size_t)l*128*256;
    const double* We  = Wedge2 + (size_t)l*37*128;
    const double* xvl = xvW    + (size_t)l*128*256;
    const float* u1W = upd_W1 + (size_t)l*256*HD;
    const float* u1b = upd_b1 + (size_t)l*HD;
    const float* u2W = upd_W2 + (size_t)l*HD*HD;
    const float* u2b = upd_b2 + (size_t)l*HD;
    const float* aWl = att_W  + (size_t)l*HD*HD;
    const float* a1W = act_W1 + (size_t)l*HD*HD;
    const float* a1b = act_b1 + (size_t)l*HD;
    const float* a2W = act_W2 + (size_t)l*HD*HD;
    const float* a2b = act_b2 + (size_t)l*HD;

    k_nodeproj<<<NN/8,256,0,stream>>>(hbuf, Wn, Pbuf);
    k_layer<<<NN/4,256,0,stream>>>(Pbuf, rbfD, edgea, src, We,
                                   hbuf, u1W, u1b, u2W, u2b, h2b,
                                   vcur, dirvD, xvl, vnxt);
    k_att1<<<64,128,0,stream>>>(h2b, attp);
    k_att2<<<8,128,0,stream>>>(attp, aWl, ubuf);
    k_actcomb<<<NN/4,128,0,stream>>>(h2b, ubuf, a1W, a1b, a2W, a2b, hbuf);
    double* tmp=vcur; vcur=vnxt; vnxt=tmp;
  }
  // vcur == va (final v), vnxt == vb (free -> v1)
  k_gebv<<<NN/2,256,0,stream>>>(vcur, geb_Wv1, geb_Wv2, vnxt, nv2b);
  k_gebs<<<NN/4,256,0,stream>>>(hbuf, nv2b, geb_W1, geb_b1, geb_W2, geb_b2, sbuf);
  k_kpc<<<8,256,0,stream>>>(XcaD, cbbD);
  k_kpgen<<<NN/2,256,0,stream>>>(XcaD, sbuf, vnxt, cbbD, fin_W, sc_W1, sc_b1, sc_W2, sc_b2, ypartD);
  k_kpfin<<<8,64,0,stream>>>(ypartD, cbbD, YbufD);
  k_final<<<BSZ,256,0,stream>>>(YbufD, tkpcD, kpcD, rot, trans, XcaD, ori0D, x1aD, otb_, dkb_, rmb_);
  k_stab<<<1000,256,0,stream>>>(x1aD, XcaD, stp_);
  k_out<<<1,64,0,stream>>>(otb_, dkb_, rmb_, stp_, out);
}